// Round 1
// baseline (7209.306 us; speedup 1.0000x reference)
//
#include <hip/hip_runtime.h>
#include <math.h>

// Problem dims
#define B_    512
#define T_    125
#define N_    66
#define D_    20
#define H_    256
#define ST_   6
#define THIS_ 25
#define C_    (N_*H_)     // 16896 channels for BN
#define ROWS_ (B_*N_)     // 33792
#define NBG_  16          // batch groups for BN stats
#define BPG_  (B_/NBG_)   // 32
#define EPS_  1e-5f

// ---------------------------------------------------------------------------
// DCT along time: xd[b][n][d] = sum_t trans[d][t] * x[b][t][n]
// ---------------------------------------------------------------------------
__global__ __launch_bounds__(256) void k_dct(const float* __restrict__ x,
                                             const float* __restrict__ tm,
                                             float* __restrict__ xd) {
    __shared__ float xs[T_*N_];   // 8250 floats = 33 KB
    __shared__ float tl[D_*T_];   // 2500 floats = 10 KB
    const int b = blockIdx.x, tid = threadIdx.x;
    const float* xb = x + (size_t)b * T_ * N_;
    for (int i = tid; i < T_*N_; i += 256) xs[i] = xb[i];
    for (int i = tid; i < D_*T_; i += 256) tl[i] = tm[i];   // first 20 rows contiguous
    __syncthreads();
    for (int p = tid; p < N_*D_; p += 256) {
        const int n = p / D_, d = p % D_;
        float acc = 0.f;
        for (int t = 0; t < T_; ++t)
            acc = fmaf(tl[d*T_ + t], xs[t*N_ + n], acc);
        xd[(size_t)b * N_ * D_ + p] = acc;   // p == n*D_+d
    }
}

// ---------------------------------------------------------------------------
// C[row][f] = sum_k A'[row][k] * W[k][f]   (F fixed = 256)
// A' = A when scale==nullptr, else A' = tanh(A*scale[ch]+shift[ch]) (fused BN,
// channel = (row%66)*256 + k, only used with K==256).
// 64 rows/block, 4 waves; wave rg handles rows rg*16..+15; lane fq holds 4 f.
// A reads are wave-uniform -> scalar loads; W reads coalesced float4.
// ---------------------------------------------------------------------------
__global__ __launch_bounds__(256) void k_xw(const float* __restrict__ A,
                                            const float* __restrict__ W,
                                            float* __restrict__ C,
                                            const int K,
                                            const float* __restrict__ scale,
                                            const float* __restrict__ shift) {
    const int tid = threadIdx.x;
    const int fq  = tid & 63;
    const int rg  = __builtin_amdgcn_readfirstlane(tid >> 6);
    const int row0 = blockIdx.x * 64 + rg * 16;

    float4 acc[16];
    #pragma unroll
    for (int r = 0; r < 16; ++r) acc[r] = make_float4(0.f, 0.f, 0.f, 0.f);

    if (scale == nullptr) {
        for (int k = 0; k < K; ++k) {
            const float4 wv = *(const float4*)(W + (size_t)k * H_ + fq * 4);
            #pragma unroll
            for (int r = 0; r < 16; ++r) {
                const float a = A[(size_t)(row0 + r) * K + k];
                acc[r].x = fmaf(a, wv.x, acc[r].x);
                acc[r].y = fmaf(a, wv.y, acc[r].y);
                acc[r].z = fmaf(a, wv.z, acc[r].z);
                acc[r].w = fmaf(a, wv.w, acc[r].w);
            }
        }
    } else {
        // K == 256 here; channel base per row is loop-invariant (LICM -> SGPR)
        for (int k = 0; k < K; ++k) {
            const float4 wv = *(const float4*)(W + (size_t)k * H_ + fq * 4);
            #pragma unroll
            for (int r = 0; r < 16; ++r) {
                const int row = row0 + r;
                const int cb  = (row % N_) * H_ + k;
                const float raw = A[(size_t)row * K + k];
                const float a = tanhf(fmaf(raw, scale[cb], shift[cb]));
                acc[r].x = fmaf(a, wv.x, acc[r].x);
                acc[r].y = fmaf(a, wv.y, acc[r].y);
                acc[r].z = fmaf(a, wv.z, acc[r].z);
                acc[r].w = fmaf(a, wv.w, acc[r].w);
            }
        }
    }
    #pragma unroll
    for (int r = 0; r < 16; ++r)
        *(float4*)(C + (size_t)(row0 + r) * H_ + fq * 4) = acc[r];
}

// ---------------------------------------------------------------------------
// y[b][n][f] = sum_m att[n][m] * xw[b][m][f] + bias[f]
// grid (B, 2): block owns one b and one 128-wide f half. xw slab in LDS.
// wave ng handles n = ng*17 .. ; lane fq holds 2 f. att reads wave-uniform.
// ---------------------------------------------------------------------------
__global__ __launch_bounds__(256) void k_att(const float* __restrict__ xw,
                                             const float* __restrict__ att,
                                             const float* __restrict__ bias,
                                             float* __restrict__ y) {
    __shared__ float xl[N_ * 128];   // 33 KB
    const int b = blockIdx.x, fh = blockIdx.y, tid = threadIdx.x;
    const float* src = xw + (size_t)b * C_ + fh * 128;
    for (int i = tid; i < N_ * 32; i += 256) {       // 2112 float4
        const int m = i >> 5, f4 = i & 31;
        *(float4*)(xl + m * 128 + f4 * 4) =
            *(const float4*)(src + (size_t)m * H_ + f4 * 4);
    }
    __syncthreads();

    const int fq = tid & 63;
    const int ng = __builtin_amdgcn_readfirstlane(tid >> 6);
    const int n0 = ng * 17;

    float2 acc[17];
    #pragma unroll
    for (int i = 0; i < 17; ++i) acc[i] = make_float2(0.f, 0.f);

    for (int m = 0; m < N_; ++m) {
        const float2 xv = *(const float2*)(xl + m * 128 + fq * 2);
        #pragma unroll
        for (int i = 0; i < 17; ++i) {
            int n = n0 + i; n = n < N_ ? n : N_ - 1;   // clamp (stores guarded)
            const float a = att[n * N_ + m];
            acc[i].x = fmaf(a, xv.x, acc[i].x);
            acc[i].y = fmaf(a, xv.y, acc[i].y);
        }
    }
    const float2 bv = *(const float2*)(bias + fh * 128 + fq * 2);
    #pragma unroll
    for (int i = 0; i < 17; ++i) {
        const int n = n0 + i;
        if (n < N_) {
            float2 o = make_float2(acc[i].x + bv.x, acc[i].y + bv.y);
            *(float2*)(y + (size_t)b * C_ + n * H_ + fh * 128 + fq * 2) = o;
        }
    }
}

// ---------------------------------------------------------------------------
// BN partial stats: P1/P2[g][c] = sum / sumsq over batch group g (32 b's).
// Deterministic fixed-order reduction. grid (17, 16), float4 per thread.
// ---------------------------------------------------------------------------
__global__ __launch_bounds__(256) void k_stats(const float* __restrict__ v,
                                               float* __restrict__ P1,
                                               float* __restrict__ P2) {
    const int c4 = blockIdx.x * 256 + threadIdx.x;
    if (c4 >= C_ / 4) return;
    const int g = blockIdx.y;
    float4 s1 = make_float4(0.f,0.f,0.f,0.f), s2 = make_float4(0.f,0.f,0.f,0.f);
    const float4* vp = (const float4*)v;
    for (int i = 0; i < BPG_; ++i) {
        const int b = g * BPG_ + i;
        const float4 t = vp[(size_t)b * (C_ / 4) + c4];
        s1.x += t.x; s1.y += t.y; s1.z += t.z; s1.w += t.w;
        s2.x = fmaf(t.x, t.x, s2.x); s2.y = fmaf(t.y, t.y, s2.y);
        s2.z = fmaf(t.z, t.z, s2.z); s2.w = fmaf(t.w, t.w, s2.w);
    }
    ((float4*)(P1 + (size_t)g * C_))[c4] = s1;
    ((float4*)(P2 + (size_t)g * C_))[c4] = s2;
}

__device__ __forceinline__ void bn_coef(const float* P1, const float* P2,
                                        const float* gam, const float* bet,
                                        int c4, float4& sc, float4& sh) {
    float4 s1 = make_float4(0.f,0.f,0.f,0.f), s2 = make_float4(0.f,0.f,0.f,0.f);
    for (int g = 0; g < NBG_; ++g) {
        const float4 a = ((const float4*)(P1 + (size_t)g * C_))[c4];
        const float4 b = ((const float4*)(P2 + (size_t)g * C_))[c4];
        s1.x += a.x; s1.y += a.y; s1.z += a.z; s1.w += a.w;
        s2.x += b.x; s2.y += b.y; s2.z += b.z; s2.w += b.w;
    }
    const float inv = 1.f / (float)B_;
    const float4 gm = ((const float4*)gam)[c4];
    const float4 bt = ((const float4*)bet)[c4];
    float mu, var;
    mu = s1.x*inv; var = fmaf(-mu, mu, s2.x*inv); sc.x = gm.x*rsqrtf(var+EPS_); sh.x = bt.x - mu*sc.x;
    mu = s1.y*inv; var = fmaf(-mu, mu, s2.y*inv); sc.y = gm.y*rsqrtf(var+EPS_); sh.y = bt.y - mu*sc.y;
    mu = s1.z*inv; var = fmaf(-mu, mu, s2.z*inv); sc.z = gm.z*rsqrtf(var+EPS_); sh.z = bt.z - mu*sc.z;
    mu = s1.w*inv; var = fmaf(-mu, mu, s2.w*inv); sc.w = gm.w*rsqrtf(var+EPS_); sh.w = bt.w - mu*sc.w;
}

// Finalize BN coefficients into SC/SH (consumed by the fused k_xw).
__global__ __launch_bounds__(256) void k_bnfin(const float* __restrict__ P1,
                                               const float* __restrict__ P2,
                                               const float* __restrict__ gam,
                                               const float* __restrict__ bet,
                                               float* __restrict__ SC,
                                               float* __restrict__ SH) {
    const int c4 = blockIdx.x * 256 + threadIdx.x;
    if (c4 >= C_ / 4) return;
    float4 sc, sh;
    bn_coef(P1, P2, gam, bet, c4, sc, sh);
    ((float4*)SC)[c4] = sc;
    ((float4*)SH)[c4] = sh;
}

// out = tanh(v*sc+sh) (+ res). grid (17, 16). res may alias out (elementwise).
__global__ __launch_bounds__(256) void k_apply(const float* __restrict__ v,
                                               const float* __restrict__ P1,
                                               const float* __restrict__ P2,
                                               const float* __restrict__ gam,
                                               const float* __restrict__ bet,
                                               const float* __restrict__ res,
                                               float* __restrict__ out) {
    const int c4 = blockIdx.x * 256 + threadIdx.x;
    if (c4 >= C_ / 4) return;
    const int g = blockIdx.y;
    float4 sc, sh;
    bn_coef(P1, P2, gam, bet, c4, sc, sh);
    const float4* vp = (const float4*)v;
    const float4* rp = (const float4*)res;
    float4* op = (float4*)out;
    for (int i = 0; i < BPG_; ++i) {
        const size_t idx = (size_t)(g * BPG_ + i) * (C_ / 4) + c4;
        const float4 t = vp[idx];
        float4 o;
        o.x = tanhf(fmaf(t.x, sc.x, sh.x));
        o.y = tanhf(fmaf(t.y, sc.y, sh.y));
        o.z = tanhf(fmaf(t.z, sc.z, sh.z));
        o.w = tanhf(fmaf(t.w, sc.w, sh.w));
        if (res) {
            const float4 r = rp[idx];
            o.x += r.x; o.y += r.y; o.z += r.z; o.w += r.w;
        }
        op[idx] = o;
    }
}

// ---------------------------------------------------------------------------
// Decoder x@w: o[row][d] = sum_k h[row][k] * W[k][d], W = [256][20].
// One thread per row; W reads wave-uniform -> scalar loads.
// ---------------------------------------------------------------------------
__global__ __launch_bounds__(256) void k_dec_xw(const float* __restrict__ h,
                                                const float* __restrict__ W,
                                                float* __restrict__ o) {
    const int row = blockIdx.x * 256 + threadIdx.x;   // grid 132 -> exact
    float acc[D_];
    #pragma unroll
    for (int f = 0; f < D_; ++f) acc[f] = 0.f;
    const float* hr = h + (size_t)row * H_;
    for (int k4 = 0; k4 < H_; k4 += 4) {
        const float4 a = *(const float4*)(hr + k4);
        const float av[4] = {a.x, a.y, a.z, a.w};
        #pragma unroll
        for (int kk = 0; kk < 4; ++kk) {
            #pragma unroll
            for (int f = 0; f < D_; ++f)
                acc[f] = fmaf(av[kk], W[(k4 + kk) * D_ + f], acc[f]);
        }
    }
    float* op = o + (size_t)row * D_;
    #pragma unroll
    for (int f = 0; f < D_; ++f) op[f] = acc[f];
}

// ---------------------------------------------------------------------------
// Decoder att + bias + xd residual, then iDCT + history splice.
// ---------------------------------------------------------------------------
__global__ __launch_bounds__(256) void k_dec_fin(const float* __restrict__ ow,
                                                 const float* __restrict__ att,
                                                 const float* __restrict__ dbias,
                                                 const float* __restrict__ xd,
                                                 const float* __restrict__ itm,
                                                 const float* __restrict__ x,
                                                 float* __restrict__ out) {
    __shared__ float attL[N_ * N_];    // 4356
    __shared__ float owL[N_ * D_];     // 1320
    __shared__ float odL[N_ * 21];     // padded to 21 -> conflict-free
    __shared__ float itL[T_ * D_];     // 2500
    const int b = blockIdx.x, tid = threadIdx.x;
    for (int i = tid; i < N_*N_; i += 256) attL[i] = att[i];
    for (int i = tid; i < N_*D_; i += 256) owL[i] = ow[(size_t)b * N_ * D_ + i];
    for (int i = tid; i < T_*D_; i += 256) {
        const int t = i / D_, d = i % D_;
        itL[i] = itm[t * T_ + d];      // itrans_m[:, :20]
    }
    __syncthreads();
    for (int p = tid; p < N_*D_; p += 256) {
        const int n = p / D_, d = p % D_;
        float acc = dbias[d] + xd[(size_t)b * N_ * D_ + p];
        for (int m = 0; m < N_; ++m)
            acc = fmaf(attL[n * N_ + m], owL[m * D_ + d], acc);
        odL[n * 21 + d] = acc;
    }
    __syncthreads();
    const float* xb = x + (size_t)b * T_ * N_;
    float* ob = out + (size_t)b * T_ * N_;
    for (int q = tid; q < T_*N_; q += 256) {
        const int t = q / N_, n = q % N_;
        float o;
        if (t < THIS_) {
            o = xb[q];                 // ground-truth history frames
        } else {
            o = 0.f;
            for (int d = 0; d < D_; ++d)
                o = fmaf(itL[t * D_ + d], odL[n * 21 + d], o);
        }
        ob[q] = o;
    }
}

// ---------------------------------------------------------------------------
extern "C" void kernel_launch(void* const* d_in, const int* in_sizes, int n_in,
                              void* d_out, int out_size, void* d_ws, size_t ws_size,
                              hipStream_t stream) {
    const float* x    = (const float*)d_in[0];
    const float* tm   = (const float*)d_in[1];
    const float* itm  = (const float*)d_in[2];
    const float* encw = (const float*)d_in[3];
    const float* enca = (const float*)d_in[4];
    const float* encb = (const float*)d_in[5];
    const float* bn0g = (const float*)d_in[6];
    const float* bn0b = (const float*)d_in[7];
    const float* g1w  = (const float*)d_in[8];
    const float* g1a  = (const float*)d_in[9];
    const float* g1b  = (const float*)d_in[10];
    const float* b1g  = (const float*)d_in[11];
    const float* b1b  = (const float*)d_in[12];
    const float* g2w  = (const float*)d_in[13];
    const float* g2a  = (const float*)d_in[14];
    const float* g2b  = (const float*)d_in[15];
    const float* b2g  = (const float*)d_in[16];
    const float* b2b  = (const float*)d_in[17];
    const float* decw = (const float*)d_in[18];
    const float* deca = (const float*)d_in[19];
    const float* decb = (const float*)d_in[20];
    float* out = (float*)d_out;

    float* ws = (float*)d_ws;
    float* xd = ws;                         //   675840 floats
    float* h  = xd + 675840;                //  8650752
    float* xw = h  + 8650752;               //  8650752
    float* y  = xw + 8650752;               //  8650752
    float* P1 = y  + 8650752;               //   270336
    float* P2 = P1 + 270336;                //   270336
    float* SC = P2 + 270336;                //    16896
    float* SH = SC + 16896;                 //    16896  (~104 MiB total)

    const dim3 blk(256);
    const dim3 gS(17, NBG_);

    k_dct<<<B_, blk, 0, stream>>>(x, tm, xd);

    // encoder: gc(dct->hid) + bn0 + tanh
    k_xw <<<ROWS_/64, blk, 0, stream>>>(xd, encw, xw, D_, nullptr, nullptr);
    k_att<<<dim3(B_,2), blk, 0, stream>>>(xw, enca, encb, y);
    k_stats<<<gS, blk, 0, stream>>>(y, P1, P2);
    k_apply<<<gS, blk, 0, stream>>>(y, P1, P2, bn0g, bn0b, nullptr, h);

    for (int s = 0; s < ST_; ++s) {
        // gc1: xw = h@w1; y = att1*xw + b1; stats; bn coefs
        k_xw <<<ROWS_/64, blk, 0, stream>>>(h, g1w + s*H_*H_, xw, H_, nullptr, nullptr);
        k_att<<<dim3(B_,2), blk, 0, stream>>>(xw, g1a + s*N_*N_, g1b + s*H_, y);
        k_stats<<<gS, blk, 0, stream>>>(y, P1, P2);
        k_bnfin<<<17, blk, 0, stream>>>(P1, P2, b1g + s*C_, b1b + s*C_, SC, SH);
        // gc2 with fused bn1+tanh on the fly: xw = tanh(bn(y)) @ w2
        k_xw <<<ROWS_/64, blk, 0, stream>>>(y, g2w + s*H_*H_, xw, H_, SC, SH);
        k_att<<<dim3(B_,2), blk, 0, stream>>>(xw, g2a + s*N_*N_, g2b + s*H_, y);
        k_stats<<<gS, blk, 0, stream>>>(y, P1, P2);
        // h = tanh(bn2(y)) + h
        k_apply<<<gS, blk, 0, stream>>>(y, P1, P2, b2g + s*C_, b2b + s*C_, h, h);
    }

    // decoder + iDCT + splice
    k_dec_xw<<<ROWS_/256, blk, 0, stream>>>(h, decw, y);   // y reused: [ROWS][20]
    k_dec_fin<<<B_, blk, 0, stream>>>(y, deca, decb, xd, itm, x, out);
}

// Round 7
// 1183.513 us; speedup vs baseline: 6.0914x; 6.0914x over previous
//
#include <hip/hip_runtime.h>
#include <math.h>

// Problem dims
#define B_    512
#define T_    125
#define N_    66
#define D_    20
#define H_    256
#define ST_   6
#define THIS_ 25
#define C_    (N_*H_)     // 16896 channels for BN
#define ROWS_ (B_*N_)     // 33792
#define NBG_  16          // batch groups for BN stats
#define BPG_  (B_/NBG_)   // 32
#define EPS_  1e-5f

typedef __attribute__((ext_vector_type(8))) short bf16x8;
typedef __attribute__((ext_vector_type(4))) float f32x4;

__device__ __forceinline__ ushort f2bf(float f) {
    unsigned u = __float_as_uint(f);
    u += 0x7fffu + ((u >> 16) & 1u);       // round-to-nearest-even
    return (ushort)(u >> 16);
}

// ---------------------------------------------------------------------------
// DCT along time: xd[b][n][d] = sum_t trans[d][t] * x[b][t][n]   (= round 1)
// ---------------------------------------------------------------------------
__global__ __launch_bounds__(256) void k_dct(const float* __restrict__ x,
                                             const float* __restrict__ tm,
                                             float* __restrict__ xd) {
    __shared__ float xs[T_*N_];
    __shared__ float tl[D_*T_];
    const int b = blockIdx.x, tid = threadIdx.x;
    const float* xb = x + (size_t)b * T_ * N_;
    for (int i = tid; i < T_*N_; i += 256) xs[i] = xb[i];
    for (int i = tid; i < D_*T_; i += 256) tl[i] = tm[i];
    __syncthreads();
    for (int p = tid; p < N_*D_; p += 256) {
        const int n = p / D_, d = p % D_;
        float acc = 0.f;
        for (int t = 0; t < T_; ++t)
            acc = fmaf(tl[d*T_ + t], xs[t*N_ + n], acc);
        xd[(size_t)b * N_ * D_ + p] = acc;
    }
}

// ---------------------------------------------------------------------------
// Encoder GEMM (K=20, fp32): C[row][f] = sum_k A[row][k]*W[k][f]  (= round 1)
// ---------------------------------------------------------------------------
__global__ __launch_bounds__(256) void k_xw(const float* __restrict__ A,
                                            const float* __restrict__ W,
                                            float* __restrict__ C) {
    const int tid = threadIdx.x;
    const int fq  = tid & 63;
    const int rg  = __builtin_amdgcn_readfirstlane(tid >> 6);
    const int row0 = blockIdx.x * 64 + rg * 16;

    float4 acc[16];
    #pragma unroll
    for (int r = 0; r < 16; ++r) acc[r] = make_float4(0.f, 0.f, 0.f, 0.f);

    for (int k = 0; k < D_; ++k) {
        const float4 wv = *(const float4*)(W + (size_t)k * H_ + fq * 4);
        #pragma unroll
        for (int r = 0; r < 16; ++r) {
            const float a = A[(size_t)(row0 + r) * D_ + k];
            acc[r].x = fmaf(a, wv.x, acc[r].x);
            acc[r].y = fmaf(a, wv.y, acc[r].y);
            acc[r].z = fmaf(a, wv.z, acc[r].z);
            acc[r].w = fmaf(a, wv.w, acc[r].w);
        }
    }
    #pragma unroll
    for (int r = 0; r < 16; ++r)
        *(float4*)(C + (size_t)(row0 + r) * H_ + fq * 4) = acc[r];
}

// ---------------------------------------------------------------------------
// MFMA stage GEMM, fp32 in / fp32 out, in-kernel bf16 conversion.
// C[row][f] = sum_k A'[row][k] * W[k][f];  A' = A or tanh(A*sc+sh) (fused BN,
// channel cb = (row%66)*256+k).  W is the ORIGINAL [256][256] fp32 weight.
// Tile: 64 rows x 256 cols, BK=32, 4 waves (wave = 64-col strip). grid 528.
// LDS: As[64][32] bf16 (row-major), Bt[256][32] bf16 (Bt[col][k] transposed
// during staging).  Fragments: lane=(kq*16+fr): a[m]=As[m*16+fr][kq*8..],
// b[n]=Bt[wc*64+n*16+fr][kq*8..];  C/D: col=fr, row=kq*4+j (probe-verified).
// ---------------------------------------------------------------------------
__global__ __launch_bounds__(256) void k_mfma(const float* __restrict__ A,
                                              const float* __restrict__ W,
                                              float* __restrict__ C,
                                              const float* __restrict__ scale,
                                              const float* __restrict__ shift) {
    __shared__ __align__(16) ushort As[64 * 32];
    __shared__ __align__(16) ushort Bt[256 * 32];
    const int tid  = threadIdx.x;
    const int lane = tid & 63;
    const int wc   = tid >> 6;            // wave -> 64-col strip
    const int row0 = blockIdx.x * 64;
    const int kq = lane >> 4;
    const int fr = lane & 15;

    // A staging: thread covers row ar, k-slot ak..ak+7
    const int ar   = tid >> 2;            // 0..63
    const int ak   = (tid & 3) * 8;       // 0,8,16,24
    const int arow = row0 + ar;
    const int cbb  = (arow % N_) * H_;    // BN channel base (fused path)

    f32x4 acc[4][4] = {};

    for (int kt = 0; kt < 8; ++kt) {
        const int kb = kt * 32;

        // ---- prefetch into registers (no LDS hazard yet) ----
        float av[8];
        const float* ap = A + (size_t)arow * H_ + kb + ak;
        *(float4*)&av[0] = *(const float4*)ap;
        *(float4*)&av[4] = *(const float4*)(ap + 4);
        if (scale) {
            float sv[8], hv[8];
            const float* sp = scale + cbb + kb + ak;
            const float* hp = shift + cbb + kb + ak;
            *(float4*)&sv[0] = *(const float4*)sp;
            *(float4*)&sv[4] = *(const float4*)(sp + 4);
            *(float4*)&hv[0] = *(const float4*)hp;
            *(float4*)&hv[4] = *(const float4*)(hp + 4);
            #pragma unroll
            for (int j = 0; j < 8; ++j)
                av[j] = tanhf(fmaf(av[j], sv[j], hv[j]));
        }
        bf16x8 av8;
        #pragma unroll
        for (int j = 0; j < 8; ++j) av8[j] = (short)f2bf(av[j]);

        float wv[32];                      // W[kb+kr][tid], coalesced across tid
        #pragma unroll
        for (int kr = 0; kr < 32; ++kr)
            wv[kr] = W[(size_t)(kb + kr) * H_ + tid];

        __syncthreads();                   // prev iteration's LDS reads done
        *(bf16x8*)&As[ar * 32 + ak] = av8;
        #pragma unroll
        for (int kr = 0; kr < 32; ++kr)
            Bt[tid * 32 + kr] = f2bf(wv[kr]);
        __syncthreads();                   // tile ready

        bf16x8 a[4], b[4];
        #pragma unroll
        for (int m = 0; m < 4; ++m)
            a[m] = *(const bf16x8*)&As[(m * 16 + fr) * 32 + kq * 8];
        #pragma unroll
        for (int n = 0; n < 4; ++n)
            b[n] = *(const bf16x8*)&Bt[(wc * 64 + n * 16 + fr) * 32 + kq * 8];
        #pragma unroll
        for (int m = 0; m < 4; ++m)
            #pragma unroll
            for (int n = 0; n < 4; ++n)
                acc[m][n] = __builtin_amdgcn_mfma_f32_16x16x32_bf16(
                                a[m], b[n], acc[m][n], 0, 0, 0);
    }

    #pragma unroll
    for (int m = 0; m < 4; ++m) {
        #pragma unroll
        for (int n = 0; n < 4; ++n) {
            #pragma unroll
            for (int j = 0; j < 4; ++j) {
                const int grow = row0 + m * 16 + kq * 4 + j;
                const int gcol = wc * 64 + n * 16 + fr;
                C[(size_t)grow * H_ + gcol] = acc[m][n][j];
            }
        }
    }
}

// ---------------------------------------------------------------------------
// y[b][n][f] = sum_m att[n][m] * xw[b][m][f] + bias[f]   (= round 1, NOT
// in-place: xw and y are separate buffers)
// ---------------------------------------------------------------------------
__global__ __launch_bounds__(256) void k_att(const float* __restrict__ xw,
                                             const float* __restrict__ att,
                                             const float* __restrict__ bias,
                                             float* __restrict__ y) {
    __shared__ float xl[N_ * 128];
    const int b = blockIdx.x, fh = blockIdx.y, tid = threadIdx.x;
    const float* src = xw + (size_t)b * C_ + fh * 128;
    for (int i = tid; i < N_ * 32; i += 256) {
        const int m = i >> 5, f4 = i & 31;
        *(float4*)(xl + m * 128 + f4 * 4) =
            *(const float4*)(src + (size_t)m * H_ + f4 * 4);
    }
    __syncthreads();

    const int fq = tid & 63;
    const int ng = __builtin_amdgcn_readfirstlane(tid >> 6);
    const int n0 = ng * 17;

    float2 acc[17];
    #pragma unroll
    for (int i = 0; i < 17; ++i) acc[i] = make_float2(0.f, 0.f);

    for (int m = 0; m < N_; ++m) {
        const float2 xv = *(const float2*)(xl + m * 128 + fq * 2);
        #pragma unroll
        for (int i = 0; i < 17; ++i) {
            int n = n0 + i; n = n < N_ ? n : N_ - 1;
            const float a = att[n * N_ + m];
            acc[i].x = fmaf(a, xv.x, acc[i].x);
            acc[i].y = fmaf(a, xv.y, acc[i].y);
        }
    }
    const float2 bv = *(const float2*)(bias + fh * 128 + fq * 2);
    #pragma unroll
    for (int i = 0; i < 17; ++i) {
        const int n = n0 + i;
        if (n < N_) {
            float2 o = make_float2(acc[i].x + bv.x, acc[i].y + bv.y);
            *(float2*)(y + (size_t)b * C_ + n * H_ + fh * 128 + fq * 2) = o;
        }
    }
}

// ---------------------------------------------------------------------------
// BN partial stats over batch group g.   (= round 1)
// ---------------------------------------------------------------------------
__global__ __launch_bounds__(256) void k_stats(const float* __restrict__ v,
                                               float* __restrict__ P1,
                                               float* __restrict__ P2) {
    const int c4 = blockIdx.x * 256 + threadIdx.x;
    if (c4 >= C_ / 4) return;
    const int g = blockIdx.y;
    float4 s1 = make_float4(0.f,0.f,0.f,0.f), s2 = make_float4(0.f,0.f,0.f,0.f);
    const float4* vp = (const float4*)v;
    for (int i = 0; i < BPG_; ++i) {
        const int b = g * BPG_ + i;
        const float4 t = vp[(size_t)b * (C_ / 4) + c4];
        s1.x += t.x; s1.y += t.y; s1.z += t.z; s1.w += t.w;
        s2.x = fmaf(t.x, t.x, s2.x); s2.y = fmaf(t.y, t.y, s2.y);
        s2.z = fmaf(t.z, t.z, s2.z); s2.w = fmaf(t.w, t.w, s2.w);
    }
    ((float4*)(P1 + (size_t)g * C_))[c4] = s1;
    ((float4*)(P2 + (size_t)g * C_))[c4] = s2;
}

__device__ __forceinline__ void bn_coef(const float* P1, const float* P2,
                                        const float* gam, const float* bet,
                                        int c4, float4& sc, float4& sh) {
    float4 s1 = make_float4(0.f,0.f,0.f,0.f), s2 = make_float4(0.f,0.f,0.f,0.f);
    for (int g = 0; g < NBG_; ++g) {
        const float4 a = ((const float4*)(P1 + (size_t)g * C_))[c4];
        const float4 b = ((const float4*)(P2 + (size_t)g * C_))[c4];
        s1.x += a.x; s1.y += a.y; s1.z += a.z; s1.w += a.w;
        s2.x += b.x; s2.y += b.y; s2.z += b.z; s2.w += b.w;
    }
    const float inv = 1.f / (float)B_;
    const float4 gm = ((const float4*)gam)[c4];
    const float4 bt = ((const float4*)bet)[c4];
    float mu, var;
    mu = s1.x*inv; var = fmaf(-mu, mu, s2.x*inv); sc.x = gm.x*rsqrtf(var+EPS_); sh.x = bt.x - mu*sc.x;
    mu = s1.y*inv; var = fmaf(-mu, mu, s2.y*inv); sc.y = gm.y*rsqrtf(var+EPS_); sh.y = bt.y - mu*sc.y;
    mu = s1.z*inv; var = fmaf(-mu, mu, s2.z*inv); sc.z = gm.z*rsqrtf(var+EPS_); sh.z = bt.z - mu*sc.z;
    mu = s1.w*inv; var = fmaf(-mu, mu, s2.w*inv); sc.w = gm.w*rsqrtf(var+EPS_); sh.w = bt.w - mu*sc.w;
}

// Finalize BN coefficients into SC/SH.   (= round 1)
__global__ __launch_bounds__(256) void k_bnfin(const float* __restrict__ P1,
                                               const float* __restrict__ P2,
                                               const float* __restrict__ gam,
                                               const float* __restrict__ bet,
                                               float* __restrict__ SC,
                                               float* __restrict__ SH) {
    const int c4 = blockIdx.x * 256 + threadIdx.x;
    if (c4 >= C_ / 4) return;
    float4 sc, sh;
    bn_coef(P1, P2, gam, bet, c4, sc, sh);
    ((float4*)SC)[c4] = sc;
    ((float4*)SH)[c4] = sh;
}

// out = tanh(v*sc+sh) (+ res).   (= round 1, fp32 only, no shadows)
__global__ __launch_bounds__(256) void k_apply(const float* __restrict__ v,
                                               const float* __restrict__ P1,
                                               const float* __restrict__ P2,
                                               const float* __restrict__ gam,
                                               const float* __restrict__ bet,
                                               const float* __restrict__ res,
                                               float* __restrict__ out) {
    const int c4 = blockIdx.x * 256 + threadIdx.x;
    if (c4 >= C_ / 4) return;
    const int g = blockIdx.y;
    float4 sc, sh;
    bn_coef(P1, P2, gam, bet, c4, sc, sh);
    const float4* vp = (const float4*)v;
    const float4* rp = (const float4*)res;
    float4* op = (float4*)out;
    for (int i = 0; i < BPG_; ++i) {
        const size_t idx = (size_t)(g * BPG_ + i) * (C_ / 4) + c4;
        const float4 t = vp[idx];
        float4 o;
        o.x = tanhf(fmaf(t.x, sc.x, sh.x));
        o.y = tanhf(fmaf(t.y, sc.y, sh.y));
        o.z = tanhf(fmaf(t.z, sc.z, sh.z));
        o.w = tanhf(fmaf(t.w, sc.w, sh.w));
        if (res) {
            const float4 r = rp[idx];
            o.x += r.x; o.y += r.y; o.z += r.z; o.w += r.w;
        }
        op[idx] = o;
    }
}

// ---------------------------------------------------------------------------
// Decoder x@w (fp32, K=256, F=20)   (= round 1)
// ---------------------------------------------------------------------------
__global__ __launch_bounds__(256) void k_dec_xw(const float* __restrict__ h,
                                                const float* __restrict__ W,
                                                float* __restrict__ o) {
    const int row = blockIdx.x * 256 + threadIdx.x;
    float acc[D_];
    #pragma unroll
    for (int f = 0; f < D_; ++f) acc[f] = 0.f;
    const float* hr = h + (size_t)row * H_;
    for (int k4 = 0; k4 < H_; k4 += 4) {
        const float4 a = *(const float4*)(hr + k4);
        const float av[4] = {a.x, a.y, a.z, a.w};
        #pragma unroll
        for (int kk = 0; kk < 4; ++kk) {
            #pragma unroll
            for (int f = 0; f < D_; ++f)
                acc[f] = fmaf(av[kk], W[(k4 + kk) * D_ + f], acc[f]);
        }
    }
    float* op = o + (size_t)row * D_;
    #pragma unroll
    for (int f = 0; f < D_; ++f) op[f] = acc[f];
}

// ---------------------------------------------------------------------------
// Decoder att + bias + xd residual, iDCT, history splice.   (= round 1)
// ---------------------------------------------------------------------------
__global__ __launch_bounds__(256) void k_dec_fin(const float* __restrict__ ow,
                                                 const float* __restrict__ att,
                                                 const float* __restrict__ dbias,
                                                 const float* __restrict__ xd,
                                                 const float* __restrict__ itm,
                                                 const float* __restrict__ x,
                                                 float* __restrict__ out) {
    __shared__ float attL[N_ * N_];
    __shared__ float owL[N_ * D_];
    __shared__ float odL[N_ * 21];
    __shared__ float itL[T_ * D_];
    const int b = blockIdx.x, tid = threadIdx.x;
    for (int i = tid; i < N_*N_; i += 256) attL[i] = att[i];
    for (int i = tid; i < N_*D_; i += 256) owL[i] = ow[(size_t)b * N_ * D_ + i];
    for (int i = tid; i < T_*D_; i += 256) {
        const int t = i / D_, d = i % D_;
        itL[i] = itm[t * T_ + d];
    }
    __syncthreads();
    for (int p = tid; p < N_*D_; p += 256) {
        const int n = p / D_, d = p % D_;
        float acc = dbias[d] + xd[(size_t)b * N_ * D_ + p];
        for (int m = 0; m < N_; ++m)
            acc = fmaf(attL[n * N_ + m], owL[m * D_ + d], acc);
        odL[n * 21 + d] = acc;
    }
    __syncthreads();
    const float* xb = x + (size_t)b * T_ * N_;
    float* ob = out + (size_t)b * T_ * N_;
    for (int q = tid; q < T_*N_; q += 256) {
        const int t = q / N_, n = q % N_;
        float o;
        if (t < THIS_) {
            o = xb[q];
        } else {
            o = 0.f;
            for (int d = 0; d < D_; ++d)
                o = fmaf(itL[t * D_ + d], odL[n * 21 + d], o);
        }
        ob[q] = o;
    }
}

// ---------------------------------------------------------------------------
extern "C" void kernel_launch(void* const* d_in, const int* in_sizes, int n_in,
                              void* d_out, int out_size, void* d_ws, size_t ws_size,
                              hipStream_t stream) {
    const float* x    = (const float*)d_in[0];
    const float* tm   = (const float*)d_in[1];
    const float* itm  = (const float*)d_in[2];
    const float* encw = (const float*)d_in[3];
    const float* enca = (const float*)d_in[4];
    const float* encb = (const float*)d_in[5];
    const float* bn0g = (const float*)d_in[6];
    const float* bn0b = (const float*)d_in[7];
    const float* g1w  = (const float*)d_in[8];
    const float* g1a  = (const float*)d_in[9];
    const float* g1b  = (const float*)d_in[10];
    const float* b1g  = (const float*)d_in[11];
    const float* b1b  = (const float*)d_in[12];
    const float* g2w  = (const float*)d_in[13];
    const float* g2a  = (const float*)d_in[14];
    const float* g2b  = (const float*)d_in[15];
    const float* b2g  = (const float*)d_in[16];
    const float* b2b  = (const float*)d_in[17];
    const float* decw = (const float*)d_in[18];
    const float* deca = (const float*)d_in[19];
    const float* decb = (const float*)d_in[20];
    float* out = (float*)d_out;

    // ws layout: EXACT round 1 (~103.8 MiB, proven to fit)
    float* ws = (float*)d_ws;
    float* xd = ws;                         //   675840 floats
    float* h  = xd + 675840;                //  8650752
    float* xw = h  + 8650752;               //  8650752
    float* y  = xw + 8650752;               //  8650752
    float* P1 = y  + 8650752;               //   270336
    float* P2 = P1 + 270336;                //   270336
    float* SC = P2 + 270336;                //    16896
    float* SH = SC + 16896;                 //    16896

    const dim3 blk(256);
    const dim3 gS(17, NBG_);

    k_dct<<<B_, blk, 0, stream>>>(x, tm, xd);

    // encoder: gc(dct->hid) fp32 + bn0 + tanh
    k_xw <<<ROWS_/64, blk, 0, stream>>>(xd, encw, xw);
    k_att<<<dim3(B_,2), blk, 0, stream>>>(xw, enca, encb, y);
    k_stats<<<gS, blk, 0, stream>>>(y, P1, P2);
    k_apply<<<gS, blk, 0, stream>>>(y, P1, P2, bn0g, bn0b, nullptr, h);

    for (int s = 0; s < ST_; ++s) {
        // gc1: xw = h@w1 (MFMA); y = att1*xw + b1; stats; bn coefs
        k_mfma<<<ROWS_/64, blk, 0, stream>>>(h, g1w + s*H_*H_, xw,
                                             nullptr, nullptr);
        k_att<<<dim3(B_,2), blk, 0, stream>>>(xw, g1a + s*N_*N_, g1b + s*H_, y);
        k_stats<<<gS, blk, 0, stream>>>(y, P1, P2);
        k_bnfin<<<17, blk, 0, stream>>>(P1, P2, b1g + s*C_, b1b + s*C_, SC, SH);
        // gc2 with fused bn1+tanh in staging: xw = tanh(bn(y)) @ w2 (MFMA)
        k_mfma<<<ROWS_/64, blk, 0, stream>>>(y, g2w + s*H_*H_, xw, SC, SH);
        k_att<<<dim3(B_,2), blk, 0, stream>>>(xw, g2a + s*N_*N_, g2b + s*H_, y);
        k_stats<<<gS, blk, 0, stream>>>(y, P1, P2);
        // h = tanh(bn2(y)) + h
        k_apply<<<gS, blk, 0, stream>>>(y, P1, P2, b2g + s*C_, b2b + s*C_, h, h);
    }

    // decoder + iDCT + splice
    k_dec_xw<<<ROWS_/256, blk, 0, stream>>>(h, decw, y);   // y reused: [ROWS][20]
    k_dec_fin<<<B_, blk, 0, stream>>>(y, deca, decb, xd, itm, x, out);
}

// Round 8
// 1113.889 us; speedup vs baseline: 6.4722x; 1.0625x over previous
//
#include <hip/hip_runtime.h>
#include <math.h>

// Problem dims
#define B_    512
#define T_    125
#define N_    66
#define D_    20
#define H_    256
#define ST_   6
#define THIS_ 25
#define C_    (N_*H_)     // 16896 channels for BN
#define ROWS_ (B_*N_)     // 33792
#define NBG_  16          // batch groups for BN stats
#define BPG_  (B_/NBG_)   // 32
#define EPS_  1e-5f

typedef __attribute__((ext_vector_type(8))) short bf16x8;
typedef __attribute__((ext_vector_type(4))) float f32x4;

__device__ __forceinline__ ushort f2bf(float f) {
    unsigned u = __float_as_uint(f);
    u += 0x7fffu + ((u >> 16) & 1u);       // round-to-nearest-even
    return (ushort)(u >> 16);
}
__device__ __forceinline__ float bf2f(ushort h) {
    return __uint_as_float((unsigned)h << 16);
}

// ---------------------------------------------------------------------------
// Weight convert (NO transpose — pure elementwise): Wb[i] = bf16(W[i])
// ---------------------------------------------------------------------------
__global__ __launch_bounds__(256) void k_wcvt(const float* __restrict__ W,
                                              ushort* __restrict__ Wb,
                                              int nelem) {
    const int idx = (blockIdx.x * 256 + threadIdx.x) * 4;
    if (idx >= nelem) return;
    const float4 v = *(const float4*)(W + idx);
    ushort4 o;
    o.x = f2bf(v.x); o.y = f2bf(v.y); o.z = f2bf(v.z); o.w = f2bf(v.w);
    *(ushort4*)(Wb + idx) = o;
}

// ---------------------------------------------------------------------------
// DCT along time: xd[b][n][d] = sum_t trans[d][t] * x[b][t][n]   (= r7)
// ---------------------------------------------------------------------------
__global__ __launch_bounds__(256) void k_dct(const float* __restrict__ x,
                                             const float* __restrict__ tm,
                                             float* __restrict__ xd) {
    __shared__ float xs[T_*N_];
    __shared__ float tl[D_*T_];
    const int b = blockIdx.x, tid = threadIdx.x;
    const float* xb = x + (size_t)b * T_ * N_;
    for (int i = tid; i < T_*N_; i += 256) xs[i] = xb[i];
    for (int i = tid; i < D_*T_; i += 256) tl[i] = tm[i];
    __syncthreads();
    for (int p = tid; p < N_*D_; p += 256) {
        const int n = p / D_, d = p % D_;
        float acc = 0.f;
        for (int t = 0; t < T_; ++t)
            acc = fmaf(tl[d*T_ + t], xs[t*N_ + n], acc);
        xd[(size_t)b * N_ * D_ + p] = acc;
    }
}

// ---------------------------------------------------------------------------
// Fused encoder GC: per-batch block. Phase 1 (VALU, K=20):
// xw[n][f] = xd[b][n][:] @ encw  -> XL (bf16 LDS).  Phase 2: y[b][n][f] =
// sum_m att[n][m]*XL[m][f] + bias[f].
// ---------------------------------------------------------------------------
__global__ __launch_bounds__(256) void k_genc(const float* __restrict__ xd,
                                              const float* __restrict__ ew,
                                              const float* __restrict__ att,
                                              const float* __restrict__ bias,
                                              float* __restrict__ Y) {
    __shared__ float  xs[N_ * D_];        //  5280 B
    __shared__ float  ws[D_ * H_];        // 20480 B
    __shared__ ushort XL[N_ * H_];        // 33792 B
    const int b = blockIdx.x, tid = threadIdx.x;
    for (int i = tid; i < N_*D_; i += 256) xs[i] = xd[(size_t)b * N_ * D_ + i];
    for (int i = tid; i < D_*H_; i += 256) ws[i] = ew[i];
    __syncthreads();

    const int fq = tid & 63;
    const int ng = __builtin_amdgcn_readfirstlane(tid >> 6);
    const int n0 = ng * 17;

    // phase 1: rows n0..n0+16, cols fq*4..+3
    float4 acc[17];
    #pragma unroll
    for (int i = 0; i < 17; ++i) acc[i] = make_float4(0.f,0.f,0.f,0.f);
    for (int k = 0; k < D_; ++k) {
        const float4 wv = *(const float4*)(ws + k * H_ + fq * 4);
        #pragma unroll
        for (int i = 0; i < 17; ++i) {
            int n = n0 + i; n = n < N_ ? n : N_ - 1;
            const float a = xs[n * D_ + k];
            acc[i].x = fmaf(a, wv.x, acc[i].x);
            acc[i].y = fmaf(a, wv.y, acc[i].y);
            acc[i].z = fmaf(a, wv.z, acc[i].z);
            acc[i].w = fmaf(a, wv.w, acc[i].w);
        }
    }
    #pragma unroll
    for (int i = 0; i < 17; ++i) {
        const int n = n0 + i;
        if (n < N_) {
            ushort4 o;
            o.x = f2bf(acc[i].x); o.y = f2bf(acc[i].y);
            o.z = f2bf(acc[i].z); o.w = f2bf(acc[i].w);
            *(ushort4*)&XL[n * H_ + fq * 4] = o;
        }
    }
    __syncthreads();

    // phase 2: att-mix + bias
    float4 yac[17];
    #pragma unroll
    for (int i = 0; i < 17; ++i) yac[i] = make_float4(0.f,0.f,0.f,0.f);
    for (int m = 0; m < N_; ++m) {
        const ushort4 xv = *(const ushort4*)&XL[m * H_ + fq * 4];
        const float x0 = bf2f(xv.x), x1 = bf2f(xv.y),
                    x2 = bf2f(xv.z), x3 = bf2f(xv.w);
        #pragma unroll
        for (int i = 0; i < 17; ++i) {
            int n = n0 + i; n = n < N_ ? n : N_ - 1;
            const float a = att[n * N_ + m];
            yac[i].x = fmaf(a, x0, yac[i].x);
            yac[i].y = fmaf(a, x1, yac[i].y);
            yac[i].z = fmaf(a, x2, yac[i].z);
            yac[i].w = fmaf(a, x3, yac[i].w);
        }
    }
    const float4 bv = *(const float4*)(bias + fq * 4);
    #pragma unroll
    for (int i = 0; i < 17; ++i) {
        const int n = n0 + i;
        if (n < N_) {
            float4 o = make_float4(yac[i].x + bv.x, yac[i].y + bv.y,
                                   yac[i].z + bv.z, yac[i].w + bv.w);
            *(float4*)(Y + (size_t)b * C_ + n * H_ + fq * 4) = o;
        }
    }
}

// ---------------------------------------------------------------------------
// Fused stage GC: per-batch block (grid 512).  Phase 1 (MFMA, K=256):
// xw = A'[b] @ W  (A' = A or tanh(A*sc+sh), channel = n*256+k), M padded
// 66->80 (5 frags), 4 waves = 64-col strips, BK=32.  W pre-converted bf16
// row-major [k][f] (k_wcvt — no transpose).  Epilogue -> XL bf16 LDS.
// Phase 2: y[b] = att*XL + bias (k_att pattern from LDS).  In-place A=Y ok.
// ---------------------------------------------------------------------------
__global__ __launch_bounds__(256) void k_gc(const float* __restrict__ A,
                                            const ushort* __restrict__ Wb,
                                            const float* __restrict__ att,
                                            const float* __restrict__ bias,
                                            const float* __restrict__ scale,
                                            const float* __restrict__ shift,
                                            float* __restrict__ Y) {
    __shared__ __align__(16) ushort As[80 * 32];    //  5120 B
    __shared__ __align__(16) ushort Bs[H_ * 32];    // 16384 B
    __shared__ __align__(16) ushort XL[N_ * H_];    // 33792 B
    const int b    = blockIdx.x;
    const int tid  = threadIdx.x;
    const int lane = tid & 63;
    const int wc   = tid >> 6;            // wave -> 64-col strip
    const int kq   = lane >> 4;
    const int fr   = lane & 15;

    // A staging slots: slot1 = rows 0..63, slot2 (tid<64) = rows 64..79
    const int ar1 = tid >> 2;
    const int ak  = (tid & 3) * 8;
    const int ar2 = 64 + (tid >> 2);      // valid only for tid < 64

    f32x4 acc[5][4] = {};

    for (int kt = 0; kt < 8; ++kt) {
        const int kb = kt * 32;

        // ---- register prefetch ----
        float av1[8];
        {
            const float* ap = A + ((size_t)b * N_ + ar1) * H_ + kb + ak;
            *(float4*)&av1[0] = *(const float4*)ap;
            *(float4*)&av1[4] = *(const float4*)(ap + 4);
            if (scale) {
                const int cb = ar1 * H_ + kb + ak;
                float sv[8], hv[8];
                *(float4*)&sv[0] = *(const float4*)(scale + cb);
                *(float4*)&sv[4] = *(const float4*)(scale + cb + 4);
                *(float4*)&hv[0] = *(const float4*)(shift + cb);
                *(float4*)&hv[4] = *(const float4*)(shift + cb + 4);
                #pragma unroll
                for (int j = 0; j < 8; ++j)
                    av1[j] = tanhf(fmaf(av1[j], sv[j], hv[j]));
            }
        }
        float av2[8] = {0,0,0,0,0,0,0,0};
        if (tid < 64 && ar2 < N_) {       // rows 64,65 real; 66..79 zero
            const float* ap = A + ((size_t)b * N_ + ar2) * H_ + kb + ak;
            *(float4*)&av2[0] = *(const float4*)ap;
            *(float4*)&av2[4] = *(const float4*)(ap + 4);
            if (scale) {
                const int cb = ar2 * H_ + kb + ak;
                float sv[8], hv[8];
                *(float4*)&sv[0] = *(const float4*)(scale + cb);
                *(float4*)&sv[4] = *(const float4*)(scale + cb + 4);
                *(float4*)&hv[0] = *(const float4*)(shift + cb);
                *(float4*)&hv[4] = *(const float4*)(shift + cb + 4);
                #pragma unroll
                for (int j = 0; j < 8; ++j)
                    av2[j] = tanhf(fmaf(av2[j], sv[j], hv[j]));
            }
        }
        ushort wv[32];                    // Wb[kb+kr][tid], coalesced over tid
        #pragma unroll
        for (int kr = 0; kr < 32; ++kr)
            wv[kr] = Wb[(size_t)(kb + kr) * H_ + tid];

        __syncthreads();                  // prev iteration's LDS reads done
        {
            bf16x8 a8;
            #pragma unroll
            for (int j = 0; j < 8; ++j) a8[j] = (short)f2bf(av1[j]);
            *(bf16x8*)&As[ar1 * 32 + ak] = a8;
        }
        if (tid < 64) {
            bf16x8 a8;
            #pragma unroll
            for (int j = 0; j < 8; ++j) a8[j] = (short)f2bf(av2[j]);
            *(bf16x8*)&As[ar2 * 32 + ak] = a8;
        }
        #pragma unroll
        for (int kr = 0; kr < 32; ++kr)
            Bs[tid * 32 + kr] = wv[kr];
        __syncthreads();                  // tile ready

        bf16x8 a[5], bfr[4];
        #pragma unroll
        for (int m = 0; m < 5; ++m)
            a[m] = *(const bf16x8*)&As[(m * 16 + fr) * 32 + kq * 8];
        #pragma unroll
        for (int n = 0; n < 4; ++n)
            bfr[n] = *(const bf16x8*)&Bs[(wc * 64 + n * 16 + fr) * 32 + kq * 8];
        #pragma unroll
        for (int m = 0; m < 5; ++m)
            #pragma unroll
            for (int n = 0; n < 4; ++n)
                acc[m][n] = __builtin_amdgcn_mfma_f32_16x16x32_bf16(
                                a[m], bfr[n], acc[m][n], 0, 0, 0);
    }

    // epilogue: acc -> XL (bf16).  C/D: col=fr, row=kq*4+j (probe-verified r4/r7)
    #pragma unroll
    for (int m = 0; m < 5; ++m) {
        #pragma unroll
        for (int n = 0; n < 4; ++n) {
            #pragma unroll
            for (int j = 0; j < 4; ++j) {
                const int row = m * 16 + kq * 4 + j;
                if (row < N_)
                    XL[row * H_ + wc * 64 + n * 16 + fr] = f2bf(acc[m][n][j]);
            }
        }
    }
    __syncthreads();

    // phase 2: y[b][n][f] = sum_m att[n][m]*XL[m][f] + bias[f]
    const int fq = lane;
    const int ng = __builtin_amdgcn_readfirstlane(tid >> 6);
    const int n0 = ng * 17;
    float4 yac[17];
    #pragma unroll
    for (int i = 0; i < 17; ++i) yac[i] = make_float4(0.f,0.f,0.f,0.f);
    for (int m = 0; m < N_; ++m) {
        const ushort4 xv = *(const ushort4*)&XL[m * H_ + fq * 4];
        const float x0 = bf2f(xv.x), x1 = bf2f(xv.y),
                    x2 = bf2f(xv.z), x3 = bf2f(xv.w);
        #pragma unroll
        for (int i = 0; i < 17; ++i) {
            int n = n0 + i; n = n < N_ ? n : N_ - 1;
            const float aa = att[n * N_ + m];
            yac[i].x = fmaf(aa, x0, yac[i].x);
            yac[i].y = fmaf(aa, x1, yac[i].y);
            yac[i].z = fmaf(aa, x2, yac[i].z);
            yac[i].w = fmaf(aa, x3, yac[i].w);
        }
    }
    const float4 bv = *(const float4*)(bias + fq * 4);
    #pragma unroll
    for (int i = 0; i < 17; ++i) {
        const int n = n0 + i;
        if (n < N_) {
            float4 o = make_float4(yac[i].x + bv.x, yac[i].y + bv.y,
                                   yac[i].z + bv.z, yac[i].w + bv.w);
            *(float4*)(Y + (size_t)b * C_ + n * H_ + fq * 4) = o;
        }
    }
}

// ---------------------------------------------------------------------------
// BN partial stats over batch group g.   (= r7)
// ---------------------------------------------------------------------------
__global__ __launch_bounds__(256) void k_stats(const float* __restrict__ v,
                                               float* __restrict__ P1,
                                               float* __restrict__ P2) {
    const int c4 = blockIdx.x * 256 + threadIdx.x;
    if (c4 >= C_ / 4) return;
    const int g = blockIdx.y;
    float4 s1 = make_float4(0.f,0.f,0.f,0.f), s2 = make_float4(0.f,0.f,0.f,0.f);
    const float4* vp = (const float4*)v;
    for (int i = 0; i < BPG_; ++i) {
        const int b = g * BPG_ + i;
        const float4 t = vp[(size_t)b * (C_ / 4) + c4];
        s1.x += t.x; s1.y += t.y; s1.z += t.z; s1.w += t.w;
        s2.x = fmaf(t.x, t.x, s2.x); s2.y = fmaf(t.y, t.y, s2.y);
        s2.z = fmaf(t.z, t.z, s2.z); s2.w = fmaf(t.w, t.w, s2.w);
    }
    ((float4*)(P1 + (size_t)g * C_))[c4] = s1;
    ((float4*)(P2 + (size_t)g * C_))[c4] = s2;
}

__device__ __forceinline__ void bn_coef(const float* P1, const float* P2,
                                        const float* gam, const float* bet,
                                        int c4, float4& sc, float4& sh) {
    float4 s1 = make_float4(0.f,0.f,0.f,0.f), s2 = make_float4(0.f,0.f,0.f,0.f);
    for (int g = 0; g < NBG_; ++g) {
        const float4 a = ((const float4*)(P1 + (size_t)g * C_))[c4];
        const float4 b = ((const float4*)(P2 + (size_t)g * C_))[c4];
        s1.x += a.x; s1.y += a.y; s1.z += a.z; s1.w += a.w;
        s2.x += b.x; s2.y += b.y; s2.z += b.z; s2.w += b.w;
    }
    const float inv = 1.f / (float)B_;
    const float4 gm = ((const float4*)gam)[c4];
    const float4 bt = ((const float4*)bet)[c4];
    float mu, var;
    mu = s1.x*inv; var = fmaf(-mu, mu, s2.x*inv); sc.x = gm.x*rsqrtf(var+EPS_); sh.x = bt.x - mu*sc.x;
    mu = s1.y*inv; var = fmaf(-mu, mu, s2.y*inv); sc.y = gm.y*rsqrtf(var+EPS_); sh.y = bt.y - mu*sc.y;
    mu = s1.z*inv; var = fmaf(-mu, mu, s2.z*inv); sc.z = gm.z*rsqrtf(var+EPS_); sh.z = bt.z - mu*sc.z;
    mu = s1.w*inv; var = fmaf(-mu, mu, s2.w*inv); sc.w = gm.w*rsqrtf(var+EPS_); sh.w = bt.w - mu*sc.w;
}

// Finalize BN coefficients into SC/SH.   (= r7)
__global__ __launch_bounds__(256) void k_bnfin(const float* __restrict__ P1,
                                               const float* __restrict__ P2,
                                               const float* __restrict__ gam,
                                               const float* __restrict__ bet,
                                               float* __restrict__ SC,
                                               float* __restrict__ SH) {
    const int c4 = blockIdx.x * 256 + threadIdx.x;
    if (c4 >= C_ / 4) return;
    float4 sc, sh;
    bn_coef(P1, P2, gam, bet, c4, sc, sh);
    ((float4*)SC)[c4] = sc;
    ((float4*)SH)[c4] = sh;
}

// out = tanh(v*sc+sh) (+ res).   (= r7)
__global__ __launch_bounds__(256) void k_apply(const float* __restrict__ v,
                                               const float* __restrict__ P1,
                                               const float* __restrict__ P2,
                                               const float* __restrict__ gam,
                                               const float* __restrict__ bet,
                                               const float* __restrict__ res,
                                               float* __restrict__ out) {
    const int c4 = blockIdx.x * 256 + threadIdx.x;
    if (c4 >= C_ / 4) return;
    const int g = blockIdx.y;
    float4 sc, sh;
    bn_coef(P1, P2, gam, bet, c4, sc, sh);
    const float4* vp = (const float4*)v;
    const float4* rp = (const float4*)res;
    float4* op = (float4*)out;
    for (int i = 0; i < BPG_; ++i) {
        const size_t idx = (size_t)(g * BPG_ + i) * (C_ / 4) + c4;
        const float4 t = vp[idx];
        float4 o;
        o.x = tanhf(fmaf(t.x, sc.x, sh.x));
        o.y = tanhf(fmaf(t.y, sc.y, sh.y));
        o.z = tanhf(fmaf(t.z, sc.z, sh.z));
        o.w = tanhf(fmaf(t.w, sc.w, sh.w));
        if (res) {
            const float4 r = rp[idx];
            o.x += r.x; o.y += r.y; o.z += r.z; o.w += r.w;
        }
        op[idx] = o;
    }
}

// ---------------------------------------------------------------------------
// Fused decoder: per-batch block.  o = h[b]@decw;  od = deca*o + dbias + xd[b];
// out[b] = splice(x[b][:25], iDCT(od)).
// ---------------------------------------------------------------------------
__global__ __launch_bounds__(256) void k_dec(const float* __restrict__ h,
                                             const float* __restrict__ dw,
                                             const float* __restrict__ da,
                                             const float* __restrict__ db,
                                             const float* __restrict__ xd,
                                             const float* __restrict__ itm,
                                             const float* __restrict__ x,
                                             float* __restrict__ out) {
    __shared__ float dwL[H_ * D_];     // 20480 B
    __shared__ float hsL[N_ * 64];     // 16896 B
    __shared__ float oL [N_ * 21];     //  5544 B
    __shared__ float atL[N_ * N_];     // 17424 B
    __shared__ float odL[N_ * 21];     //  5544 B
    __shared__ float itL[T_ * D_];     // 10000 B
    const int b = blockIdx.x, tid = threadIdx.x;

    for (int i = tid; i < H_*D_; i += 256) dwL[i] = dw[i];
    for (int i = tid; i < N_*N_; i += 256) atL[i] = da[i];
    for (int i = tid; i < T_*D_; i += 256) {
        const int t = i / D_, d = i % D_;
        itL[i] = itm[t * T_ + d];
    }

    // phase A: o[n][d] = sum_k h[b][n][k] * dw[k][d]
    // primary slot: n = tid>>2 (0..63), d-quarter dq = tid&3 (5 d's)
    // secondary (tid<8): n = 64+(tid>>2), dq = tid&3
    const int n1 = tid >> 2, dq1 = tid & 3;
    float a1[5] = {0,0,0,0,0};
    float a2[5] = {0,0,0,0,0};
    for (int kc = 0; kc < 4; ++kc) {
        __syncthreads();   // prev hsL reads done (also covers initial staging)
        for (int i = tid; i < N_ * 16; i += 256) {
            const int n = i >> 4, k4 = i & 15;
            *(float4*)&hsL[n * 64 + k4 * 4] =
                *(const float4*)(h + ((size_t)b * N_ + n) * H_ + kc * 64 + k4 * 4);
        }
        __syncthreads();
        for (int kk = 0; kk < 64; ++kk) {
            const float hv = hsL[n1 * 64 + kk];
            const float* wp = &dwL[(kc * 64 + kk) * D_ + dq1 * 5];
            #pragma unroll
            for (int dd = 0; dd < 5; ++dd)
                a1[dd] = fmaf(hv, wp[dd], a1[dd]);
        }
        if (tid < 8) {
            const int n2 = 64 + (tid >> 2), dq2 = tid & 3;
            for (int kk = 0; kk < 64; ++kk) {
                const float hv = hsL[n2 * 64 + kk];
                const float* wp = &dwL[(kc * 64 + kk) * D_ + dq2 * 5];
                #pragma unroll
                for (int dd = 0; dd < 5; ++dd)
                    a2[dd] = fmaf(hv, wp[dd], a2[dd]);
            }
        }
    }
    #pragma unroll
    for (int dd = 0; dd < 5; ++dd) oL[n1 * 21 + dq1 * 5 + dd] = a1[dd];
    if (tid < 8) {
        const int n2 = 64 + (tid >> 2), dq2 = tid & 3;
        #pragma unroll
        for (int dd = 0; dd < 5; ++dd) oL[n2 * 21 + dq2 * 5 + dd] = a2[dd];
    }
    __syncthreads();

    // phase B: od[n][d] = db[d] + xd[b][n][d] + sum_m atL[n][m]*oL[m][d]
    for (int p = tid; p < N_*D_; p += 256) {
        const int n = p / D_, d = p % D_;
        float acc = db[d] + xd[(size_t)b * N_ * D_ + p];
        for (int m = 0; m < N_; ++m)
            acc = fmaf(atL[n * N_ + m], oL[m * 21 + d], acc);
        odL[n * 21 + d] = acc;
    }
    __syncthreads();

    // phase C: iDCT + splice
    const float* xb = x + (size_t)b * T_ * N_;
    float* ob = out + (size_t)b * T_ * N_;
    for (int q = tid; q < T_*N_; q += 256) {
        const int t = q / N_, n = q % N_;
        float o;
        if (t < THIS_) {
            o = xb[q];
        } else {
            o = 0.f;
            for (int d = 0; d < D_; ++d)
                o = fmaf(itL[t * D_ + d], odL[n * 21 + d], o);
        }
        ob[q] = o;
    }
}

// ---------------------------------------------------------------------------
extern "C" void kernel_launch(void* const* d_in, const int* in_sizes, int n_in,
                              void* d_out, int out_size, void* d_ws, size_t ws_size,
                              hipStream_t stream) {
    const float* x    = (const float*)d_in[0];
    const float* tm   = (const float*)d_in[1];
    const float* itm  = (const float*)d_in[2];
    const float* encw = (const float*)d_in[3];
    const float* enca = (const float*)d_in[4];
    const float* encb = (const float*)d_in[5];
    const float* bn0g = (const float*)d_in[6];
    const float* bn0b = (const float*)d_in[7];
    const float* g1w  = (const float*)d_in[8];
    const float* g1a  = (const float*)d_in[9];
    const float* g1b  = (const float*)d_in[10];
    const float* b1g  = (const float*)d_in[11];
    const float* b1b  = (const float*)d_in[12];
    const float* g2w  = (const float*)d_in[13];
    const float* g2a  = (const float*)d_in[14];
    const float* g2b  = (const float*)d_in[15];
    const float* b2g  = (const float*)d_in[16];
    const float* b2b  = (const float*)d_in[17];
    const float* decw = (const float*)d_in[18];
    const float* deca = (const float*)d_in[19];
    const float* decb = (const float*)d_in[20];
    float* out = (float*)d_out;

    // ws layout: EXACT round 1 (~103.8 MiB proven); bf16 weights carved from
    // the now-dead xw slot (34.6 MB free).
    float* ws = (float*)d_ws;
    float* xd = ws;                         //   675840 floats
    float* h  = xd + 675840;                //  8650752
    float* xw = h  + 8650752;               //  8650752  (dead: reused below)
    float* y  = xw + 8650752;               //  8650752
    float* P1 = y  + 8650752;               //   270336
    float* P2 = P1 + 270336;                //   270336
    float* SC = P2 + 270336;                //    16896
    float* SH = SC + 16896;                 //    16896
    ushort* Wb1 = (ushort*)xw;              //   393216 u16 (inside xw slot)
    ushort* Wb2 = Wb1 + 393216;             //   393216 u16

    const dim3 blk(256);
    const dim3 gS(17, NBG_);

    // pre-convert stage weights to bf16 (pure elementwise, no transpose)
    k_wcvt<<<384, blk, 0, stream>>>(g1w, Wb1, ST_*H_*H_);
    k_wcvt<<<384, blk, 0, stream>>>(g2w, Wb2, ST_*H_*H_);

    k_dct<<<B_, blk, 0, stream>>>(x, tm, xd);

    // encoder (fused gc) + bn0 + tanh
    k_genc<<<B_, blk, 0, stream>>>(xd, encw, enca, encb, y);
    k_stats<<<gS, blk, 0, stream>>>(y, P1, P2);
    k_apply<<<gS, blk, 0, stream>>>(y, P1, P2, bn0g, bn0b, nullptr, h);

    for (int s = 0; s < ST_; ++s) {
        // gc1: y = att1*(h@w1) + b1
        k_gc<<<B_, blk, 0, stream>>>(h, Wb1 + s*H_*H_, g1a + s*N_*N_,
                                     g1b + s*H_, nullptr, nullptr, y);
        k_stats<<<gS, blk, 0, stream>>>(y, P1, P2);
        k_bnfin<<<17, blk, 0, stream>>>(P1, P2, b1g + s*C_, b1b + s*C_, SC, SH);
        // gc2: y = att2*(tanh(bn1(y))@w2) + b2   (in-place safe)
        k_gc<<<B_, blk, 0, stream>>>(y, Wb2 + s*H_*H_, g2a + s*N_*N_,
                                     g2b + s*H_, SC, SH, y);
        k_stats<<<gS, blk, 0, stream>>>(y, P1, P2);
        // h = tanh(bn2(y)) + h
        k_apply<<<gS, blk, 0, stream>>>(y, P1, P2, b2g + s*C_, b2b + s*C_, h, h);
    }

    // fused decoder + iDCT + splice
    k_dec<<<B_, blk, 0, stream>>>(h, decw, deca, decb, xd, itm, x, out);
}

// Round 9
// 1110.885 us; speedup vs baseline: 6.4897x; 1.0027x over previous
//
#include <hip/hip_runtime.h>
#include <math.h>

// Problem dims
#define B_    512
#define T_    125
#define N_    66
#define D_    20
#define H_    256
#define ST_   6
#define THIS_ 25
#define C_    (N_*H_)     // 16896 channels for BN
#define ROWS_ (B_*N_)     // 33792
#define NBG_  16          // batch groups for BN stats
#define BPG_  (B_/NBG_)   // 32
#define EPS_  1e-5f

#define BSTR  40          // padded LDS row stride (ushorts) for As/Bs
#define XSTR  260         // padded LDS row stride (ushorts) for XL

typedef __attribute__((ext_vector_type(8))) short bf16x8;
typedef __attribute__((ext_vector_type(4))) float f32x4;

__device__ __forceinline__ ushort f2bf(float f) {
    unsigned u = __float_as_uint(f);
    u += 0x7fffu + ((u >> 16) & 1u);       // round-to-nearest-even
    return (ushort)(u >> 16);
}
__device__ __forceinline__ float bf2f(ushort h) {
    return __uint_as_float((unsigned)h << 16);
}

// ---------------------------------------------------------------------------
// Weight convert (NO transpose — pure elementwise): Wb[i] = bf16(W[i])
// ---------------------------------------------------------------------------
__global__ __launch_bounds__(256) void k_wcvt(const float* __restrict__ W,
                                              ushort* __restrict__ Wb,
                                              int nelem) {
    const int idx = (blockIdx.x * 256 + threadIdx.x) * 4;
    if (idx >= nelem) return;
    const float4 v = *(const float4*)(W + idx);
    ushort4 o;
    o.x = f2bf(v.x); o.y = f2bf(v.y); o.z = f2bf(v.z); o.w = f2bf(v.w);
    *(ushort4*)(Wb + idx) = o;
}

// ---------------------------------------------------------------------------
// DCT along time: xd[b][n][d] = sum_t trans[d][t] * x[b][t][n]
// ---------------------------------------------------------------------------
__global__ __launch_bounds__(256) void k_dct(const float* __restrict__ x,
                                             const float* __restrict__ tm,
                                             float* __restrict__ xd) {
    __shared__ float xs[T_*N_];
    __shared__ float tl[D_*T_];
    const int b = blockIdx.x, tid = threadIdx.x;
    const float* xb = x + (size_t)b * T_ * N_;
    for (int i = tid; i < T_*N_; i += 256) xs[i] = xb[i];
    for (int i = tid; i < D_*T_; i += 256) tl[i] = tm[i];
    __syncthreads();
    for (int p = tid; p < N_*D_; p += 256) {
        const int n = p / D_, d = p % D_;
        float acc = 0.f;
        for (int t = 0; t < T_; ++t)
            acc = fmaf(tl[d*T_ + t], xs[t*N_ + n], acc);
        xd[(size_t)b * N_ * D_ + p] = acc;
    }
}

// ---------------------------------------------------------------------------
// Fused encoder GC: per-batch block; y -> bf16.
// ---------------------------------------------------------------------------
__global__ __launch_bounds__(256) void k_genc(const float* __restrict__ xd,
                                              const float* __restrict__ ew,
                                              const float* __restrict__ att,
                                              const float* __restrict__ bias,
                                              ushort* __restrict__ Ybf) {
    __shared__ float  xs[N_ * D_];
    __shared__ float  ws[D_ * H_];
    __shared__ ushort XL[N_ * XSTR];
    const int b = blockIdx.x, tid = threadIdx.x;
    for (int i = tid; i < N_*D_; i += 256) xs[i] = xd[(size_t)b * N_ * D_ + i];
    for (int i = tid; i < D_*H_; i += 256) ws[i] = ew[i];
    __syncthreads();

    const int fq = tid & 63;
    const int ng = __builtin_amdgcn_readfirstlane(tid >> 6);
    const int n0 = ng * 17;

    float4 acc[17];
    #pragma unroll
    for (int i = 0; i < 17; ++i) acc[i] = make_float4(0.f,0.f,0.f,0.f);
    for (int k = 0; k < D_; ++k) {
        const float4 wv = *(const float4*)(ws + k * H_ + fq * 4);
        #pragma unroll
        for (int i = 0; i < 17; ++i) {
            int n = n0 + i; n = n < N_ ? n : N_ - 1;
            const float a = xs[n * D_ + k];
            acc[i].x = fmaf(a, wv.x, acc[i].x);
            acc[i].y = fmaf(a, wv.y, acc[i].y);
            acc[i].z = fmaf(a, wv.z, acc[i].z);
            acc[i].w = fmaf(a, wv.w, acc[i].w);
        }
    }
    #pragma unroll
    for (int i = 0; i < 17; ++i) {
        const int n = n0 + i;
        if (n < N_) {
            ushort4 o;
            o.x = f2bf(acc[i].x); o.y = f2bf(acc[i].y);
            o.z = f2bf(acc[i].z); o.w = f2bf(acc[i].w);
            *(ushort4*)&XL[n * XSTR + fq * 4] = o;
        }
    }
    __syncthreads();

    float4 yac[17];
    #pragma unroll
    for (int i = 0; i < 17; ++i) yac[i] = make_float4(0.f,0.f,0.f,0.f);
    for (int m = 0; m < N_; ++m) {
        const ushort4 xv = *(const ushort4*)&XL[m * XSTR + fq * 4];
        const float x0 = bf2f(xv.x), x1 = bf2f(xv.y),
                    x2 = bf2f(xv.z), x3 = bf2f(xv.w);
        #pragma unroll
        for (int i = 0; i < 17; ++i) {
            int n = n0 + i; n = n < N_ ? n : N_ - 1;
            const float a = att[n * N_ + m];
            yac[i].x = fmaf(a, x0, yac[i].x);
            yac[i].y = fmaf(a, x1, yac[i].y);
            yac[i].z = fmaf(a, x2, yac[i].z);
            yac[i].w = fmaf(a, x3, yac[i].w);
        }
    }
    const float4 bv = *(const float4*)(bias + fq * 4);
    #pragma unroll
    for (int i = 0; i < 17; ++i) {
        const int n = n0 + i;
        if (n < N_) {
            ushort4 o;
            o.x = f2bf(yac[i].x + bv.x); o.y = f2bf(yac[i].y + bv.y);
            o.z = f2bf(yac[i].z + bv.z); o.w = f2bf(yac[i].w + bv.w);
            *(ushort4*)(Ybf + (size_t)b * C_ + n * H_ + fq * 4) = o;
        }
    }
}

// ---------------------------------------------------------------------------
// Fused stage GC: per-batch block (grid 512).  MFMA phase 1 + att phase 2.
// Input: Af (fp32, gc1) XOR Ab (bf16 + fused tanh(bn) via scale/shift, gc2).
// Output: Ybf (bf16). LDS rows padded (BSTR=40, XSTR=260) -> conflict-free.
// ---------------------------------------------------------------------------
__global__ __launch_bounds__(256) void k_gc(const float* __restrict__ Af,
                                            const ushort* __restrict__ Ab,
                                            const ushort* __restrict__ Wb,
                                            const float* __restrict__ att,
                                            const float* __restrict__ bias,
                                            const float* __restrict__ scale,
                                            const float* __restrict__ shift,
                                            ushort* __restrict__ Ybf) {
    __shared__ __align__(16) ushort As[80 * BSTR];    //  6400 B
    __shared__ __align__(16) ushort Bs[H_ * BSTR];    // 20480 B
    __shared__ __align__(16) ushort XL[N_ * XSTR];    // 34320 B
    const int b    = blockIdx.x;
    const int tid  = threadIdx.x;
    const int lane = tid & 63;
    const int wc   = tid >> 6;            // wave -> 64-col strip
    const int kq   = lane >> 4;
    const int fr   = lane & 15;

    const int ar1 = tid >> 2;             // rows 0..63
    const int ak  = (tid & 3) * 8;
    const int ar2 = 64 + (tid >> 2);      // rows 64..79 (tid<64 only)

    f32x4 acc[5][4] = {};

    for (int kt = 0; kt < 8; ++kt) {
        const int kb = kt * 32;

        // ---- register prefetch: A rows ----
        bf16x8 a81, a82;
        if (Af) {
            float av[8];
            const float* ap = Af + ((size_t)b * N_ + ar1) * H_ + kb + ak;
            *(float4*)&av[0] = *(const float4*)ap;
            *(float4*)&av[4] = *(const float4*)(ap + 4);
            #pragma unroll
            for (int j = 0; j < 8; ++j) a81[j] = (short)f2bf(av[j]);
        } else {
            const bf16x8 raw = *(const bf16x8*)(Ab + ((size_t)b * N_ + ar1) * H_ + kb + ak);
            const int cb = ar1 * H_ + kb + ak;
            float sv[8], hv[8];
            *(float4*)&sv[0] = *(const float4*)(scale + cb);
            *(float4*)&sv[4] = *(const float4*)(scale + cb + 4);
            *(float4*)&hv[0] = *(const float4*)(shift + cb);
            *(float4*)&hv[4] = *(const float4*)(shift + cb + 4);
            #pragma unroll
            for (int j = 0; j < 8; ++j)
                a81[j] = (short)f2bf(tanhf(fmaf(bf2f((ushort)raw[j]), sv[j], hv[j])));
        }
        if (tid < 64) {
            if (ar2 < N_) {
                if (Af) {
                    float av[8];
                    const float* ap = Af + ((size_t)b * N_ + ar2) * H_ + kb + ak;
                    *(float4*)&av[0] = *(const float4*)ap;
                    *(float4*)&av[4] = *(const float4*)(ap + 4);
                    #pragma unroll
                    for (int j = 0; j < 8; ++j) a82[j] = (short)f2bf(av[j]);
                } else {
                    const bf16x8 raw = *(const bf16x8*)(Ab + ((size_t)b * N_ + ar2) * H_ + kb + ak);
                    const int cb = ar2 * H_ + kb + ak;
                    float sv[8], hv[8];
                    *(float4*)&sv[0] = *(const float4*)(scale + cb);
                    *(float4*)&sv[4] = *(const float4*)(scale + cb + 4);
                    *(float4*)&hv[0] = *(const float4*)(shift + cb);
                    *(float4*)&hv[4] = *(const float4*)(shift + cb + 4);
                    #pragma unroll
                    for (int j = 0; j < 8; ++j)
                        a82[j] = (short)f2bf(tanhf(fmaf(bf2f((ushort)raw[j]), sv[j], hv[j])));
                }
            } else {
                #pragma unroll
                for (int j = 0; j < 8; ++j) a82[j] = 0;
            }
        }
        // ---- register prefetch: W rows (coalesced over tid per kr) ----
        ushort wv[32];
        #pragma unroll
        for (int kr = 0; kr < 32; ++kr)
            wv[kr] = Wb[(size_t)(kb + kr) * H_ + tid];

        __syncthreads();                  // prev iteration's LDS reads done
        *(bf16x8*)&As[ar1 * BSTR + ak] = a81;
        if (tid < 64)
            *(bf16x8*)&As[ar2 * BSTR + ak] = a82;
        #pragma unroll
        for (int j = 0; j < 4; ++j) {
            bf16x8 w8;
            #pragma unroll
            for (int e = 0; e < 8; ++e) w8[e] = (short)wv[j * 8 + e];
            *(bf16x8*)&Bs[tid * BSTR + j * 8] = w8;
        }
        __syncthreads();                  // tile ready

        bf16x8 a[5], bfr[4];
        #pragma unroll
        for (int m = 0; m < 5; ++m)
            a[m] = *(const bf16x8*)&As[(m * 16 + fr) * BSTR + kq * 8];
        #pragma unroll
        for (int n = 0; n < 4; ++n)
            bfr[n] = *(const bf16x8*)&Bs[(wc * 64 + n * 16 + fr) * BSTR + kq * 8];
        #pragma unroll
        for (int m = 0; m < 5; ++m)
            #pragma unroll
            for (int n = 0; n < 4; ++n)
                acc[m][n] = __builtin_amdgcn_mfma_f32_16x16x32_bf16(
                                a[m], bfr[n], acc[m][n], 0, 0, 0);
    }

    // epilogue -> XL (bf16).  C/D: col=fr, row=kq*4+j (probe-verified r4/r7)
    #pragma unroll
    for (int m = 0; m < 5; ++m) {
        #pragma unroll
        for (int n = 0; n < 4; ++n) {
            #pragma unroll
            for (int j = 0; j < 4; ++j) {
                const int row = m * 16 + kq * 4 + j;
                if (row < N_)
                    XL[row * XSTR + wc * 64 + n * 16 + fr] = f2bf(acc[m][n][j]);
            }
        }
    }
    __syncthreads();

    // phase 2: y[b][n][f] = sum_m att[n][m]*XL[m][f] + bias[f]  -> bf16
    const int fq = lane;
    const int ng = __builtin_amdgcn_readfirstlane(tid >> 6);
    const int n0 = ng * 17;
    float4 yac[17];
    #pragma unroll
    for (int i = 0; i < 17; ++i) yac[i] = make_float4(0.f,0.f,0.f,0.f);
    for (int m = 0; m < N_; ++m) {
        const ushort4 xv = *(const ushort4*)&XL[m * XSTR + fq * 4];
        const float x0 = bf2f(xv.x), x1 = bf2f(xv.y),
                    x2 = bf2f(xv.z), x3 = bf2f(xv.w);
        #pragma unroll
        for (int i = 0; i < 17; ++i) {
            int n = n0 + i; n = n < N_ ? n : N_ - 1;
            const float aa = att[n * N_ + m];
            yac[i].x = fmaf(aa, x0, yac[i].x);
            yac[i].y = fmaf(aa, x1, yac[i].y);
            yac[i].z = fmaf(aa, x2, yac[i].z);
            yac[i].w = fmaf(aa, x3, yac[i].w);
        }
    }
    const float4 bv = *(const float4*)(bias + fq * 4);
    #pragma unroll
    for (int i = 0; i < 17; ++i) {
        const int n = n0 + i;
        if (n < N_) {
            ushort4 o;
            o.x = f2bf(yac[i].x + bv.x); o.y = f2bf(yac[i].y + bv.y);
            o.z = f2bf(yac[i].z + bv.z); o.w = f2bf(yac[i].w + bv.w);
            *(ushort4*)(Ybf + (size_t)b * C_ + n * H_ + fq * 4) = o;
        }
    }
}

// ---------------------------------------------------------------------------
// BN partial stats over batch group g (bf16 input).
// ---------------------------------------------------------------------------
__global__ __launch_bounds__(256) void k_stats(const ushort* __restrict__ v,
                                               float* __restrict__ P1,
                                               float* __restrict__ P2) {
    const int c4 = blockIdx.x * 256 + threadIdx.x;
    if (c4 >= C_ / 4) return;
    const int g = blockIdx.y;
    float4 s1 = make_float4(0.f,0.f,0.f,0.f), s2 = make_float4(0.f,0.f,0.f,0.f);
    const ushort4* vp = (const ushort4*)v;
    for (int i = 0; i < BPG_; ++i) {
        const int b = g * BPG_ + i;
        const ushort4 t4 = vp[(size_t)b * (C_ / 4) + c4];
        const float tx = bf2f(t4.x), ty = bf2f(t4.y),
                    tz = bf2f(t4.z), tw = bf2f(t4.w);
        s1.x += tx; s1.y += ty; s1.z += tz; s1.w += tw;
        s2.x = fmaf(tx, tx, s2.x); s2.y = fmaf(ty, ty, s2.y);
        s2.z = fmaf(tz, tz, s2.z); s2.w = fmaf(tw, tw, s2.w);
    }
    ((float4*)(P1 + (size_t)g * C_))[c4] = s1;
    ((float4*)(P2 + (size_t)g * C_))[c4] = s2;
}

__device__ __forceinline__ void bn_coef(const float* P1, const float* P2,
                                        const float* gam, const float* bet,
                                        int c4, float4& sc, float4& sh) {
    float4 s1 = make_float4(0.f,0.f,0.f,0.f), s2 = make_float4(0.f,0.f,0.f,0.f);
    for (int g = 0; g < NBG_; ++g) {
        const float4 a = ((const float4*)(P1 + (size_t)g * C_))[c4];
        const float4 b = ((const float4*)(P2 + (size_t)g * C_))[c4];
        s1.x += a.x; s1.y += a.y; s1.z += a.z; s1.w += a.w;
        s2.x += b.x; s2.y += b.y; s2.z += b.z; s2.w += b.w;
    }
    const float inv = 1.f / (float)B_;
    const float4 gm = ((const float4*)gam)[c4];
    const float4 bt = ((const float4*)bet)[c4];
    float mu, var;
    mu = s1.x*inv; var = fmaf(-mu, mu, s2.x*inv); sc.x = gm.x*rsqrtf(var+EPS_); sh.x = bt.x - mu*sc.x;
    mu = s1.y*inv; var = fmaf(-mu, mu, s2.y*inv); sc.y = gm.y*rsqrtf(var+EPS_); sh.y = bt.y - mu*sc.y;
    mu = s1.z*inv; var = fmaf(-mu, mu, s2.z*inv); sc.z = gm.z*rsqrtf(var+EPS_); sh.z = bt.z - mu*sc.z;
    mu = s1.w*inv; var = fmaf(-mu, mu, s2.w*inv); sc.w = gm.w*rsqrtf(var+EPS_); sh.w = bt.w - mu*sc.w;
}

// Finalize BN coefficients into SC/SH.
__global__ __launch_bounds__(256) void k_bnfin(const float* __restrict__ P1,
                                               const float* __restrict__ P2,
                                               const float* __restrict__ gam,
                                               const float* __restrict__ bet,
                                               float* __restrict__ SC,
                                               float* __restrict__ SH) {
    const int c4 = blockIdx.x * 256 + threadIdx.x;
    if (c4 >= C_ / 4) return;
    float4 sc, sh;
    bn_coef(P1, P2, gam, bet, c4, sc, sh);
    ((float4*)SC)[c4] = sc;
    ((float4*)SH)[c4] = sh;
}

// out = tanh(v*sc+sh) (+ res).  v is bf16; res/out fp32.
__global__ __launch_bounds__(256) void k_apply(const ushort* __restrict__ v,
                                               const float* __restrict__ P1,
                                               const float* __restrict__ P2,
                                               const float* __restrict__ gam,
                                               const float* __restrict__ bet,
                                               const float* __restrict__ res,
                                               float* __restrict__ out) {
    const int c4 = blockIdx.x * 256 + threadIdx.x;
    if (c4 >= C_ / 4) return;
    const int g = blockIdx.y;
    float4 sc, sh;
    bn_coef(P1, P2, gam, bet, c4, sc, sh);
    const ushort4* vp = (const ushort4*)v;
    const float4* rp = (const float4*)res;
    float4* op = (float4*)out;
    for (int i = 0; i < BPG_; ++i) {
        const size_t idx = (size_t)(g * BPG_ + i) * (C_ / 4) + c4;
        const ushort4 t4 = vp[idx];
        float4 o;
        o.x = tanhf(fmaf(bf2f(t4.x), sc.x, sh.x));
        o.y = tanhf(fmaf(bf2f(t4.y), sc.y, sh.y));
        o.z = tanhf(fmaf(bf2f(t4.z), sc.z, sh.z));
        o.w = tanhf(fmaf(bf2f(t4.w), sc.w, sh.w));
        if (res) {
            const float4 r = rp[idx];
            o.x += r.x; o.y += r.y; o.z += r.z; o.w += r.w;
        }
        op[idx] = o;
    }
}

// ---------------------------------------------------------------------------
// Fused decoder: per-batch block (hsL padded stride 68 -> conflict-free).
// ---------------------------------------------------------------------------
__global__ __launch_bounds__(256) void k_dec(const float* __restrict__ h,
                                             const float* __restrict__ dw,
                                             const float* __restrict__ da,
                                             const float* __restrict__ db,
                                             const float* __restrict__ xd,
                                             const float* __restrict__ itm,
                                             const float* __restrict__ x,
                                             float* __restrict__ out) {
    __shared__ float dwL[H_ * D_];     // 20480 B
    __shared__ float hsL[N_ * 68];     // 17952 B
    __shared__ float oL [N_ * 21];     //  5544 B
    __shared__ float atL[N_ * N_];     // 17424 B
    __shared__ float odL[N_ * 21];     //  5544 B
    __shared__ float itL[T_ * D_];     // 10000 B
    const int b = blockIdx.x, tid = threadIdx.x;

    for (int i = tid; i < H_*D_; i += 256) dwL[i] = dw[i];
    for (int i = tid; i < N_*N_; i += 256) atL[i] = da[i];
    for (int i = tid; i < T_*D_; i += 256) {
        const int t = i / D_, d = i % D_;
        itL[i] = itm[t * T_ + d];
    }

    const int n1 = tid >> 2, dq1 = tid & 3;
    float a1[5] = {0,0,0,0,0};
    float a2[5] = {0,0,0,0,0};
    for (int kc = 0; kc < 4; ++kc) {
        __syncthreads();   // prev hsL reads done (also covers initial staging)
        for (int i = tid; i < N_ * 16; i += 256) {
            const int n = i >> 4, k4 = i & 15;
            *(float4*)&hsL[n * 68 + k4 * 4] =
                *(const float4*)(h + ((size_t)b * N_ + n) * H_ + kc * 64 + k4 * 4);
        }
        __syncthreads();
        for (int kk = 0; kk < 64; ++kk) {
            const float hv = hsL[n1 * 68 + kk];
            const float* wp = &dwL[(kc * 64 + kk) * D_ + dq1 * 5];
            #pragma unroll
            for (int dd = 0; dd < 5; ++dd)
                a1[dd] = fmaf(hv, wp[dd], a1[dd]);
        }
        if (tid < 8) {
            const int n2 = 64 + (tid >> 2), dq2 = tid & 3;
            for (int kk = 0; kk < 64; ++kk) {
                const float hv = hsL[n2 * 68 + kk];
                const float* wp = &dwL[(kc * 64 + kk) * D_ + dq2 * 5];
                #pragma unroll
                for (int dd = 0; dd < 5; ++dd)
                    a2[dd] = fmaf(hv, wp[dd], a2[dd]);
            }
        }
    }
    #pragma unroll
    for (int dd = 0; dd < 5; ++dd) oL[n1 * 21 + dq1 * 5 + dd] = a1[dd];
    if (tid < 8) {
        const int n2 = 64 + (tid >> 2), dq2 = tid & 3;
        #pragma unroll
        for (int dd = 0; dd < 5; ++dd) oL[n2 * 21 + dq2 * 5 + dd] = a2[dd];
    }
    __syncthreads();

    for (int p = tid; p < N_*D_; p += 256) {
        const int n = p / D_, d = p % D_;
        float acc = db[d] + xd[(size_t)b * N_ * D_ + p];
        for (int m = 0; m < N_; ++m)
            acc = fmaf(atL[n * N_ + m], oL[m * 21 + d], acc);
        odL[n * 21 + d] = acc;
    }
    __syncthreads();

    const float* xb = x + (size_t)b * T_ * N_;
    float* ob = out + (size_t)b * T_ * N_;
    for (int q = tid; q < T_*N_; q += 256) {
        const int t = q / N_, n = q % N_;
        float o;
        if (t < THIS_) {
            o = xb[q];
        } else {
            o = 0.f;
            for (int d = 0; d < D_; ++d)
                o = fmaf(itL[t * D_ + d], odL[n * 21 + d], o);
        }
        ob[q] = o;
    }
}

// ---------------------------------------------------------------------------
extern "C" void kernel_launch(void* const* d_in, const int* in_sizes, int n_in,
                              void* d_out, int out_size, void* d_ws, size_t ws_size,
                              hipStream_t stream) {
    const float* x    = (const float*)d_in[0];
    const float* tm   = (const float*)d_in[1];
    const float* itm  = (const float*)d_in[2];
    const float* encw = (const float*)d_in[3];
    const float* enca = (const float*)d_in[4];
    const float* encb = (const float*)d_in[5];
    const float* bn0g = (const float*)d_in[6];
    const float* bn0b = (const float*)d_in[7];
    const float* g1w  = (const float*)d_in[8];
    const float* g1a  = (const float*)d_in[9];
    const float* g1b  = (const float*)d_in[10];
    const float* b1g  = (const float*)d_in[11];
    const float* b1b  = (const float*)d_in[12];
    const float* g2w  = (const float*)d_in[13];
    const float* g2a  = (const float*)d_in[14];
    const float* g2b  = (const float*)d_in[15];
    const float* b2g  = (const float*)d_in[16];
    const float* b2b  = (const float*)d_in[17];
    const float* decw = (const float*)d_in[18];
    const float* deca = (const float*)d_in[19];
    const float* decb = (const float*)d_in[20];
    float* out = (float*)d_out;

    // ws layout (round-1 footprint, proven)
    float* ws = (float*)d_ws;
    float* xd = ws;                         //   675840 floats
    float* h  = xd + 675840;                //  8650752
    float* slotA = h + 8650752;             //  8650752 (bf16 buffers)
    float* slotB = slotA + 8650752;         //  8650752 (dead)
    float* P1 = slotB + 8650752;            //   270336
    float* P2 = P1 + 270336;                //   270336
    float* SC = P2 + 270336;                //    16896
    float* SH = SC + 16896;                 //    16896
    ushort* Wb1 = (ushort*)slotA;           //   393216 u16
    ushort* Wb2 = Wb1 + 393216;             //   393216 u16
    ushort* ybf = Wb2 + 393216;             //  8650752 u16

    const dim3 blk(256);
    const dim3 gS(17, NBG_);

    // pre-convert stage weights to bf16 (pure elementwise, no transpose)
    k_wcvt<<<384, blk, 0, stream>>>(g1w, Wb1, ST_*H_*H_);
    k_wcvt<<<384, blk, 0, stream>>>(g2w, Wb2, ST_*H_*H_);

    k_dct<<<B_, blk, 0, stream>>>(x, tm, xd);

    // encoder (fused gc) + bn0 + tanh
    k_genc<<<B_, blk, 0, stream>>>(xd, encw, enca, encb, ybf);
    k_stats<<<gS, blk, 0, stream>>>(ybf, P1, P2);
    k_apply<<<gS, blk, 0, stream>>>(ybf, P1, P2, bn0g, bn0b, nullptr, h);

    for (int s = 0; s < ST_; ++s) {
        // gc1: ybf = att1*(h@w1) + b1
        k_gc<<<B_, blk, 0, stream>>>(h, nullptr, Wb1 + s*H_*H_, g1a + s*N_*N_,
                                     g1b + s*H_, nullptr, nullptr, ybf);
        k_stats<<<gS, blk, 0, stream>>>(ybf, P1, P2);
        k_bnfin<<<17, blk, 0, stream>>>(P1, P2, b1g + s*C_, b1b + s*C_, SC, SH);
        // gc2: ybf = att2*(tanh(bn1(ybf))@w2) + b2   (in-place safe)
        k_gc<<<B_, blk, 0, stream>>>(nullptr, ybf, Wb2 + s*H_*H_, g2a + s*N_*N_,
                                     g2b + s*H_, SC, SH, ybf);
        k_stats<<<gS, blk, 0, stream>>>(ybf, P1, P2);
        // h = tanh(bn2(ybf)) + h
        k_apply<<<gS, blk, 0, stream>>>(ybf, P1, P2, b2g + s*C_, b2b + s*C_, h, h);
    }

    // fused decoder + iDCT + splice
    k_dec<<<B_, blk, 0, stream>>>(h, decw, deca, decb, xd, itm, x, out);
}

// Round 10
// 1092.327 us; speedup vs baseline: 6.6000x; 1.0170x over previous
//
#include <hip/hip_runtime.h>
#include <math.h>

// Problem dims
#define B_    512
#define T_    125
#define N_    66
#define D_    20
#define H_    256
#define ST_   6
#define THIS_ 25
#define C_    (N_*H_)     // 16896 channels for BN
#define ROWS_ (B_*N_)     // 33792
#define NBG_  16          // batch groups for BN stats
#define BPG_  (B_/NBG_)   // 32
#define EPS_  1e-5f

#define BSTR  40          // padded LDS row stride (ushorts) for As/Bs
#define XSTR  260         // padded LDS row stride (ushorts) for XL

typedef __attribute__((ext_vector_type(8))) short bf16x8;
typedef __attribute__((ext_vector_type(4))) float f32x4;

__device__ __forceinline__ ushort f2bf(float f) {
    unsigned u = __float_as_uint(f);
    u += 0x7fffu + ((u >> 16) & 1u);       // round-to-nearest-even
    return (ushort)(u >> 16);
}
__device__ __forceinline__ float bf2f(ushort h) {
    return __uint_as_float((unsigned)h << 16);
}

// ---------------------------------------------------------------------------
// Weight transpose+convert: WT[s][f][k] = bf16(W[s][k][f]).  grid (4,4,ST).
// LDS tile 64x65 (padded, conflict-free); reads and writes fully coalesced.
// ---------------------------------------------------------------------------
__global__ __launch_bounds__(256) void k_wtrans(const float* __restrict__ W,
                                                ushort* __restrict__ WT) {
    __shared__ ushort t[64][65];
    const int s = blockIdx.z;
    const int kb = blockIdx.x * 64, fb = blockIdx.y * 64;
    const int tid = threadIdx.x;
    const int c = tid & 63;
    const int r4 = tid >> 6;
    for (int rr = 0; rr < 64; rr += 4) {
        const int r = rr + r4;     // k-row
        t[r][c] = f2bf(W[(size_t)s * 65536 + (size_t)(kb + r) * 256 + fb + c]);
    }
    __syncthreads();
    for (int rr = 0; rr < 64; rr += 4) {
        const int f = rr + r4;     // f-row of WT
        WT[(size_t)s * 65536 + (size_t)(fb + f) * 256 + kb + c] = t[c][f];
    }
}

// ---------------------------------------------------------------------------
// DCT along time: xd[b][n][d] = sum_t trans[d][t] * x[b][t][n]
// ---------------------------------------------------------------------------
__global__ __launch_bounds__(256) void k_dct(const float* __restrict__ x,
                                             const float* __restrict__ tm,
                                             float* __restrict__ xd) {
    __shared__ float xs[T_*N_];
    __shared__ float tl[D_*T_];
    const int b = blockIdx.x, tid = threadIdx.x;
    const float* xb = x + (size_t)b * T_ * N_;
    for (int i = tid; i < T_*N_; i += 256) xs[i] = xb[i];
    for (int i = tid; i < D_*T_; i += 256) tl[i] = tm[i];
    __syncthreads();
    for (int p = tid; p < N_*D_; p += 256) {
        const int n = p / D_, d = p % D_;
        float acc = 0.f;
        for (int t = 0; t < T_; ++t)
            acc = fmaf(tl[d*T_ + t], xs[t*N_ + n], acc);
        xd[(size_t)b * N_ * D_ + p] = acc;
    }
}

// ---------------------------------------------------------------------------
// Fused encoder GC: per-batch block; y -> bf16.
// ---------------------------------------------------------------------------
__global__ __launch_bounds__(256) void k_genc(const float* __restrict__ xd,
                                              const float* __restrict__ ew,
                                              const float* __restrict__ att,
                                              const float* __restrict__ bias,
                                              ushort* __restrict__ Ybf) {
    __shared__ float  xs[N_ * D_];
    __shared__ float  ws[D_ * H_];
    __shared__ ushort XL[N_ * XSTR];
    const int b = blockIdx.x, tid = threadIdx.x;
    for (int i = tid; i < N_*D_; i += 256) xs[i] = xd[(size_t)b * N_ * D_ + i];
    for (int i = tid; i < D_*H_; i += 256) ws[i] = ew[i];
    __syncthreads();

    const int fq = tid & 63;
    const int ng = __builtin_amdgcn_readfirstlane(tid >> 6);
    const int n0 = ng * 17;

    float4 acc[17];
    #pragma unroll
    for (int i = 0; i < 17; ++i) acc[i] = make_float4(0.f,0.f,0.f,0.f);
    for (int k = 0; k < D_; ++k) {
        const float4 wv = *(const float4*)(ws + k * H_ + fq * 4);
        #pragma unroll
        for (int i = 0; i < 17; ++i) {
            int n = n0 + i; n = n < N_ ? n : N_ - 1;
            const float a = xs[n * D_ + k];
            acc[i].x = fmaf(a, wv.x, acc[i].x);
            acc[i].y = fmaf(a, wv.y, acc[i].y);
            acc[i].z = fmaf(a, wv.z, acc[i].z);
            acc[i].w = fmaf(a, wv.w, acc[i].w);
        }
    }
    #pragma unroll
    for (int i = 0; i < 17; ++i) {
        const int n = n0 + i;
        if (n < N_) {
            ushort4 o;
            o.x = f2bf(acc[i].x); o.y = f2bf(acc[i].y);
            o.z = f2bf(acc[i].z); o.w = f2bf(acc[i].w);
            *(ushort4*)&XL[n * XSTR + fq * 4] = o;
        }
    }
    __syncthreads();

    float4 yac[17];
    #pragma unroll
    for (int i = 0; i < 17; ++i) yac[i] = make_float4(0.f,0.f,0.f,0.f);
    for (int m = 0; m < N_; ++m) {
        const ushort4 xv = *(const ushort4*)&XL[m * XSTR + fq * 4];
        const float x0 = bf2f(xv.x), x1 = bf2f(xv.y),
                    x2 = bf2f(xv.z), x3 = bf2f(xv.w);
        #pragma unroll
        for (int i = 0; i < 17; ++i) {
            int n = n0 + i; n = n < N_ ? n : N_ - 1;
            const float a = att[n * N_ + m];
            yac[i].x = fmaf(a, x0, yac[i].x);
            yac[i].y = fmaf(a, x1, yac[i].y);
            yac[i].z = fmaf(a, x2, yac[i].z);
            yac[i].w = fmaf(a, x3, yac[i].w);
        }
    }
    const float4 bv = *(const float4*)(bias + fq * 4);
    #pragma unroll
    for (int i = 0; i < 17; ++i) {
        const int n = n0 + i;
        if (n < N_) {
            ushort4 o;
            o.x = f2bf(yac[i].x + bv.x); o.y = f2bf(yac[i].y + bv.y);
            o.z = f2bf(yac[i].z + bv.z); o.w = f2bf(yac[i].w + bv.w);
            *(ushort4*)(Ybf + (size_t)b * C_ + n * H_ + fq * 4) = o;
        }
    }
}

// ---------------------------------------------------------------------------
// Fused stage GC: per-batch block (grid 512).  MFMA phase 1 + att phase 2.
// Input: Af (fp32, gc1) XOR Ab (bf16 + fused tanh(bn), gc2).  Weight: WT
// (pre-transposed bf16, WT[f][k] = W[k][f]) -> B staging is 4x vectorized
// bf16x8 loads + ds_write_b128 per thread per k-step (was 32 scalar loads).
// ---------------------------------------------------------------------------
__global__ __launch_bounds__(256) void k_gc(const float* __restrict__ Af,
                                            const ushort* __restrict__ Ab,
                                            const ushort* __restrict__ WT,
                                            const float* __restrict__ att,
                                            const float* __restrict__ bias,
                                            const float* __restrict__ scale,
                                            const float* __restrict__ shift,
                                            ushort* __restrict__ Ybf) {
    __shared__ __align__(16) ushort As[80 * BSTR];    //  6400 B
    __shared__ __align__(16) ushort Bs[H_ * BSTR];    // 20480 B
    __shared__ __align__(16) ushort XL[N_ * XSTR];    // 34320 B
    const int b    = blockIdx.x;
    const int tid  = threadIdx.x;
    const int lane = tid & 63;
    const int wc   = tid >> 6;            // wave -> 64-col strip
    const int kq   = lane >> 4;
    const int fr   = lane & 15;

    const int ar1 = tid >> 2;             // rows 0..63
    const int ak  = (tid & 3) * 8;
    const int ar2 = 64 + (tid >> 2);      // rows 64..79 (tid<64 only)
    const int br  = tid >> 2;             // B rows br + 64*j
    const int bk  = (tid & 3) * 8;

    f32x4 acc[5][4] = {};

    for (int kt = 0; kt < 8; ++kt) {
        const int kb = kt * 32;

        // ---- register prefetch: A rows ----
        bf16x8 a81, a82;
        if (Af) {
            float av[8];
            const float* ap = Af + ((size_t)b * N_ + ar1) * H_ + kb + ak;
            *(float4*)&av[0] = *(const float4*)ap;
            *(float4*)&av[4] = *(const float4*)(ap + 4);
            #pragma unroll
            for (int j = 0; j < 8; ++j) a81[j] = (short)f2bf(av[j]);
        } else {
            const bf16x8 raw = *(const bf16x8*)(Ab + ((size_t)b * N_ + ar1) * H_ + kb + ak);
            const int cb = ar1 * H_ + kb + ak;
            float sv[8], hv[8];
            *(float4*)&sv[0] = *(const float4*)(scale + cb);
            *(float4*)&sv[4] = *(const float4*)(scale + cb + 4);
            *(float4*)&hv[0] = *(const float4*)(shift + cb);
            *(float4*)&hv[4] = *(const float4*)(shift + cb + 4);
            #pragma unroll
            for (int j = 0; j < 8; ++j)
                a81[j] = (short)f2bf(tanhf(fmaf(bf2f((ushort)raw[j]), sv[j], hv[j])));
        }
        if (tid < 64) {
            if (ar2 < N_) {
                if (Af) {
                    float av[8];
                    const float* ap = Af + ((size_t)b * N_ + ar2) * H_ + kb + ak;
                    *(float4*)&av[0] = *(const float4*)ap;
                    *(float4*)&av[4] = *(const float4*)(ap + 4);
                    #pragma unroll
                    for (int j = 0; j < 8; ++j) a82[j] = (short)f2bf(av[j]);
                } else {
                    const bf16x8 raw = *(const bf16x8*)(Ab + ((size_t)b * N_ + ar2) * H_ + kb + ak);
                    const int cb = ar2 * H_ + kb + ak;
                    float sv[8], hv[8];
                    *(float4*)&sv[0] = *(const float4*)(scale + cb);
                    *(float4*)&sv[4] = *(const float4*)(scale + cb + 4);
                    *(float4*)&hv[0] = *(const float4*)(shift + cb);
                    *(float4*)&hv[4] = *(const float4*)(shift + cb + 4);
                    #pragma unroll
                    for (int j = 0; j < 8; ++j)
                        a82[j] = (short)f2bf(tanhf(fmaf(bf2f((ushort)raw[j]), sv[j], hv[j])));
                }
            } else {
                #pragma unroll
                for (int j = 0; j < 8; ++j) a82[j] = 0;
            }
        }
        // ---- register prefetch: B rows from WT (vectorized, coalesced) ----
        bf16x8 w8[4];
        #pragma unroll
        for (int j = 0; j < 4; ++j)
            w8[j] = *(const bf16x8*)(WT + (size_t)(j * 64 + br) * H_ + kb + bk);

        __syncthreads();                  // prev iteration's LDS reads done
        *(bf16x8*)&As[ar1 * BSTR + ak] = a81;
        if (tid < 64)
            *(bf16x8*)&As[ar2 * BSTR + ak] = a82;
        #pragma unroll
        for (int j = 0; j < 4; ++j)
            *(bf16x8*)&Bs[(j * 64 + br) * BSTR + bk] = w8[j];
        __syncthreads();                  // tile ready

        bf16x8 a[5], bfr[4];
        #pragma unroll
        for (int m = 0; m < 5; ++m)
            a[m] = *(const bf16x8*)&As[(m * 16 + fr) * BSTR + kq * 8];
        #pragma unroll
        for (int n = 0; n < 4; ++n)
            bfr[n] = *(const bf16x8*)&Bs[(wc * 64 + n * 16 + fr) * BSTR + kq * 8];
        #pragma unroll
        for (int m = 0; m < 5; ++m)
            #pragma unroll
            for (int n = 0; n < 4; ++n)
                acc[m][n] = __builtin_amdgcn_mfma_f32_16x16x32_bf16(
                                a[m], bfr[n], acc[m][n], 0, 0, 0);
    }

    // epilogue -> XL (bf16).  C/D: col=fr, row=kq*4+j (probe-verified)
    #pragma unroll
    for (int m = 0; m < 5; ++m) {
        #pragma unroll
        for (int n = 0; n < 4; ++n) {
            #pragma unroll
            for (int j = 0; j < 4; ++j) {
                const int row = m * 16 + kq * 4 + j;
                if (row < N_)
                    XL[row * XSTR + wc * 64 + n * 16 + fr] = f2bf(acc[m][n][j]);
            }
        }
    }
    __syncthreads();

    // phase 2: y[b][n][f] = sum_m att[n][m]*XL[m][f] + bias[f]  -> bf16
    const int fq = lane;
    const int ng = __builtin_amdgcn_readfirstlane(tid >> 6);
    const int n0 = ng * 17;
    float4 yac[17];
    #pragma unroll
    for (int i = 0; i < 17; ++i) yac[i] = make_float4(0.f,0.f,0.f,0.f);
    for (int m = 0; m < N_; ++m) {
        const ushort4 xv = *(const ushort4*)&XL[m * XSTR + fq * 4];
        const float x0 = bf2f(xv.x), x1 = bf2f(xv.y),
                    x2 = bf2f(xv.z), x3 = bf2f(xv.w);
        #pragma unroll
        for (int i = 0; i < 17; ++i) {
            int n = n0 + i; n = n < N_ ? n : N_ - 1;
            const float aa = att[n * N_ + m];
            yac[i].x = fmaf(aa, x0, yac[i].x);
            yac[i].y = fmaf(aa, x1, yac[i].y);
            yac[i].z = fmaf(aa, x2, yac[i].z);
            yac[i].w = fmaf(aa, x3, yac[i].w);
        }
    }
    const float4 bv = *(const float4*)(bias + fq * 4);
    #pragma unroll
    for (int i = 0; i < 17; ++i) {
        const int n = n0 + i;
        if (n < N_) {
            ushort4 o;
            o.x = f2bf(yac[i].x + bv.x); o.y = f2bf(yac[i].y + bv.y);
            o.z = f2bf(yac[i].z + bv.z); o.w = f2bf(yac[i].w + bv.w);
            *(ushort4*)(Ybf + (size_t)b * C_ + n * H_ + fq * 4) = o;
        }
    }
}

// ---------------------------------------------------------------------------
// BN partial stats over batch group g (bf16 input).
// ---------------------------------------------------------------------------
__global__ __launch_bounds__(256) void k_stats(const ushort* __restrict__ v,
                                               float* __restrict__ P1,
                                               float* __restrict__ P2) {
    const int c4 = blockIdx.x * 256 + threadIdx.x;
    if (c4 >= C_ / 4) return;
    const int g = blockIdx.y;
    float4 s1 = make_float4(0.f,0.f,0.f,0.f), s2 = make_float4(0.f,0.f,0.f,0.f);
    const ushort4* vp = (const ushort4*)v;
    for (int i = 0; i < BPG_; ++i) {
        const int b = g * BPG_ + i;
        const ushort4 t4 = vp[(size_t)b * (C_ / 4) + c4];
        const float tx = bf2f(t4.x), ty = bf2f(t4.y),
                    tz = bf2f(t4.z), tw = bf2f(t4.w);
        s1.x += tx; s1.y += ty; s1.z += tz; s1.w += tw;
        s2.x = fmaf(tx, tx, s2.x); s2.y = fmaf(ty, ty, s2.y);
        s2.z = fmaf(tz, tz, s2.z); s2.w = fmaf(tw, tw, s2.w);
    }
    ((float4*)(P1 + (size_t)g * C_))[c4] = s1;
    ((float4*)(P2 + (size_t)g * C_))[c4] = s2;
}

__device__ __forceinline__ void bn_coef(const float* P1, const float* P2,
                                        const float* gam, const float* bet,
                                        int c4, float4& sc, float4& sh) {
    float4 s1 = make_float4(0.f,0.f,0.f,0.f), s2 = make_float4(0.f,0.f,0.f,0.f);
    for (int g = 0; g < NBG_; ++g) {
        const float4 a = ((const float4*)(P1 + (size_t)g * C_))[c4];
        const float4 b = ((const float4*)(P2 + (size_t)g * C_))[c4];
        s1.x += a.x; s1.y += a.y; s1.z += a.z; s1.w += a.w;
        s2.x += b.x; s2.y += b.y; s2.z += b.z; s2.w += b.w;
    }
    const float inv = 1.f / (float)B_;
    const float4 gm = ((const float4*)gam)[c4];
    const float4 bt = ((const float4*)bet)[c4];
    float mu, var;
    mu = s1.x*inv; var = fmaf(-mu, mu, s2.x*inv); sc.x = gm.x*rsqrtf(var+EPS_); sh.x = bt.x - mu*sc.x;
    mu = s1.y*inv; var = fmaf(-mu, mu, s2.y*inv); sc.y = gm.y*rsqrtf(var+EPS_); sh.y = bt.y - mu*sc.y;
    mu = s1.z*inv; var = fmaf(-mu, mu, s2.z*inv); sc.z = gm.z*rsqrtf(var+EPS_); sh.z = bt.z - mu*sc.z;
    mu = s1.w*inv; var = fmaf(-mu, mu, s2.w*inv); sc.w = gm.w*rsqrtf(var+EPS_); sh.w = bt.w - mu*sc.w;
}

// Finalize BN coefficients into SC/SH.
__global__ __launch_bounds__(256) void k_bnfin(const float* __restrict__ P1,
                                               const float* __restrict__ P2,
                                               const float* __restrict__ gam,
                                               const float* __restrict__ bet,
                                               float* __restrict__ SC,
                                               float* __restrict__ SH) {
    const int c4 = blockIdx.x * 256 + threadIdx.x;
    if (c4 >= C_ / 4) return;
    float4 sc, sh;
    bn_coef(P1, P2, gam, bet, c4, sc, sh);
    ((float4*)SC)[c4] = sc;
    ((float4*)SH)[c4] = sh;
}

// out = tanh(v*sc+sh) (+ res).  v is bf16; res/out fp32.
__global__ __launch_bounds__(256) void k_apply(const ushort* __restrict__ v,
                                               const float* __restrict__ P1,
                                               const float* __restrict__ P2,
                                               const float* __restrict__ gam,
                                               const float* __restrict__ bet,
                                               const float* __restrict__ res,
                                               float* __restrict__ out) {
    const int c4 = blockIdx.x * 256 + threadIdx.x;
    if (c4 >= C_ / 4) return;
    const int g = blockIdx.y;
    float4 sc, sh;
    bn_coef(P1, P2, gam, bet, c4, sc, sh);
    const ushort4* vp = (const ushort4*)v;
    const float4* rp = (const float4*)res;
    float4* op = (float4*)out;
    for (int i = 0; i < BPG_; ++i) {
        const size_t idx = (size_t)(g * BPG_ + i) * (C_ / 4) + c4;
        const ushort4 t4 = vp[idx];
        float4 o;
        o.x = tanhf(fmaf(bf2f(t4.x), sc.x, sh.x));
        o.y = tanhf(fmaf(bf2f(t4.y), sc.y, sh.y));
        o.z = tanhf(fmaf(bf2f(t4.z), sc.z, sh.z));
        o.w = tanhf(fmaf(bf2f(t4.w), sc.w, sh.w));
        if (res) {
            const float4 r = rp[idx];
            o.x += r.x; o.y += r.y; o.z += r.z; o.w += r.w;
        }
        op[idx] = o;
    }
}

// ---------------------------------------------------------------------------
// Decoder part A: per-batch.  o = h[b]@decw;  od[b] = deca*o + dbias + xd[b].
// ---------------------------------------------------------------------------
__global__ __launch_bounds__(256) void k_decA(const float* __restrict__ h,
                                              const float* __restrict__ dw,
                                              const float* __restrict__ da,
                                              const float* __restrict__ db,
                                              const float* __restrict__ xd,
                                              float* __restrict__ od) {
    __shared__ float dwL[H_ * D_];     // 20480 B
    __shared__ float hsL[N_ * 68];     // 17952 B
    __shared__ float oL [N_ * 21];     //  5544 B
    __shared__ float atL[N_ * N_];     // 17424 B
    const int b = blockIdx.x, tid = threadIdx.x;

    for (int i = tid; i < H_*D_; i += 256) dwL[i] = dw[i];
    for (int i = tid; i < N_*N_; i += 256) atL[i] = da[i];

    const int n1 = tid >> 2, dq1 = tid & 3;
    float a1[5] = {0,0,0,0,0};
    float a2[5] = {0,0,0,0,0};
    for (int kc = 0; kc < 4; ++kc) {
        __syncthreads();   // prev hsL reads done (also covers initial staging)
        for (int i = tid; i < N_ * 16; i += 256) {
            const int n = i >> 4, k4 = i & 15;
            *(float4*)&hsL[n * 68 + k4 * 4] =
                *(const float4*)(h + ((size_t)b * N_ + n) * H_ + kc * 64 + k4 * 4);
        }
        __syncthreads();
        for (int kk = 0; kk < 64; ++kk) {
            const float hv = hsL[n1 * 68 + kk];
            const float* wp = &dwL[(kc * 64 + kk) * D_ + dq1 * 5];
            #pragma unroll
            for (int dd = 0; dd < 5; ++dd)
                a1[dd] = fmaf(hv, wp[dd], a1[dd]);
        }
        if (tid < 8) {
            const int n2 = 64 + (tid >> 2), dq2 = tid & 3;
            for (int kk = 0; kk < 64; ++kk) {
                const float hv = hsL[n2 * 68 + kk];
                const float* wp = &dwL[(kc * 64 + kk) * D_ + dq2 * 5];
                #pragma unroll
                for (int dd = 0; dd < 5; ++dd)
                    a2[dd] = fmaf(hv, wp[dd], a2[dd]);
            }
        }
    }
    #pragma unroll
    for (int dd = 0; dd < 5; ++dd) oL[n1 * 21 + dq1 * 5 + dd] = a1[dd];
    if (tid < 8) {
        const int n2 = 64 + (tid >> 2), dq2 = tid & 3;
        #pragma unroll
        for (int dd = 0; dd < 5; ++dd) oL[n2 * 21 + dq2 * 5 + dd] = a2[dd];
    }
    __syncthreads();

    for (int p = tid; p < N_*D_; p += 256) {
        const int n = p / D_, d = p % D_;
        float acc = db[d] + xd[(size_t)b * N_ * D_ + p];
        for (int m = 0; m < N_; ++m)
            acc = fmaf(atL[n * N_ + m], oL[m * 21 + d], acc);
        od[(size_t)b * N_ * D_ + p] = acc;
    }
}

// ---------------------------------------------------------------------------
// Decoder part C: streaming iDCT + history splice.  grid (B, 2).
// ---------------------------------------------------------------------------
__global__ __launch_bounds__(256) void k_decC(const float* __restrict__ od,
                                              const float* __restrict__ itm,
                                              const float* __restrict__ x,
                                              float* __restrict__ out) {
    __shared__ float odL[N_ * 21];     // 5544 B
    __shared__ float itL[63 * D_];     // 5040 B
    const int b = blockIdx.x, half = blockIdx.y, tid = threadIdx.x;
    const int t0 = half * 63;
    const int nt = half ? (T_ - 63) : 63;

    for (int i = tid; i < N_*D_; i += 256) {
        const int n = i / D_, d = i % D_;
        odL[n * 21 + d] = od[(size_t)b * N_ * D_ + i];
    }
    for (int i = tid; i < nt*D_; i += 256) {
        const int tt = i / D_, d = i % D_;
        itL[i] = itm[(t0 + tt) * T_ + d];
    }
    __syncthreads();

    const float* xb = x + (size_t)b * T_ * N_;
    float* ob = out + (size_t)b * T_ * N_;
    for (int q = tid; q < nt*N_; q += 256) {
        const int tt = q / N_, n = q % N_;
        const int t = t0 + tt;
        float o;
        if (t < THIS_) {
            o = xb[t * N_ + n];
        } else {
            o = 0.f;
            #pragma unroll 4
            for (int d = 0; d < D_; ++d)
                o = fmaf(itL[tt * D_ + d], odL[n * 21 + d], o);
        }
        ob[t * N_ + n] = o;
    }
}

// ---------------------------------------------------------------------------
extern "C" void kernel_launch(void* const* d_in, const int* in_sizes, int n_in,
                              void* d_out, int out_size, void* d_ws, size_t ws_size,
                              hipStream_t stream) {
    const float* x    = (const float*)d_in[0];
    const float* tm   = (const float*)d_in[1];
    const float* itm  = (const float*)d_in[2];
    const float* encw = (const float*)d_in[3];
    const float* enca = (const float*)d_in[4];
    const float* encb = (const float*)d_in[5];
    const float* bn0g = (const float*)d_in[6];
    const float* bn0b = (const float*)d_in[7];
    const float* g1w  = (const float*)d_in[8];
    const float* g1a  = (const float*)d_in[9];
    const float* g1b  = (const float*)d_in[10];
    const float* b1g  = (const float*)d_in[11];
    const float* b1b  = (const float*)d_in[12];
    const float* g2w  = (const float*)d_in[13];
    const float* g2a  = (const float*)d_in[14];
    const float* g2b  = (const float*)d_in[15];
    const float* b2g  = (const float*)d_in[16];
    const float* b2b  = (const float*)d_in[17];
    const float* decw = (const float*)d_in[18];
    const float* deca = (const float*)d_in[19];
    const float* decb = (const float*)d_in[20];
    float* out = (float*)d_out;

    // ws layout (round-1 footprint, proven)
    float* ws = (float*)d_ws;
    float* xd = ws;                         //   675840 floats
    float* h  = xd + 675840;                //  8650752
    float* slotA = h + 8650752;             //  8650752 (bf16 buffers)
    float* slotB = slotA + 8650752;         //  8650752 (od inside)
    float* P1 = slotB + 8650752;            //   270336
    float* P2 = P1 + 270336;                //   270336
    float* SC = P2 + 270336;                //    16896
    float* SH = SC + 16896;                 //    16896
    ushort* WT1 = (ushort*)slotA;           //   393216 u16
    ushort* WT2 = WT1 + 393216;             //   393216 u16
    ushort* ybf = WT2 + 393216;             //  8650752 u16
    float*  od  = slotB;                    //   675840 f

    const dim3 blk(256);
    const dim3 gS(17, NBG_);

    // pre-transpose stage weights to bf16 WT[f][k]
    k_wtrans<<<dim3(4,4,ST_), blk, 0, stream>>>(g1w, WT1);
    k_wtrans<<<dim3(4,4,ST_), blk, 0, stream>>>(g2w, WT2);

    k_dct<<<B_, blk, 0, stream>>>(x, tm, xd);

    // encoder (fused gc) + bn0 + tanh
    k_genc<<<B_, blk, 0, stream>>>(xd, encw, enca, encb, ybf);
    k_stats<<<gS, blk, 0, stream>>>(ybf, P1, P2);
    k_apply<<<gS, blk, 0, stream>>>(ybf, P1, P2, bn0g, bn0b, nullptr, h);

    for (int s = 0; s < ST_; ++s) {
        // gc1: ybf = att1*(h@w1) + b1
        k_gc<<<B_, blk, 0, stream>>>(h, nullptr, WT1 + s*H_*H_, g1a + s*N_*N_,
                                     g1b + s*H_, nullptr, nullptr, ybf);
        k_stats<<<gS, blk, 0, stream>>>(ybf, P1, P2);
        k_bnfin<<<17, blk, 0, stream>>>(P1, P2, b1g + s*C_, b1b + s*C_, SC, SH);
        // gc2: ybf = att2*(tanh(bn1(ybf))@w2) + b2   (in-place safe)
        k_gc<<<B_, blk, 0, stream>>>(nullptr, ybf, WT2 + s*H_*H_, g2a + s*N_*N_,
                                     g2b + s*H_, SC, SH, ybf);
        k_stats<<<gS, blk, 0, stream>>>(ybf, P1, P2);
        // h = tanh(bn2(ybf)) + h
        k_apply<<<gS, blk, 0, stream>>>(ybf, P1, P2, b2g + s*C_, b2b + s*C_, h, h);
    }

    // decoder: per-batch GEMM+att, then streaming iDCT+splice
    k_decA<<<B_, blk, 0, stream>>>(h, decw, deca, decb, xd, od);
    k_decC<<<dim3(B_,2), blk, 0, stream>>>(od, itm, x, out);
}

// Round 11
// 822.313 us; speedup vs baseline: 8.7671x; 1.3284x over previous
//
#include <hip/hip_runtime.h>
#include <math.h>

// Problem dims
#define B_    512
#define T_    125
#define N_    66
#define D_    20
#define H_    256
#define ST_   6
#define THIS_ 25
#define C_    (N_*H_)     // 16896 channels for BN
#define ROWS_ (B_*N_)     // 33792
#define NBG_  16          // batch groups for BN stats
#define BPG_  (B_/NBG_)   // 32
#define EPS_  1e-5f

#define ASTR  264         // As row stride (ushorts), mult of 8
#define MSTR  104         // XLT row stride (ushorts), mult of 8 (96 used)
#define XSTR  260         // k_genc XL stride

typedef __attribute__((ext_vector_type(8))) short bf16x8;
typedef __attribute__((ext_vector_type(4))) float f32x4;

__device__ __forceinline__ ushort f2bf(float f) {
    unsigned u = __float_as_uint(f);
    u += 0x7fffu + ((u >> 16) & 1u);       // round-to-nearest-even
    return (ushort)(u >> 16);
}
__device__ __forceinline__ float bf2f(ushort h) {
    return __uint_as_float((unsigned)h << 16);
}

// ---------------------------------------------------------------------------
// Weight transpose+convert: WT[s][f][k] = bf16(W[s][k][f]).  grid (4,4,ST).
// ---------------------------------------------------------------------------
__global__ __launch_bounds__(256) void k_wtrans(const float* __restrict__ W,
                                                ushort* __restrict__ WT) {
    __shared__ ushort t[64][65];
    const int s = blockIdx.z;
    const int kb = blockIdx.x * 64, fb = blockIdx.y * 64;
    const int tid = threadIdx.x;
    const int c = tid & 63;
    const int r4 = tid >> 6;
    for (int rr = 0; rr < 64; rr += 4) {
        const int r = rr + r4;
        t[r][c] = f2bf(W[(size_t)s * 65536 + (size_t)(kb + r) * 256 + fb + c]);
    }
    __syncthreads();
    for (int rr = 0; rr < 64; rr += 4) {
        const int f = rr + r4;
        WT[(size_t)s * 65536 + (size_t)(fb + f) * 256 + kb + c] = t[c][f];
    }
}

// ---------------------------------------------------------------------------
// att pad+convert: P[s][r][m] = bf16(A[s][r][m]) for r,m<66 else 0.  [80][96]
// ---------------------------------------------------------------------------
__global__ __launch_bounds__(256) void k_aprep(const float* __restrict__ A,
                                               ushort* __restrict__ P,
                                               int S) {
    const int idx = blockIdx.x * 256 + threadIdx.x;
    if (idx >= S * 80 * 96) return;
    const int s = idx / 7680, rm = idx % 7680;
    const int r = rm / 96, m = rm % 96;
    const float v = (r < N_ && m < N_) ? A[(size_t)s * N_ * N_ + r * N_ + m] : 0.f;
    P[idx] = f2bf(v);
}

// ---------------------------------------------------------------------------
// DCT along time: xd[b][n][d] = sum_t trans[d][t] * x[b][t][n]
// ---------------------------------------------------------------------------
__global__ __launch_bounds__(256) void k_dct(const float* __restrict__ x,
                                             const float* __restrict__ tm,
                                             float* __restrict__ xd) {
    __shared__ float xs[T_*N_];
    __shared__ float tl[D_*T_];
    const int b = blockIdx.x, tid = threadIdx.x;
    const float* xb = x + (size_t)b * T_ * N_;
    for (int i = tid; i < T_*N_; i += 256) xs[i] = xb[i];
    for (int i = tid; i < D_*T_; i += 256) tl[i] = tm[i];
    __syncthreads();
    for (int p = tid; p < N_*D_; p += 256) {
        const int n = p / D_, d = p % D_;
        float acc = 0.f;
        for (int t = 0; t < T_; ++t)
            acc = fmaf(tl[d*T_ + t], xs[t*N_ + n], acc);
        xd[(size_t)b * N_ * D_ + p] = acc;
    }
}

// ---------------------------------------------------------------------------
// Fused encoder GC: per-batch block; y -> bf16.  (unchanged)
// ---------------------------------------------------------------------------
__global__ __launch_bounds__(256) void k_genc(const float* __restrict__ xd,
                                              const float* __restrict__ ew,
                                              const float* __restrict__ att,
                                              const float* __restrict__ bias,
                                              ushort* __restrict__ Ybf) {
    __shared__ float  xs[N_ * D_];
    __shared__ float  ws[D_ * H_];
    __shared__ ushort XL[N_ * XSTR];
    const int b = blockIdx.x, tid = threadIdx.x;
    for (int i = tid; i < N_*D_; i += 256) xs[i] = xd[(size_t)b * N_ * D_ + i];
    for (int i = tid; i < D_*H_; i += 256) ws[i] = ew[i];
    __syncthreads();

    const int fq = tid & 63;
    const int ng = __builtin_amdgcn_readfirstlane(tid >> 6);
    const int n0 = ng * 17;

    float4 acc[17];
    #pragma unroll
    for (int i = 0; i < 17; ++i) acc[i] = make_float4(0.f,0.f,0.f,0.f);
    for (int k = 0; k < D_; ++k) {
        const float4 wv = *(const float4*)(ws + k * H_ + fq * 4);
        #pragma unroll
        for (int i = 0; i < 17; ++i) {
            int n = n0 + i; n = n < N_ ? n : N_ - 1;
            const float a = xs[n * D_ + k];
            acc[i].x = fmaf(a, wv.x, acc[i].x);
            acc[i].y = fmaf(a, wv.y, acc[i].y);
            acc[i].z = fmaf(a, wv.z, acc[i].z);
            acc[i].w = fmaf(a, wv.w, acc[i].w);
        }
    }
    #pragma unroll
    for (int i = 0; i < 17; ++i) {
        const int n = n0 + i;
        if (n < N_) {
            ushort4 o;
            o.x = f2bf(acc[i].x); o.y = f2bf(acc[i].y);
            o.z = f2bf(acc[i].z); o.w = f2bf(acc[i].w);
            *(ushort4*)&XL[n * XSTR + fq * 4] = o;
        }
    }
    __syncthreads();

    float4 yac[17];
    #pragma unroll
    for (int i = 0; i < 17; ++i) yac[i] = make_float4(0.f,0.f,0.f,0.f);
    for (int m = 0; m < N_; ++m) {
        const ushort4 xv = *(const ushort4*)&XL[m * XSTR + fq * 4];
        const float x0 = bf2f(xv.x), x1 = bf2f(xv.y),
                    x2 = bf2f(xv.z), x3 = bf2f(xv.w);
        #pragma unroll
        for (int i = 0; i < 17; ++i) {
            int n = n0 + i; n = n < N_ ? n : N_ - 1;
            const float a = att[n * N_ + m];
            yac[i].x = fmaf(a, x0, yac[i].x);
            yac[i].y = fmaf(a, x1, yac[i].y);
            yac[i].z = fmaf(a, x2, yac[i].z);
            yac[i].w = fmaf(a, x3, yac[i].w);
        }
    }
    const float4 bv = *(const float4*)(bias + fq * 4);
    #pragma unroll
    for (int i = 0; i < 17; ++i) {
        const int n = n0 + i;
        if (n < N_) {
            ushort4 o;
            o.x = f2bf(yac[i].x + bv.x); o.y = f2bf(yac[i].y + bv.y);
            o.z = f2bf(yac[i].z + bv.z); o.w = f2bf(yac[i].w + bv.w);
            *(ushort4*)(Ybf + (size_t)b * C_ + n * H_ + fq * 4) = o;
        }
    }
}

// ---------------------------------------------------------------------------
// Fused stage GC, dual-MFMA: per-batch block (grid 512).
// Phase 1 (MFMA): xw = A'[b] @ W.  A' staged full-tile bf16 in LDS (As);
//   B read per-fragment from global WT (L2-resident).  No in-loop barriers.
// Epilogue: xw -> XLT[f][m] (per-wave strip, no barrier needed after).
// Phase 2 (MFMA): y[n][f] = sum_m attP[n][m]*XLT[f][m] + bias[f] -> Ybf.
// ---------------------------------------------------------------------------
__global__ __launch_bounds__(256) void k_gc(const float* __restrict__ Af,
                                            const ushort* __restrict__ Ab,
                                            const ushort* __restrict__ WT,
                                            const ushort* __restrict__ attP,
                                            const float* __restrict__ bias,
                                            const float* __restrict__ scale,
                                            const float* __restrict__ shift,
                                            ushort* __restrict__ Ybf) {
    __shared__ __align__(16) ushort smem[256 * MSTR];   // 53,248 B (union)
    ushort* As  = smem;                                 // [80][ASTR] phase 1
    ushort* XLT = smem;                                 // [256][MSTR] phase 2
    const int b    = blockIdx.x;
    const int tid  = threadIdx.x;
    const int lane = tid & 63;
    const int wc   = tid >> 6;            // wave -> 64-col (f) strip
    const int kq   = lane >> 4;
    const int fr   = lane & 15;

    // ---- stage A' (80 rows x 256 k) into As, once ----
    const int ar1 = tid >> 2;             // rows 0..63
    const int ak  = (tid & 3) * 8;
    const int ar2 = 64 + (tid >> 2);      // rows 64..79 (tid<64)
    for (int kt = 0; kt < 8; ++kt) {
        const int kk = kt * 32 + ak;
        bf16x8 v;
        if (Af) {
            float av[8];
            const float* ap = Af + ((size_t)b * N_ + ar1) * H_ + kk;
            *(float4*)&av[0] = *(const float4*)ap;
            *(float4*)&av[4] = *(const float4*)(ap + 4);
            #pragma unroll
            for (int j = 0; j < 8; ++j) v[j] = (short)f2bf(av[j]);
        } else {
            const bf16x8 raw = *(const bf16x8*)(Ab + ((size_t)b * N_ + ar1) * H_ + kk);
            const int cb = ar1 * H_ + kk;
            float sv[8], hv[8];
            *(float4*)&sv[0] = *(const float4*)(scale + cb);
            *(float4*)&sv[4] = *(const float4*)(scale + cb + 4);
            *(float4*)&hv[0] = *(const float4*)(shift + cb);
            *(float4*)&hv[4] = *(const float4*)(shift + cb + 4);
            #pragma unroll
            for (int j = 0; j < 8; ++j)
                v[j] = (short)f2bf(tanhf(fmaf(bf2f((ushort)raw[j]), sv[j], hv[j])));
        }
        *(bf16x8*)&As[ar1 * ASTR + kk] = v;
    }
    if (tid < 64) {
        for (int kt = 0; kt < 8; ++kt) {
            const int kk = kt * 32 + ak;
            bf16x8 v;
            if (ar2 < N_) {
                if (Af) {
                    float av[8];
                    const float* ap = Af + ((size_t)b * N_ + ar2) * H_ + kk;
                    *(float4*)&av[0] = *(const float4*)ap;
                    *(float4*)&av[4] = *(const float4*)(ap + 4);
                    #pragma unroll
                    for (int j = 0; j < 8; ++j) v[j] = (short)f2bf(av[j]);
                } else {
                    const bf16x8 raw = *(const bf16x8*)(Ab + ((size_t)b * N_ + ar2) * H_ + kk);
                    const int cb = ar2 * H_ + kk;
                    float sv[8], hv[8];
                    *(float4*)&sv[0] = *(const float4*)(scale + cb);
                    *(float4*)&sv[4] = *(const float4*)(scale + cb + 4);
                    *(float4*)&hv[0] = *(const float4*)(shift + cb);
                    *(float4*)&hv[4] = *(const float4*)(shift + cb + 4);
                    #pragma unroll
                    for (int j = 0; j < 8; ++j)
                        v[j] = (short)f2bf(tanhf(fmaf(bf2f((ushort)raw[j]), sv[j], hv[j])));
                }
            } else {
                #pragma unroll
                for (int j = 0; j < 8; ++j) v[j] = 0;
            }
            *(bf16x8*)&As[ar2 * ASTR + kk] = v;
        }
    }
    __syncthreads();

    // ---- phase 1 k-loop: no barriers ----
    f32x4 acc[5][4] = {};
    for (int kt = 0; kt < 8; ++kt) {
        const int kb = kt * 32;
        bf16x8 a[5], bv[4];
        #pragma unroll
        for (int m = 0; m < 5; ++m)
            a[m] = *(const bf16x8*)&As[(m * 16 + fr) * ASTR + kb + kq * 8];
        #pragma unroll
        for (int n = 0; n < 4; ++n)
            bv[n] = *(const bf16x8*)(WT + (size_t)(wc * 64 + n * 16 + fr) * H_ + kb + kq * 8);
        #pragma unroll
        for (int m = 0; m < 5; ++m)
            #pragma unroll
            for (int n = 0; n < 4; ++n)
                acc[m][n] = __builtin_amdgcn_mfma_f32_16x16x32_bf16(
                                a[m], bv[n], acc[m][n], 0, 0, 0);
    }
    __syncthreads();   // all waves done reading As -> safe to overwrite (XLT)

    // ---- epilogue: acc -> XLT[f][m] (own strip only) ----
    {
        bf16x8 z = {};
        *(bf16x8*)&XLT[(wc * 64 + lane) * MSTR + 80] = z;   // zero m=80..95
        *(bf16x8*)&XLT[(wc * 64 + lane) * MSTR + 88] = z;
    }
    #pragma unroll
    for (int m = 0; m < 5; ++m) {
        #pragma unroll
        for (int n = 0; n < 4; ++n) {
            #pragma unroll
            for (int j = 0; j < 4; ++j) {
                const int row = m * 16 + kq * 4 + j;       // m-index (0..79)
                const int f   = wc * 64 + n * 16 + fr;
                XLT[f * MSTR + row] = f2bf(acc[m][n][j]);
            }
        }
    }
    // no barrier: each wave reads only rows f it wrote (same-wave lgkmcnt order)

    // ---- phase 2: y[n][f] = sum_m attP[n][m]*XLT[f][m] ----
    f32x4 acc2[5][4] = {};
    for (int kt = 0; kt < 3; ++kt) {
        const int kb = kt * 32;
        bf16x8 a2[5], b2[4];
        #pragma unroll
        for (int m = 0; m < 5; ++m)
            a2[m] = *(const bf16x8*)(attP + (size_t)(m * 16 + fr) * 96 + kb + kq * 8);
        #pragma unroll
        for (int n = 0; n < 4; ++n)
            b2[n] = *(const bf16x8*)&XLT[(wc * 64 + n * 16 + fr) * MSTR + kb + kq * 8];
        #pragma unroll
        for (int m = 0; m < 5; ++m)
            #pragma unroll
            for (int n = 0; n < 4; ++n)
                acc2[m][n] = __builtin_amdgcn_mfma_f32_16x16x32_bf16(
                                a2[m], b2[n], acc2[m][n], 0, 0, 0);
    }
    float bsv[4];
    #pragma unroll
    for (int n = 0; n < 4; ++n) bsv[n] = bias[wc * 64 + n * 16 + fr];
    #pragma unroll
    for (int m = 0; m < 5; ++m) {
        #pragma unroll
        for (int n = 0; n < 4; ++n) {
            #pragma unroll
            for (int j = 0; j < 4; ++j) {
                const int row = m * 16 + kq * 4 + j;       // n-index
                if (row < N_) {
                    const int f = wc * 64 + n * 16 + fr;
                    Ybf[(size_t)b * C_ + row * H_ + f] = f2bf(acc2[m][n][j] + bsv[n]);
                }
            }
        }
    }
}

// ---------------------------------------------------------------------------
// BN partial stats over batch group g (bf16 input).
// ---------------------------------------------------------------------------
__global__ __launch_bounds__(256) void k_stats(const ushort* __restrict__ v,
                                               float* __restrict__ P1,
                                               float* __restrict__ P2) {
    const int c4 = blockIdx.x * 256 + threadIdx.x;
    if (c4 >= C_ / 4) return;
    const int g = blockIdx.y;
    float4 s1 = make_float4(0.f,0.f,0.f,0.f), s2 = make_float4(0.f,0.f,0.f,0.f);
    const ushort4* vp = (const ushort4*)v;
    for (int i = 0; i < BPG_; ++i) {
        const int b = g * BPG_ + i;
        const ushort4 t4 = vp[(size_t)b * (C_ / 4) + c4];
        const float tx = bf2f(t4.x), ty = bf2f(t4.y),
                    tz = bf2f(t4.z), tw = bf2f(t4.w);
        s1.x += tx; s1.y += ty; s1.z += tz; s1.w += tw;
        s2.x = fmaf(tx, tx, s2.x); s2.y = fmaf(ty, ty, s2.y);
        s2.z = fmaf(tz, tz, s2.z); s2.w = fmaf(tw, tw, s2.w);
    }
    ((float4*)(P1 + (size_t)g * C_))[c4] = s1;
    ((float4*)(P2 + (size_t)g * C_))[c4] = s2;
}

__device__ __forceinline__ void bn_coef(const float* P1, const float* P2,
                                        const float* gam, const float* bet,
                                        int c4, float4& sc, float4& sh) {
    float4 s1 = make_float4(0.f,0.f,0.f,0.f), s2 = make_float4(0.f,0.f,0.f,0.f);
    for (int g = 0; g < NBG_; ++g) {
        const float4 a = ((const float4*)(P1 + (size_t)g * C_))[c4];
        const float4 b = ((const float4*)(P2 + (size_t)g * C_))[c4];
        s1.x += a.x; s1.y += a.y; s1.z += a.z; s1.w += a.w;
        s2.x += b.x; s2.y += b.y; s2.z += b.z; s2.w += b.w;
    }
    const float inv = 1.f / (float)B_;
    const float4 gm = ((const float4*)gam)[c4];
    const float4 bt = ((const float4*)bet)[c4];
    float mu, var;
    mu = s1.x*inv; var = fmaf(-mu, mu, s2.x*inv); sc.x = gm.x*rsqrtf(var+EPS_); sh.x = bt.x - mu*sc.x;
    mu = s1.y*inv; var = fmaf(-mu, mu, s2.y*inv); sc.y = gm.y*rsqrtf(var+EPS_); sh.y = bt.y - mu*sc.y;
    mu = s1.z*inv; var = fmaf(-mu, mu, s2.z*inv); sc.z = gm.z*rsqrtf(var+EPS_); sh.z = bt.z - mu*sc.z;
    mu = s1.w*inv; var = fmaf(-mu, mu, s2.w*inv); sc.w = gm.w*rsqrtf(var+EPS_); sh.w = bt.w - mu*sc.w;
}

// Finalize BN coefficients into SC/SH.
__global__ __launch_bounds__(256) void k_bnfin(const float* __restrict__ P1,
                                               const float* __restrict__ P2,
                                               const float* __restrict__ gam,
                                               const float* __restrict__ bet,
                                               float* __restrict__ SC,
                                               float* __restrict__ SH) {
    const int c4 = blockIdx.x * 256 + threadIdx.x;
    if (c4 >= C_ / 4) return;
    float4 sc, sh;
    bn_coef(P1, P2, gam, bet, c4, sc, sh);
    ((float4*)SC)[c4] = sc;
    ((float4*)SH)[c4] = sh;
}

// out = tanh(v*sc+sh) (+ res).  v is bf16; res/out fp32.
__global__ __launch_bounds__(256) void k_apply(const ushort* __restrict__ v,
                                               const float* __restrict__ P1,
                                               const float* __restrict__ P2,
                                               const float* __restrict__ gam,
                                               const float* __restrict__ bet,
                                               const float* __restrict__ res,
                                               float* __restrict__ out) {
    const int c4 = blockIdx.x * 256 + threadIdx.x;
    if (c4 >= C_ / 4) return;
    const int g = blockIdx.y;
    float4 sc, sh;
    bn_coef(P1, P2, gam, bet, c4, sc, sh);
    const ushort4* vp = (const ushort4*)v;
    const float4* rp = (const float4*)res;
    float4* op = (float4*)out;
    for (int i = 0; i < BPG_; ++i) {
        const size_t idx = (size_t)(g * BPG_ + i) * (C_ / 4) + c4;
        const ushort4 t4 = vp[idx];
        float4 o;
        o.x = tanhf(fmaf(bf2f(t4.x), sc.x, sh.x));
        o.y = tanhf(fmaf(bf2f(t4.y), sc.y, sh.y));
        o.z = tanhf(fmaf(bf2f(t4.z), sc.z, sh.z));
        o.w = tanhf(fmaf(bf2f(t4.w), sc.w, sh.w));
        if (res) {
            const float4 r = rp[idx];
            o.x += r.x; o.y += r.y; o.z += r.z; o.w += r.w;
        }
        op[idx] = o;
    }
}

// ---------------------------------------------------------------------------
// Decoder part A: per-batch.  o = h[b]@decw;  od[b] = deca*o + dbias + xd[b].
// ---------------------------------------------------------------------------
__global__ __launch_bounds__(256) void k_decA(const float* __restrict__ h,
                                              const float* __restrict__ dw,
                                              const float* __restrict__ da,
                                              const float* __restrict__ db,
                                              const float* __restrict__ xd,
                                              float* __restrict__ od) {
    __shared__ float dwL[H_ * D_];
    __shared__ float hsL[N_ * 68];
    __shared__ float oL [N_ * 21];
    __shared__ float atL[N_ * N_];
    const int b = blockIdx.x, tid = threadIdx.x;

    for (int i = tid; i < H_*D_; i += 256) dwL[i] = dw[i];
    for (int i = tid; i < N_*N_; i += 256) atL[i] = da[i];

    const int n1 = tid >> 2, dq1 = tid & 3;
    float a1[5] = {0,0,0,0,0};
    float a2[5] = {0,0,0,0,0};
    for (int kc = 0; kc < 4; ++kc) {
        __syncthreads();
        for (int i = tid; i < N_ * 16; i += 256) {
            const int n = i >> 4, k4 = i & 15;
            *(float4*)&hsL[n * 68 + k4 * 4] =
                *(const float4*)(h + ((size_t)b * N_ + n) * H_ + kc * 64 + k4 * 4);
        }
        __syncthreads();
        for (int kk = 0; kk < 64; ++kk) {
            const float hv = hsL[n1 * 68 + kk];
            const float* wp = &dwL[(kc * 64 + kk) * D_ + dq1 * 5];
            #pragma unroll
            for (int dd = 0; dd < 5; ++dd)
                a1[dd] = fmaf(hv, wp[dd], a1[dd]);
        }
        if (tid < 8) {
            const int n2 = 64 + (tid >> 2), dq2 = tid & 3;
            for (int kk = 0; kk < 64; ++kk) {
                const float hv = hsL[n2 * 68 + kk];
                const float* wp = &dwL[(kc * 64 + kk) * D_ + dq2 * 5];
                #pragma unroll
                for (int dd = 0; dd < 5; ++dd)
                    a2[dd] = fmaf(hv, wp[dd], a2[dd]);
            }
        }
    }
    #pragma unroll
    for (int dd = 0; dd < 5; ++dd) oL[n1 * 21 + dq1 * 5 + dd] = a1[dd];
    if (tid < 8) {
        const int n2 = 64 + (tid >> 2), dq2 = tid & 3;
        #pragma unroll
        for (int dd = 0; dd < 5; ++dd) oL[n2 * 21 + dq2 * 5 + dd] = a2[dd];
    }
    __syncthreads();

    for (int p = tid; p < N_*D_; p += 256) {
        const int n = p / D_, d = p % D_;
        float acc = db[d] + xd[(size_t)b * N_ * D_ + p];
        for (int m = 0; m < N_; ++m)
            acc = fmaf(atL[n * N_ + m], oL[m * 21 + d], acc);
        od[(size_t)b * N_ * D_ + p] = acc;
    }
}

// ---------------------------------------------------------------------------
// Decoder part C: streaming iDCT + history splice.  grid (B, 2).
// ---------------------------------------------------------------------------
__global__ __launch_bounds__(256) void k_decC(const float* __restrict__ od,
                                              const float* __restrict__ itm,
                                              const float* __restrict__ x,
                                              float* __restrict__ out) {
    __shared__ float odL[N_ * 21];
    __shared__ float itL[63 * D_];
    const int b = blockIdx.x, half = blockIdx.y, tid = threadIdx.x;
    const int t0 = half * 63;
    const int nt = half ? (T_ - 63) : 63;

    for (int i = tid; i < N_*D_; i += 256) {
        const int n = i / D_, d = i % D_;
        odL[n * 21 + d] = od[(size_t)b * N_ * D_ + i];
    }
    for (int i = tid; i < nt*D_; i += 256) {
        const int tt = i / D_, d = i % D_;
        itL[i] = itm[(t0 + tt) * T_ + d];
    }
    __syncthreads();

    const float* xb = x + (size_t)b * T_ * N_;
    float* ob = out + (size_t)b * T_ * N_;
    for (int q = tid; q < nt*N_; q += 256) {
        const int tt = q / N_, n = q % N_;
        const int t = t0 + tt;
        float o;
        if (t < THIS_) {
            o = xb[t * N_ + n];
        } else {
            o = 0.f;
            #pragma unroll 4
            for (int d = 0; d < D_; ++d)
                o = fmaf(itL[tt * D_ + d], odL[n * 21 + d], o);
        }
        ob[t * N_ + n] = o;
    }
}

// ---------------------------------------------------------------------------
extern "C" void kernel_launch(void* const* d_in, const int* in_sizes, int n_in,
                              void* d_out, int out_size, void* d_ws, size_t ws_size,
                              hipStream_t stream) {
    const float* x    = (const float*)d_in[0];
    const float* tm   = (const float*)d_in[1];
    const float* itm  = (const float*)d_in[2];
    const float* encw = (const float*)d_in[3];
    const float* enca = (const float*)d_in[4];
    const float* encb = (const float*)d_in[5];
    const float* bn0g = (const float*)d_in[6];
    const float* bn0b = (const float*)d_in[7];
    const float* g1w  = (const float*)d_in[8];
    const float* g1a  = (const float*)d_in[9];
    const float* g1b  = (const float*)d_in[10];
    const float* b1g  = (const float*)d_in[11];
    const float* b1b  = (const float*)d_in[12];
    const float* g2w  = (const float*)d_in[13];
    const float* g2a  = (const float*)d_in[14];
    const float* g2b  = (const float*)d_in[15];
    const float* b2g  = (const float*)d_in[16];
    const float* b2b  = (const float*)d_in[17];
    const float* decw = (const float*)d_in[18];
    const float* deca = (const float*)d_in[19];
    const float* decb = (const float*)d_in[20];
    float* out = (float*)d_out;

    // ws layout (round-1 footprint, proven)
    float* ws = (float*)d_ws;
    float* xd = ws;                         //   675840 floats
    float* h  = xd + 675840;                //  8650752
    float* slotA = h + 8650752;             //  8650752 (bf16 buffers)
    float* slotB = slotA + 8650752;         //  8650752 (od inside)
    float* P1 = slotB + 8650752;            //   270336
    float* P2 = P1 + 270336;                //   270336
    float* SC = P2 + 270336;                //    16896
    float* SH = SC + 16896;                 //    16896
    ushort* WT1 = (ushort*)slotA;           //   393216 u16
    ushort* WT2 = WT1 + 393216;             //   393216 u16
    ushort* ybf = WT2 + 393216;             //  8650752 u16
    ushort* aP1 = ybf + 8650752;            //    46080 u16 (6x80x96)
    ushort* aP2 = aP1 + 46080;              //    46080 u16
    float*  od  = slotB;                    //   675840 f

    const dim3 blk(256);
    const dim3 gS(17, NBG_);

    // weight/att preprocessing
    k_wtrans<<<dim3(4,4,ST_), blk, 0, stream>>>(g1w, WT1);
    k_wtrans<<<dim3(4,4,ST_), blk, 0, stream>>>(g2w, WT2);
    k_aprep<<<180, blk, 0, stream>>>(g1a, aP1, ST_);
    k_aprep<<<180, blk, 0, stream>>>(g2a, aP2, ST_);

    k_dct<<<B_, blk, 0, stream>>>(x, tm, xd);

    // encoder (fused gc) + bn0 + tanh
    k_genc<<<B_, blk, 0, stream>>>(xd, encw, enca, encb, ybf);
    k_stats<<<gS, blk, 0, stream>>>(ybf, P1, P2);
    k_apply<<<gS, blk, 0, stream>>>(ybf, P1, P2, bn0g, bn0b, nullptr, h);

    for (int s = 0; s < ST_; ++s) {
        // gc1: ybf = att1*(h@w1) + b1
        k_gc<<<B_, blk, 0, stream>>>(h, nullptr, WT1 + s*H_*H_, aP1 + s*7680,
                                     g1b + s*H_, nullptr, nullptr, ybf);
        k_stats<<<gS, blk, 0, stream>>>(ybf, P1, P2);
        k_bnfin<<<17, blk, 0, stream>>>(P1, P2, b1g + s*C_, b1b + s*C_, SC, SH);
        // gc2: ybf = att2*(tanh(bn1(ybf))@w2) + b2   (in-place safe)
        k_gc<<<B_, blk, 0, stream>>>(nullptr, ybf, WT2 + s*H_*H_, aP2 + s*7680,
                                     g2b + s*H_, SC, SH, ybf);
        k_stats<<<gS, blk, 0, stream>>>(ybf, P1, P2);
        // h = tanh(bn2(ybf)) + h
        k_apply<<<gS, blk, 0, stream>>>(ybf, P1, P2, b2g + s*C_, b2b + s*C_, h, h);
    }

    // decoder: per-batch GEMM+att, then streaming iDCT+splice
    k_decA<<<B_, blk, 0, stream>>>(h, decw, deca, decb, xd, od);
    k_decC<<<dim3(B_,2), blk, 0, stream>>>(od, itm, x, out);
}

// Round 12
// 787.391 us; speedup vs baseline: 9.1559x; 1.0444x over previous
//
#include <hip/hip_runtime.h>
#include <math.h>

// Problem dims
#define B_    512
#define T_    125
#define N_    66
#define D_    20
#define H_    256
#define ST_   6
#define THIS_ 25
#define C_    (N_*H_)     // 16896 channels for BN
#define ROWS_ (B_*N_)     // 33792
#define NBG_  16          // batch groups for BN stats
#define BPG_  (B_/NBG_)   // 32
#define EPS_  1e-5f

#define ASTR  264         // As row stride (ushorts), mult of 8
#define MSTR  104         // XLT/oT row stride (ushorts), mult of 8 (96 used)
#define XSTR  260         // k_genc XL stride

typedef __attribute__((ext_vector_type(8))) short bf16x8;
typedef __attribute__((ext_vector_type(4))) float f32x4;

__device__ __forceinline__ ushort f2bf(float f) {
    unsigned u = __float_as_uint(f);
    u += 0x7fffu + ((u >> 16) & 1u);       // round-to-nearest-even
    return (ushort)(u >> 16);
}
__device__ __forceinline__ float bf2f(ushort h) {
    return __uint_as_float((unsigned)h << 16);
}

// ---------------------------------------------------------------------------
// Weight transpose+convert: WT[s][f][k] = bf16(W[s][k][f]).  grid (4,4,ST).
// ---------------------------------------------------------------------------
__global__ __launch_bounds__(256) void k_wtrans(const float* __restrict__ W,
                                                ushort* __restrict__ WT) {
    __shared__ ushort t[64][65];
    const int s = blockIdx.z;
    const int kb = blockIdx.x * 64, fb = blockIdx.y * 64;
    const int tid = threadIdx.x;
    const int c = tid & 63;
    const int r4 = tid >> 6;
    for (int rr = 0; rr < 64; rr += 4) {
        const int r = rr + r4;
        t[r][c] = f2bf(W[(size_t)s * 65536 + (size_t)(kb + r) * 256 + fb + c]);
    }
    __syncthreads();
    for (int rr = 0; rr < 64; rr += 4) {
        const int f = rr + r4;
        WT[(size_t)s * 65536 + (size_t)(fb + f) * 256 + kb + c] = t[c][f];
    }
}

// ---------------------------------------------------------------------------
// att pad+convert: P[s][r][m] = bf16(A[s][r][m]) for r,m<66 else 0.  [80][96]
// ---------------------------------------------------------------------------
__global__ __launch_bounds__(256) void k_aprep(const float* __restrict__ A,
                                               ushort* __restrict__ P,
                                               int S) {
    const int idx = blockIdx.x * 256 + threadIdx.x;
    if (idx >= S * 80 * 96) return;
    const int s = idx / 7680, rm = idx % 7680;
    const int r = rm / 96, m = rm % 96;
    const float v = (r < N_ && m < N_) ? A[(size_t)s * N_ * N_ + r * N_ + m] : 0.f;
    P[idx] = f2bf(v);
}

// ---------------------------------------------------------------------------
// decw pad+transpose: dwT[f][k] = bf16(decw[k][f]) for f<20 else 0.  [32][256]
// ---------------------------------------------------------------------------
__global__ __launch_bounds__(256) void k_dwprep(const float* __restrict__ dw,
                                                ushort* __restrict__ dwT) {
    const int idx = blockIdx.x * 256 + threadIdx.x;
    if (idx >= 32 * 256) return;
    const int f = idx / 256, k = idx % 256;
    const float v = (f < D_) ? dw[(size_t)k * D_ + f] : 0.f;
    dwT[idx] = f2bf(v);
}

// ---------------------------------------------------------------------------
// DCT along time: xd[b][n][d] = sum_t trans[d][t] * x[b][t][n]
// ---------------------------------------------------------------------------
__global__ __launch_bounds__(256) void k_dct(const float* __restrict__ x,
                                             const float* __restrict__ tm,
                                             float* __restrict__ xd) {
    __shared__ float xs[T_*N_];
    __shared__ float tl[D_*T_];
    const int b = blockIdx.x, tid = threadIdx.x;
    const float* xb = x + (size_t)b * T_ * N_;
    for (int i = tid; i < T_*N_; i += 256) xs[i] = xb[i];
    for (int i = tid; i < D_*T_; i += 256) tl[i] = tm[i];
    __syncthreads();
    for (int p = tid; p < N_*D_; p += 256) {
        const int n = p / D_, d = p % D_;
        float acc = 0.f;
        for (int t = 0; t < T_; ++t)
            acc = fmaf(tl[d*T_ + t], xs[t*N_ + n], acc);
        xd[(size_t)b * N_ * D_ + p] = acc;
    }
}

// ---------------------------------------------------------------------------
// Fused encoder GC: per-batch block; y -> bf16.  (unchanged)
// ---------------------------------------------------------------------------
__global__ __launch_bounds__(256) void k_genc(const float* __restrict__ xd,
                                              const float* __restrict__ ew,
                                              const float* __restrict__ att,
                                              const float* __restrict__ bias,
                                              ushort* __restrict__ Ybf) {
    __shared__ float  xs[N_ * D_];
    __shared__ float  ws[D_ * H_];
    __shared__ ushort XL[N_ * XSTR];
    const int b = blockIdx.x, tid = threadIdx.x;
    for (int i = tid; i < N_*D_; i += 256) xs[i] = xd[(size_t)b * N_ * D_ + i];
    for (int i = tid; i < D_*H_; i += 256) ws[i] = ew[i];
    __syncthreads();

    const int fq = tid & 63;
    const int ng = __builtin_amdgcn_readfirstlane(tid >> 6);
    const int n0 = ng * 17;

    float4 acc[17];
    #pragma unroll
    for (int i = 0; i < 17; ++i) acc[i] = make_float4(0.f,0.f,0.f,0.f);
    for (int k = 0; k < D_; ++k) {
        const float4 wv = *(const float4*)(ws + k * H_ + fq * 4);
        #pragma unroll
        for (int i = 0; i < 17; ++i) {
            int n = n0 + i; n = n < N_ ? n : N_ - 1;
            const float a = xs[n * D_ + k];
            acc[i].x = fmaf(a, wv.x, acc[i].x);
            acc[i].y = fmaf(a, wv.y, acc[i].y);
            acc[i].z = fmaf(a, wv.z, acc[i].z);
            acc[i].w = fmaf(a, wv.w, acc[i].w);
        }
    }
    #pragma unroll
    for (int i = 0; i < 17; ++i) {
        const int n = n0 + i;
        if (n < N_) {
            ushort4 o;
            o.x = f2bf(acc[i].x); o.y = f2bf(acc[i].y);
            o.z = f2bf(acc[i].z); o.w = f2bf(acc[i].w);
            *(ushort4*)&XL[n * XSTR + fq * 4] = o;
        }
    }
    __syncthreads();

    float4 yac[17];
    #pragma unroll
    for (int i = 0; i < 17; ++i) yac[i] = make_float4(0.f,0.f,0.f,0.f);
    for (int m = 0; m < N_; ++m) {
        const ushort4 xv = *(const ushort4*)&XL[m * XSTR + fq * 4];
        const float x0 = bf2f(xv.x), x1 = bf2f(xv.y),
                    x2 = bf2f(xv.z), x3 = bf2f(xv.w);
        #pragma unroll
        for (int i = 0; i < 17; ++i) {
            int n = n0 + i; n = n < N_ ? n : N_ - 1;
            const float a = att[n * N_ + m];
            yac[i].x = fmaf(a, x0, yac[i].x);
            yac[i].y = fmaf(a, x1, yac[i].y);
            yac[i].z = fmaf(a, x2, yac[i].z);
            yac[i].w = fmaf(a, x3, yac[i].w);
        }
    }
    const float4 bv = *(const float4*)(bias + fq * 4);
    #pragma unroll
    for (int i = 0; i < 17; ++i) {
        const int n = n0 + i;
        if (n < N_) {
            ushort4 o;
            o.x = f2bf(yac[i].x + bv.x); o.y = f2bf(yac[i].y + bv.y);
            o.z = f2bf(yac[i].z + bv.z); o.w = f2bf(yac[i].w + bv.w);
            *(ushort4*)(Ybf + (size_t)b * C_ + n * H_ + fq * 4) = o;
        }
    }
}

// ---------------------------------------------------------------------------
// Fused stage GC, dual-MFMA: per-batch block (grid 512).  (unchanged r11)
// ---------------------------------------------------------------------------
__global__ __launch_bounds__(256) void k_gc(const float* __restrict__ Af,
                                            const ushort* __restrict__ Ab,
                                            const ushort* __restrict__ WT,
                                            const ushort* __restrict__ attP,
                                            const float* __restrict__ bias,
                                            const float* __restrict__ scale,
                                            const float* __restrict__ shift,
                                            ushort* __restrict__ Ybf) {
    __shared__ __align__(16) ushort smem[256 * MSTR];   // 53,248 B (union)
    ushort* As  = smem;                                 // [80][ASTR] phase 1
    ushort* XLT = smem;                                 // [256][MSTR] phase 2
    const int b    = blockIdx.x;
    const int tid  = threadIdx.x;
    const int lane = tid & 63;
    const int wc   = tid >> 6;            // wave -> 64-col (f) strip
    const int kq   = lane >> 4;
    const int fr   = lane & 15;

    // ---- stage A' (80 rows x 256 k) into As, once ----
    const int ar1 = tid >> 2;             // rows 0..63
    const int ak  = (tid & 3) * 8;
    const int ar2 = 64 + (tid >> 2);      // rows 64..79 (tid<64)
    for (int kt = 0; kt < 8; ++kt) {
        const int kk = kt * 32 + ak;
        bf16x8 v;
        if (Af) {
            float av[8];
            const float* ap = Af + ((size_t)b * N_ + ar1) * H_ + kk;
            *(float4*)&av[0] = *(const float4*)ap;
            *(float4*)&av[4] = *(const float4*)(ap + 4);
            #pragma unroll
            for (int j = 0; j < 8; ++j) v[j] = (short)f2bf(av[j]);
        } else {
            const bf16x8 raw = *(const bf16x8*)(Ab + ((size_t)b * N_ + ar1) * H_ + kk);
            const int cb = ar1 * H_ + kk;
            float sv[8], hv[8];
            *(float4*)&sv[0] = *(const float4*)(scale + cb);
            *(float4*)&sv[4] = *(const float4*)(scale + cb + 4);
            *(float4*)&hv[0] = *(const float4*)(shift + cb);
            *(float4*)&hv[4] = *(const float4*)(shift + cb + 4);
            #pragma unroll
            for (int j = 0; j < 8; ++j)
                v[j] = (short)f2bf(tanhf(fmaf(bf2f((ushort)raw[j]), sv[j], hv[j])));
        }
        *(bf16x8*)&As[ar1 * ASTR + kk] = v;
    }
    if (tid < 64) {
        for (int kt = 0; kt < 8; ++kt) {
            const int kk = kt * 32 + ak;
            bf16x8 v;
            if (ar2 < N_) {
                if (Af) {
                    float av[8];
                    const float* ap = Af + ((size_t)b * N_ + ar2) * H_ + kk;
                    *(float4*)&av[0] = *(const float4*)ap;
                    *(float4*)&av[4] = *(const float4*)(ap + 4);
                    #pragma unroll
                    for (int j = 0; j < 8; ++j) v[j] = (short)f2bf(av[j]);
                } else {
                    const bf16x8 raw = *(const bf16x8*)(Ab + ((size_t)b * N_ + ar2) * H_ + kk);
                    const int cb = ar2 * H_ + kk;
                    float sv[8], hv[8];
                    *(float4*)&sv[0] = *(const float4*)(scale + cb);
                    *(float4*)&sv[4] = *(const float4*)(scale + cb + 4);
                    *(float4*)&hv[0] = *(const float4*)(shift + cb);
                    *(float4*)&hv[4] = *(const float4*)(shift + cb + 4);
                    #pragma unroll
                    for (int j = 0; j < 8; ++j)
                        v[j] = (short)f2bf(tanhf(fmaf(bf2f((ushort)raw[j]), sv[j], hv[j])));
                }
            } else {
                #pragma unroll
                for (int j = 0; j < 8; ++j) v[j] = 0;
            }
            *(bf16x8*)&As[ar2 * ASTR + kk] = v;
        }
    }
    __syncthreads();

    // ---- phase 1 k-loop: no barriers ----
    f32x4 acc[5][4] = {};
    for (int kt = 0; kt < 8; ++kt) {
        const int kb = kt * 32;
        bf16x8 a[5], bv[4];
        #pragma unroll
        for (int m = 0; m < 5; ++m)
            a[m] = *(const bf16x8*)&As[(m * 16 + fr) * ASTR + kb + kq * 8];
        #pragma unroll
        for (int n = 0; n < 4; ++n)
            bv[n] = *(const bf16x8*)(WT + (size_t)(wc * 64 + n * 16 + fr) * H_ + kb + kq * 8);
        #pragma unroll
        for (int m = 0; m < 5; ++m)
            #pragma unroll
            for (int n = 0; n < 4; ++n)
                acc[m][n] = __builtin_amdgcn_mfma_f32_16x16x32_bf16(
                                a[m], bv[n], acc[m][n], 0, 0, 0);
    }
    __syncthreads();   // all waves done reading As -> safe to overwrite (XLT)

    // ---- epilogue: acc -> XLT[f][m] (own strip only) ----
    {
        bf16x8 z = {};
        *(bf16x8*)&XLT[(wc * 64 + lane) * MSTR + 80] = z;   // zero m=80..95
        *(bf16x8*)&XLT[(wc * 64 + lane) * MSTR + 88] = z;
    }
    #pragma unroll
    for (int m = 0; m < 5; ++m) {
        #pragma unroll
        for (int n = 0; n < 4; ++n) {
            #pragma unroll
            for (int j = 0; j < 4; ++j) {
                const int row = m * 16 + kq * 4 + j;       // m-index (0..79)
                const int f   = wc * 64 + n * 16 + fr;
                XLT[f * MSTR + row] = f2bf(acc[m][n][j]);
            }
        }
    }
    // no barrier: each wave reads only rows f it wrote (same-wave lgkmcnt order)

    // ---- phase 2: y[n][f] = sum_m attP[n][m]*XLT[f][m] ----
    f32x4 acc2[5][4] = {};
    for (int kt = 0; kt < 3; ++kt) {
        const int kb = kt * 32;
        bf16x8 a2[5], b2[4];
        #pragma unroll
        for (int m = 0; m < 5; ++m)
            a2[m] = *(const bf16x8*)(attP + (size_t)(m * 16 + fr) * 96 + kb + kq * 8);
        #pragma unroll
        for (int n = 0; n < 4; ++n)
            b2[n] = *(const bf16x8*)&XLT[(wc * 64 + n * 16 + fr) * MSTR + kb + kq * 8];
        #pragma unroll
        for (int m = 0; m < 5; ++m)
            #pragma unroll
            for (int n = 0; n < 4; ++n)
                acc2[m][n] = __builtin_amdgcn_mfma_f32_16x16x32_bf16(
                                a2[m], b2[n], acc2[m][n], 0, 0, 0);
    }
    float bsv[4];
    #pragma unroll
    for (int n = 0; n < 4; ++n) bsv[n] = bias[wc * 64 + n * 16 + fr];
    #pragma unroll
    for (int m = 0; m < 5; ++m) {
        #pragma unroll
        for (int n = 0; n < 4; ++n) {
            #pragma unroll
            for (int j = 0; j < 4; ++j) {
                const int row = m * 16 + kq * 4 + j;       // n-index
                if (row < N_) {
                    const int f = wc * 64 + n * 16 + fr;
                    Ybf[(size_t)b * C_ + row * H_ + f] = f2bf(acc2[m][n][j] + bsv[n]);
                }
            }
        }
    }
}

// ---------------------------------------------------------------------------
// BN partial stats over batch group g (bf16 input).
// ---------------------------------------------------------------------------
__global__ __launch_bounds__(256) void k_stats(const ushort* __restrict__ v,
                                               float* __restrict__ P1,
                                               float* __restrict__ P2) {
    const int c4 = blockIdx.x * 256 + threadIdx.x;
    if (c4 >= C_ / 4) return;
    const int g = blockIdx.y;
    float4 s1 = make_float4(0.f,0.f,0.f,0.f), s2 = make_float4(0.f,0.f,0.f,0.f);
    const ushort4* vp = (const ushort4*)v;
    for (int i = 0; i < BPG_; ++i) {
        const int b = g * BPG_ + i;
        const ushort4 t4 = vp[(size_t)b * (C_ / 4) + c4];
        const float tx = bf2f(t4.x), ty = bf2f(t4.y),
                    tz = bf2f(t4.z), tw = bf2f(t4.w);
        s1.x += tx; s1.y += ty; s1.z += tz; s1.w += tw;
        s2.x = fmaf(tx, tx, s2.x); s2.y = fmaf(ty, ty, s2.y);
        s2.z = fmaf(tz, tz, s2.z); s2.w = fmaf(tw, tw, s2.w);
    }
    ((float4*)(P1 + (size_t)g * C_))[c4] = s1;
    ((float4*)(P2 + (size_t)g * C_))[c4] = s2;
}

__device__ __forceinline__ void bn_coef(const float* P1, const float* P2,
                                        const float* gam, const float* bet,
                                        int c4, float4& sc, float4& sh) {
    float4 s1 = make_float4(0.f,0.f,0.f,0.f), s2 = make_float4(0.f,0.f,0.f,0.f);
    for (int g = 0; g < NBG_; ++g) {
        const float4 a = ((const float4*)(P1 + (size_t)g * C_))[c4];
        const float4 b = ((const float4*)(P2 + (size_t)g * C_))[c4];
        s1.x += a.x; s1.y += a.y; s1.z += a.z; s1.w += a.w;
        s2.x += b.x; s2.y += b.y; s2.z += b.z; s2.w += b.w;
    }
    const float inv = 1.f / (float)B_;
    const float4 gm = ((const float4*)gam)[c4];
    const float4 bt = ((const float4*)bet)[c4];
    float mu, var;
    mu = s1.x*inv; var = fmaf(-mu, mu, s2.x*inv); sc.x = gm.x*rsqrtf(var+EPS_); sh.x = bt.x - mu*sc.x;
    mu = s1.y*inv; var = fmaf(-mu, mu, s2.y*inv); sc.y = gm.y*rsqrtf(var+EPS_); sh.y = bt.y - mu*sc.y;
    mu = s1.z*inv; var = fmaf(-mu, mu, s2.z*inv); sc.z = gm.z*rsqrtf(var+EPS_); sh.z = bt.z - mu*sc.z;
    mu = s1.w*inv; var = fmaf(-mu, mu, s2.w*inv); sc.w = gm.w*rsqrtf(var+EPS_); sh.w = bt.w - mu*sc.w;
}

// Finalize BN coefficients into SC/SH.
__global__ __launch_bounds__(256) void k_bnfin(const float* __restrict__ P1,
                                               const float* __restrict__ P2,
                                               const float* __restrict__ gam,
                                               const float* __restrict__ bet,
                                               float* __restrict__ SC,
                                               float* __restrict__ SH) {
    const int c4 = blockIdx.x * 256 + threadIdx.x;
    if (c4 >= C_ / 4) return;
    float4 sc, sh;
    bn_coef(P1, P2, gam, bet, c4, sc, sh);
    ((float4*)SC)[c4] = sc;
    ((float4*)SH)[c4] = sh;
}

// out = tanh(v*sc+sh) (+ res).  v is bf16; res/out fp32.
__global__ __launch_bounds__(256) void k_apply(const ushort* __restrict__ v,
                                               const float* __restrict__ P1,
                                               const float* __restrict__ P2,
                                               const float* __restrict__ gam,
                                               const float* __restrict__ bet,
                                               const float* __restrict__ res,
                                               float* __restrict__ out) {
    const int c4 = blockIdx.x * 256 + threadIdx.x;
    if (c4 >= C_ / 4) return;
    const int g = blockIdx.y;
    float4 sc, sh;
    bn_coef(P1, P2, gam, bet, c4, sc, sh);
    const ushort4* vp = (const ushort4*)v;
    const float4* rp = (const float4*)res;
    float4* op = (float4*)out;
    for (int i = 0; i < BPG_; ++i) {
        const size_t idx = (size_t)(g * BPG_ + i) * (C_ / 4) + c4;
        const ushort4 t4 = vp[idx];
        float4 o;
        o.x = tanhf(fmaf(bf2f(t4.x), sc.x, sh.x));
        o.y = tanhf(fmaf(bf2f(t4.y), sc.y, sh.y));
        o.z = tanhf(fmaf(bf2f(t4.z), sc.z, sh.z));
        o.w = tanhf(fmaf(bf2f(t4.w), sc.w, sh.w));
        if (res) {
            const float4 r = rp[idx];
            o.x += r.x; o.y += r.y; o.z += r.z; o.w += r.w;
        }
        op[idx] = o;
    }
}

// ---------------------------------------------------------------------------
// Fully fused decoder: per-batch block (grid 512), dual-MFMA + iDCT + splice.
// Phase 1 (waves 0,1): o[m][d] = h[b][m][:] @ dwT[d][:]  (M=80, K=256, N=32)
//   -> oT[d][m] bf16 LDS.  Wave 2 zero-pads oT m=80..95 concurrently.
// Phase 2 (waves 0,1): od[n][d] = sum_m attP[n][m]*oT[d][m] + db[d] + xd.
// Phase 3 (all): out[b][t][n] = t<25 ? x : sum_d itm[t][d]*od[n][d].
// ---------------------------------------------------------------------------
__global__ __launch_bounds__(256) void k_dec2(const float* __restrict__ h,
                                              const ushort* __restrict__ dwT,
                                              const ushort* __restrict__ aPd,
                                              const float* __restrict__ db,
                                              const float* __restrict__ xd,
                                              const float* __restrict__ itm,
                                              const float* __restrict__ x,
                                              float* __restrict__ out) {
    __shared__ __align__(16) ushort As[80 * ASTR];   // 42,240 B
    __shared__ __align__(16) ushort oT[32 * MSTR];   //  6,656 B
    __shared__ float odL[N_ * 21];                   //  5,544 B
    __shared__ float itL[T_ * D_];                   // 10,000 B
    const int b    = blockIdx.x;
    const int tid  = threadIdx.x;
    const int lane = tid & 63;
    const int wc   = tid >> 6;
    const int kq   = lane >> 4;
    const int fr   = lane & 15;

    // stage itm slice
    for (int i = tid; i < T_*D_; i += 256) {
        const int t = i / D_, d = i % D_;
        itL[i] = itm[t * T_ + d];
    }
    // stage As from h (fp32 -> bf16), 80 rows x 256
    const int ar1 = tid >> 2;
    const int ak  = (tid & 3) * 8;
    const int ar2 = 64 + (tid >> 2);
    for (int kt = 0; kt < 8; ++kt) {
        const int kk = kt * 32 + ak;
        float av[8];
        const float* ap = h + ((size_t)b * N_ + ar1) * H_ + kk;
        *(float4*)&av[0] = *(const float4*)ap;
        *(float4*)&av[4] = *(const float4*)(ap + 4);
        bf16x8 v;
        #pragma unroll
        for (int j = 0; j < 8; ++j) v[j] = (short)f2bf(av[j]);
        *(bf16x8*)&As[ar1 * ASTR + kk] = v;
    }
    if (tid < 64) {
        for (int kt = 0; kt < 8; ++kt) {
            const int kk = kt * 32 + ak;
            bf16x8 v;
            if (ar2 < N_) {
                float av[8];
                const float* ap = h + ((size_t)b * N_ + ar2) * H_ + kk;
                *(float4*)&av[0] = *(const float4*)ap;
                *(float4*)&av[4] = *(const float4*)(ap + 4);
                #pragma unroll
                for (int j = 0; j < 8; ++j) v[j] = (short)f2bf(av[j]);
            } else {
                #pragma unroll
                for (int j = 0; j < 8; ++j) v[j] = 0;
            }
            *(bf16x8*)&As[ar2 * ASTR + kk] = v;
        }
    }
    // wave 2 zero-pads oT m=80..95 (concurrent with staging)
    if (tid >= 128 && tid < 160) {
        bf16x8 z = {};
        *(bf16x8*)&oT[(tid - 128) * MSTR + 80] = z;
        *(bf16x8*)&oT[(tid - 128) * MSTR + 88] = z;
    }
    __syncthreads();

    // phase 1: waves 0,1; wave wc covers d = wc*16 + fr
    if (wc < 2) {
        f32x4 acc[5] = {};
        for (int kt = 0; kt < 8; ++kt) {
            const int kb = kt * 32;
            bf16x8 a[5];
            #pragma unroll
            for (int m = 0; m < 5; ++m)
                a[m] = *(const bf16x8*)&As[(m * 16 + fr) * ASTR + kb + kq * 8];
            const bf16x8 bv = *(const bf16x8*)(dwT + (size_t)(wc * 16 + fr) * H_ + kb + kq * 8);
            #pragma unroll
            for (int m = 0; m < 5; ++m)
                acc[m] = __builtin_amdgcn_mfma_f32_16x16x32_bf16(a[m], bv, acc[m], 0, 0, 0);
        }
        // epilogue: oT[d][m] = bf16(o[m][d]);  d = wc*16+fr, m = m5*16+kq*4+j
        #pragma unroll
        for (int m = 0; m < 5; ++m)
            #pragma unroll
            for (int j = 0; j < 4; ++j)
                oT[(wc * 16 + fr) * MSTR + m * 16 + kq * 4 + j] = f2bf(acc[m][j]);
    }
    __syncthreads();

    // phase 2: waves 0,1; od[n][d] = sum_m aPd[n][m]*oT[d][m] + db[d] + xd
    if (wc < 2) {
        f32x4 acc2[5] = {};
        for (int kt = 0; kt < 3; ++kt) {
            const int kb = kt * 32;
            bf16x8 a2[5];
            #pragma unroll
            for (int m = 0; m < 5; ++m)
                a2[m] = *(const bf16x8*)(aPd + (size_t)(m * 16 + fr) * 96 + kb + kq * 8);
            const bf16x8 b2 = *(const bf16x8*)&oT[(wc * 16 + fr) * MSTR + kb + kq * 8];
            #pragma unroll
            for (int m = 0; m < 5; ++m)
                acc2[m] = __builtin_amdgcn_mfma_f32_16x16x32_bf16(a2[m], b2, acc2[m], 0, 0, 0);
        }
        const int d = wc * 16 + fr;
        if (d < D_) {
            const float dbv = db[d];
            #pragma unroll
            for (int m = 0; m < 5; ++m) {
                #pragma unroll
                for (int j = 0; j < 4; ++j) {
                    const int n = m * 16 + kq * 4 + j;
                    if (n < N_)
                        odL[n * 21 + d] = acc2[m][j] + dbv
                                        + xd[(size_t)b * N_ * D_ + n * D_ + d];
                }
            }
        }
    }
    __syncthreads();

    // phase 3: iDCT + splice (all threads)
    const float* xb = x + (size_t)b * T_ * N_;
    float* ob = out + (size_t)b * T_ * N_;
    for (int q = tid; q < T_*N_; q += 256) {
        const int t = q / N_, n = q % N_;
        float o;
        if (t < THIS_) {
            o = xb[q];
        } else {
            o = 0.f;
            #pragma unroll 4
            for (int d = 0; d < D_; ++d)
                o = fmaf(itL[t * D_ + d], odL[n * 21 + d], o);
        }
        ob[q] = o;
    }
}

// ---------------------------------------------------------------------------
extern "C" void kernel_launch(void* const* d_in, const int* in_sizes, int n_in,
                              void* d_out, int out_size, void* d_ws, size_t ws_size,
                              hipStream_t stream) {
    const float* x    = (const float*)d_in[0];
    const float* tm   = (const float*)d_in[1];
    const float* itm  = (const float*)d_in[2];
    const float* encw = (const float*)d_in[3];
    const float* enca = (const float*)d_in[4];
    const float* encb = (const float*)d_in[5];
    const float* bn0g = (const float*)d_in[6];
    const float* bn0b = (const float*)d_in[7];
    const float* g1w  = (const float*)d_in[8];
    const float* g1a  = (const float*)d_in[9];
    const float* g1b  = (const float*)d_in[10];
    const float* b1g  = (const float*)d_in[11];
    const float* b1b  = (const float*)d_in[12];
    const float* g2w  = (const float*)d_in[13];
    const float* g2a  = (const float*)d_in[14];
    const float* g2b  = (const float*)d_in[15];
    const float* b2g  = (const float*)d_in[16];
    const float* b2b  = (const float*)d_in[17];
    const float* decw = (const float*)d_in[18];
    const float* deca = (const float*)d_in[19];
    const float* decb = (const float*)d_in[20];
    float* out = (float*)d_out;

    // ws layout (round-1 footprint, proven)
    float* ws = (float*)d_ws;
    float* xd = ws;                         //   675840 floats
    float* h  = xd + 675840;                //  8650752
    float* slotA = h + 8650752;             //  8650752 (bf16 buffers)
    float* slotB = slotA + 8650752;         //  8650752 (unused now)
    float* P1 = slotB + 8650752;            //   270336
    float* P2 = P1 + 270336;                //   270336
    float* SC = P2 + 270336;                //    16896
    float* SH = SC + 16896;                 //    16896
    ushort* WT1 = (ushort*)slotA;           //   393216 u16
    ushort* WT2 = WT1 + 393216;             //   393216 u16
    ushort* ybf = WT2 + 393216;             //  8650752 u16
    ushort* aP1 = ybf + 8650752;            //    46080 u16 (6x80x96)
    ushort* aP2 = aP1 + 46080;              //    46080 u16
    ushort* aPd = aP2 + 46080;              //     7680 u16 (80x96)
    ushort* dwT = aPd + 7680;               //     8192 u16 (32x256)

    const dim3 blk(256);
    const dim3 gS(17, NBG_);

    // weight/att preprocessing
    k_wtrans<<<dim3(4,4,ST_), blk, 0, stream>>>(g1w, WT1);
    k_wtrans<<<dim3(4,4,ST_), blk, 0, stream>>>(g2w, WT2);
    k_aprep<<<180, blk, 0, stream>>>(g1a, aP1, ST_);
    k_aprep<<<180, blk, 0, stream>>>(g2a, aP2, ST_);
    k_aprep<<<30, blk, 0, stream>>>(deca, aPd, 1);
    k_dwprep<<<32, blk, 0, stream>>>(decw, dwT);

    k_dct<<<B_, blk, 0, stream>>>(x, tm, xd);

    // encoder (fused gc) + bn0 + tanh
    k_genc<<<B_, blk, 0, stream>>>(xd, encw, enca, encb, ybf);
    k_stats<<<gS, blk, 0, stream>>>(ybf, P1, P2);
    k_apply<<<gS, blk, 0, stream>>>(ybf, P1, P2, bn0g, bn0b, nullptr, h);

    for (int s = 0; s < ST_; ++s) {
        // gc1: ybf = att1*(h@w1) + b1
        k_gc<<<B_, blk, 0, stream>>>(h, nullptr, WT1 + s*H_*H_, aP1 + s*7680,
                                     g1b + s*H_, nullptr, nullptr, ybf);
        k_stats<<<gS, blk, 0, stream>>>(ybf, P1, P2);
        k_bnfin<<<17, blk, 0, stream>>>(P1, P2, b1g + s*C_, b1b + s*C_, SC, SH);
        // gc2: ybf = att2*(tanh(bn1(ybf))@w2) + b2   (in-place safe)
        k_gc<<<B_, blk, 0, stream>>>(nullptr, ybf, WT2 + s*H_*H_, aP2 + s*7680,
                                     g2b + s*H_, SC, SH, ybf);
        k_stats<<<gS, blk, 0, stream>>>(ybf, P1, P2);
        // h = tanh(bn2(ybf)) + h
        k_apply<<<gS, blk, 0, stream>>>(ybf, P1, P2, b2g + s*C_, b2b + s*C_, h, h);
    }

    // fully fused decoder
    k_dec2<<<B_, blk, 0, stream>>>(h, dwT, aPd, decb, xd, itm, x, out);
}

// Round 13
// 657.753 us; speedup vs baseline: 10.9605x; 1.1971x over previous
//
#include <hip/hip_runtime.h>
#include <math.h>

// Problem dims
#define B_    512
#define T_    125
#define N_    66
#define D_    20
#define H_    256
#define ST_   6
#define THIS_ 25
#define C_    (N_*H_)     // 16896 channels for BN
#define NBG_  16          // batch groups for BN stats
#define BPG_  (B_/NBG_)   // 32
#define EPS_  1e-5f

#define ASTR  264         // As row stride (ushorts)
#define MSTR  104         // XLT/oT row stride (ushorts), 96 used
#define ESTR  40          // genc As row stride (32 used)

typedef __attribute__((ext_vector_type(8))) short bf16x8;
typedef __attribute__((ext_vector_type(4))) float f32x4;

__device__ __forceinline__ ushort f2bf(float f) {
    unsigned u = __float_as_uint(f);
    u += 0x7fffu + ((u >> 16) & 1u);       // round-to-nearest-even
    return (ushort)(u >> 16);
}
__device__ __forceinline__ float bf2f(ushort h) {
    return __uint_as_float((unsigned)h << 16);
}

// Fused staging element: t = tanh(y*sc+sh) (+ hin); optional hout write.
__device__ __forceinline__ bf16x8 stage8(const ushort* __restrict__ Yin,
                                         const float* __restrict__ SC,
                                         const float* __restrict__ SH,
                                         const float* __restrict__ hin,
                                         float* __restrict__ hout,
                                         int ch, size_t g) {
    const bf16x8 raw = *(const bf16x8*)(Yin + g);
    float sv[8], hv[8], t[8];
    *(float4*)&sv[0] = *(const float4*)(SC + ch);
    *(float4*)&sv[4] = *(const float4*)(SC + ch + 4);
    *(float4*)&hv[0] = *(const float4*)(SH + ch);
    *(float4*)&hv[4] = *(const float4*)(SH + ch + 4);
    #pragma unroll
    for (int j = 0; j < 8; ++j)
        t[j] = tanhf(fmaf(bf2f((ushort)raw[j]), sv[j], hv[j]));
    if (hin) {
        float rv[8];
        *(float4*)&rv[0] = *(const float4*)(hin + g);
        *(float4*)&rv[4] = *(const float4*)(hin + g + 4);
        #pragma unroll
        for (int j = 0; j < 8; ++j) t[j] += rv[j];
    }
    if (hout) {
        *(float4*)(hout + g)     = make_float4(t[0], t[1], t[2], t[3]);
        *(float4*)(hout + g + 4) = make_float4(t[4], t[5], t[6], t[7]);
    }
    bf16x8 v;
    #pragma unroll
    for (int j = 0; j < 8; ++j) v[j] = (short)f2bf(t[j]);
    return v;
}

// ---------------------------------------------------------------------------
// Weight transpose+convert: WT[s][f][k] = bf16(W[s][k][f]).  grid (4,4,ST).
// ---------------------------------------------------------------------------
__global__ __launch_bounds__(256) void k_wtrans(const float* __restrict__ W,
                                                ushort* __restrict__ WT) {
    __shared__ ushort t[64][65];
    const int s = blockIdx.z;
    const int kb = blockIdx.x * 64, fb = blockIdx.y * 64;
    const int tid = threadIdx.x;
    const int c = tid & 63;
    const int r4 = tid >> 6;
    for (int rr = 0; rr < 64; rr += 4) {
        const int r = rr + r4;
        t[r][c] = f2bf(W[(size_t)s * 65536 + (size_t)(kb + r) * 256 + fb + c]);
    }
    __syncthreads();
    for (int rr = 0; rr < 64; rr += 4) {
        const int f = rr + r4;
        WT[(size_t)s * 65536 + (size_t)(fb + f) * 256 + kb + c] = t[c][f];
    }
}

// ---------------------------------------------------------------------------
// att pad+convert: P[s][r][m] = bf16(A[s][r][m]) for r,m<66 else 0.  [80][96]
// ---------------------------------------------------------------------------
__global__ __launch_bounds__(256) void k_aprep(const float* __restrict__ A,
                                               ushort* __restrict__ P,
                                               int S) {
    const int idx = blockIdx.x * 256 + threadIdx.x;
    if (idx >= S * 80 * 96) return;
    const int s = idx / 7680, rm = idx % 7680;
    const int r = rm / 96, m = rm % 96;
    const float v = (r < N_ && m < N_) ? A[(size_t)s * N_ * N_ + r * N_ + m] : 0.f;
    P[idx] = f2bf(v);
}

// ---------------------------------------------------------------------------
// decw pad+transpose: dwT[f][k] = bf16(decw[k][f]) for f<20 else 0.  [32][256]
// ---------------------------------------------------------------------------
__global__ __launch_bounds__(256) void k_dwprep(const float* __restrict__ dw,
                                                ushort* __restrict__ dwT) {
    const int idx = blockIdx.x * 256 + threadIdx.x;
    if (idx >= 32 * 256) return;
    const int f = idx / 256, k = idx % 256;
    const float v = (f < D_) ? dw[(size_t)k * D_ + f] : 0.f;
    dwT[idx] = f2bf(v);
}

// ---------------------------------------------------------------------------
// encw pad+transpose: ewT[f][k] = bf16(encw[k][f]) for k<20 else 0.  [256][32]
// ---------------------------------------------------------------------------
__global__ __launch_bounds__(256) void k_ewprep(const float* __restrict__ ew,
                                                ushort* __restrict__ ewT) {
    const int idx = blockIdx.x * 256 + threadIdx.x;
    if (idx >= 256 * 32) return;
    const int f = idx / 32, k = idx % 32;
    const float v = (k < D_) ? ew[(size_t)k * H_ + f] : 0.f;
    ewT[idx] = f2bf(v);
}

// ---------------------------------------------------------------------------
// DCT along time: xd[b][n][d] = sum_t trans[d][t] * x[b][t][n]
// ---------------------------------------------------------------------------
__global__ __launch_bounds__(256) void k_dct(const float* __restrict__ x,
                                             const float* __restrict__ tm,
                                             float* __restrict__ xd) {
    __shared__ float xs[T_*N_];
    __shared__ float tl[D_*T_];
    const int b = blockIdx.x, tid = threadIdx.x;
    const float* xb = x + (size_t)b * T_ * N_;
    for (int i = tid; i < T_*N_; i += 256) xs[i] = xb[i];
    for (int i = tid; i < D_*T_; i += 256) tl[i] = tm[i];
    __syncthreads();
    for (int p = tid; p < N_*D_; p += 256) {
        const int n = p / D_, d = p % D_;
        float acc = 0.f;
        for (int t = 0; t < T_; ++t)
            acc = fmaf(tl[d*T_ + t], xs[t*N_ + n], acc);
        xd[(size_t)b * N_ * D_ + p] = acc;
    }
}

// ---------------------------------------------------------------------------
// Encoder GC, dual-MFMA: per-batch block. Phase 1 K=32 (20 real), phase 2 attP.
// ---------------------------------------------------------------------------
__global__ __launch_bounds__(256) void k_genc2(const float* __restrict__ xd,
                                               const ushort* __restrict__ ewT,
                                               const ushort* __restrict__ attP,
                                               const float* __restrict__ bias,
                                               ushort* __restrict__ Ybf) {
    __shared__ __align__(16) ushort As[80 * ESTR];       //  6,400 B
    __shared__ __align__(16) ushort XLT[256 * MSTR];     // 53,248 B
    const int b    = blockIdx.x;
    const int tid  = threadIdx.x;
    const int lane = tid & 63;
    const int wc   = tid >> 6;
    const int kq   = lane >> 4;
    const int fr   = lane & 15;

    // stage xd -> As [80][32] bf16 (k>=20 and n>=66 zero)
    const int ar1 = tid >> 2;
    const int ak  = (tid & 3) * 8;
    const int ar2 = 64 + (tid >> 2);
    {
        bf16x8 v;
        #pragma unroll
        for (int j = 0; j < 8; ++j) {
            const int k = ak + j;
            v[j] = (k < D_) ? (short)f2bf(xd[((size_t)b * N_ + ar1) * D_ + k]) : (short)0;
        }
        *(bf16x8*)&As[ar1 * ESTR + ak] = v;
    }
    if (tid < 64) {
        bf16x8 v;
        #pragma unroll
        for (int j = 0; j < 8; ++j) {
            const int k = ak + j;
            v[j] = (ar2 < N_ && k < D_) ?
                   (short)f2bf(xd[((size_t)b * N_ + ar2) * D_ + k]) : (short)0;
        }
        *(bf16x8*)&As[ar2 * ESTR + ak] = v;
    }
    __syncthreads();

    // phase 1: single k-step (K=32)
    f32x4 acc[5][4] = {};
    {
        bf16x8 a[5], bv[4];
        #pragma unroll
        for (int m = 0; m < 5; ++m)
            a[m] = *(const bf16x8*)&As[(m * 16 + fr) * ESTR + kq * 8];
        #pragma unroll
        for (int n = 0; n < 4; ++n)
            bv[n] = *(const bf16x8*)(ewT + (size_t)(wc * 64 + n * 16 + fr) * 32 + kq * 8);
        #pragma unroll
        for (int m = 0; m < 5; ++m)
            #pragma unroll
            for (int n = 0; n < 4; ++n)
                acc[m][n] = __builtin_amdgcn_mfma_f32_16x16x32_bf16(
                                a[m], bv[n], acc[m][n], 0, 0, 0);
    }

    // epilogue -> XLT[f][m] (own strip)
    {
        bf16x8 z = {};
        *(bf16x8*)&XLT[(wc * 64 + lane) * MSTR + 80] = z;
        *(bf16x8*)&XLT[(wc * 64 + lane) * MSTR + 88] = z;
    }
    #pragma unroll
    for (int m = 0; m < 5; ++m)
        #pragma unroll
        for (int n = 0; n < 4; ++n)
            #pragma unroll
            for (int j = 0; j < 4; ++j)
                XLT[(wc * 64 + n * 16 + fr) * MSTR + m * 16 + kq * 4 + j] =
                    f2bf(acc[m][n][j]);

    // phase 2: y[n][f] = sum_m attP[n][m]*XLT[f][m] + bias
    f32x4 acc2[5][4] = {};
    for (int kt = 0; kt < 3; ++kt) {
        const int kb = kt * 32;
        bf16x8 a2[5], b2[4];
        #pragma unroll
        for (int m = 0; m < 5; ++m)
            a2[m] = *(const bf16x8*)(attP + (size_t)(m * 16 + fr) * 96 + kb + kq * 8);
        #pragma unroll
        for (int n = 0; n < 4; ++n)
            b2[n] = *(const bf16x8*)&XLT[(wc * 64 + n * 16 + fr) * MSTR + kb + kq * 8];
        #pragma unroll
        for (int m = 0; m < 5; ++m)
            #pragma unroll
            for (int n = 0; n < 4; ++n)
                acc2[m][n] = __builtin_amdgcn_mfma_f32_16x16x32_bf16(
                                a2[m], b2[n], acc2[m][n], 0, 0, 0);
    }
    float bsv[4];
    #pragma unroll
    for (int n = 0; n < 4; ++n) bsv[n] = bias[wc * 64 + n * 16 + fr];
    #pragma unroll
    for (int m = 0; m < 5; ++m)
        #pragma unroll
        for (int n = 0; n < 4; ++n)
            #pragma unroll
            for (int j = 0; j < 4; ++j) {
                const int row = m * 16 + kq * 4 + j;
                if (row < N_) {
                    const int f = wc * 64 + n * 16 + fr;
                    Ybf[(size_t)b * C_ + row * H_ + f] = f2bf(acc2[m][n][j] + bsv[n]);
                }
            }
}

// ---------------------------------------------------------------------------
// Stage GC, dual-MFMA with fused BN+tanh(+residual update) staging.
// A = tanh(Yin*SC+SH) (+hin); hout = A if non-null.  Then xw = A@W (MFMA),
// y = attP*xw + bias -> Ybf.  In-place Yin==Ybf safe (staged before write).
// ---------------------------------------------------------------------------
__global__ __launch_bounds__(256) void k_gc(const ushort* __restrict__ Yin,
                                            const float* __restrict__ SC,
                                            const float* __restrict__ SH,
                                            const float* __restrict__ hin,
                                            float* __restrict__ hout,
                                            const ushort* __restrict__ WT,
                                            const ushort* __restrict__ attP,
                                            const float* __restrict__ bias,
                                            ushort* __restrict__ Ybf) {
    __shared__ __align__(16) ushort smem[256 * MSTR];   // 53,248 B (union)
    ushort* As  = smem;                                 // [80][ASTR] phase 1
    ushort* XLT = smem;                                 // [256][MSTR] phase 2
    const int b    = blockIdx.x;
    const int tid  = threadIdx.x;
    const int lane = tid & 63;
    const int wc   = tid >> 6;
    const int kq   = lane >> 4;
    const int fr   = lane & 15;

    const int ar1 = tid >> 2;
    const int ak  = (tid & 3) * 8;
    const int ar2 = 64 + (tid >> 2);

    for (int kt = 0; kt < 8; ++kt) {
        const int kk = kt * 32 + ak;
        *(bf16x8*)&As[ar1 * ASTR + kk] =
            stage8(Yin, SC, SH, hin, hout, ar1 * H_ + kk,
                   ((size_t)b * N_ + ar1) * H_ + kk);
    }
    if (tid < 64) {
        for (int kt = 0; kt < 8; ++kt) {
            const int kk = kt * 32 + ak;
            bf16x8 v = {};
            if (ar2 < N_)
                v = stage8(Yin, SC, SH, hin, hout, ar2 * H_ + kk,
                           ((size_t)b * N_ + ar2) * H_ + kk);
            *(bf16x8*)&As[ar2 * ASTR + kk] = v;
        }
    }
    __syncthreads();

    // phase 1 k-loop (B from global WT, L2-resident)
    f32x4 acc[5][4] = {};
    for (int kt = 0; kt < 8; ++kt) {
        const int kb = kt * 32;
        bf16x8 a[5], bv[4];
        #pragma unroll
        for (int m = 0; m < 5; ++m)
            a[m] = *(const bf16x8*)&As[(m * 16 + fr) * ASTR + kb + kq * 8];
        #pragma unroll
        for (int n = 0; n < 4; ++n)
            bv[n] = *(const bf16x8*)(WT + (size_t)(wc * 64 + n * 16 + fr) * H_ + kb + kq * 8);
        #pragma unroll
        for (int m = 0; m < 5; ++m)
            #pragma unroll
            for (int n = 0; n < 4; ++n)
                acc[m][n] = __builtin_amdgcn_mfma_f32_16x16x32_bf16(
                                a[m], bv[n], acc[m][n], 0, 0, 0);
    }
    __syncthreads();   // As dead -> reuse as XLT

    {
        bf16x8 z = {};
        *(bf16x8*)&XLT[(wc * 64 + lane) * MSTR + 80] = z;
        *(bf16x8*)&XLT[(wc * 64 + lane) * MSTR + 88] = z;
    }
    #pragma unroll
    for (int m = 0; m < 5; ++m)
        #pragma unroll
        for (int n = 0; n < 4; ++n)
            #pragma unroll
            for (int j = 0; j < 4; ++j)
                XLT[(wc * 64 + n * 16 + fr) * MSTR + m * 16 + kq * 4 + j] =
                    f2bf(acc[m][n][j]);
    // no barrier: each wave reads only its own strip

    f32x4 acc2[5][4] = {};
    for (int kt = 0; kt < 3; ++kt) {
        const int kb = kt * 32;
        bf16x8 a2[5], b2[4];
        #pragma unroll
        for (int m = 0; m < 5; ++m)
            a2[m] = *(const bf16x8*)(attP + (size_t)(m * 16 + fr) * 96 + kb + kq * 8);
        #pragma unroll
        for (int n = 0; n < 4; ++n)
            b2[n] = *(const bf16x8*)&XLT[(wc * 64 + n * 16 + fr) * MSTR + kb + kq * 8];
        #pragma unroll
        for (int m = 0; m < 5; ++m)
            #pragma unroll
            for (int n = 0; n < 4; ++n)
                acc2[m][n] = __builtin_amdgcn_mfma_f32_16x16x32_bf16(
                                a2[m], b2[n], acc2[m][n], 0, 0, 0);
    }
    float bsv[4];
    #pragma unroll
    for (int n = 0; n < 4; ++n) bsv[n] = bias[wc * 64 + n * 16 + fr];
    #pragma unroll
    for (int m = 0; m < 5; ++m)
        #pragma unroll
        for (int n = 0; n < 4; ++n)
            #pragma unroll
            for (int j = 0; j < 4; ++j) {
                const int row = m * 16 + kq * 4 + j;
                if (row < N_) {
                    const int f = wc * 64 + n * 16 + fr;
                    Ybf[(size_t)b * C_ + row * H_ + f] = f2bf(acc2[m][n][j] + bsv[n]);
                }
            }
}

// ---------------------------------------------------------------------------
// BN partial stats over batch group g (bf16 input).
// ---------------------------------------------------------------------------
__global__ __launch_bounds__(256) void k_stats(const ushort* __restrict__ v,
                                               float* __restrict__ P1,
                                               float* __restrict__ P2) {
    const int c4 = blockIdx.x * 256 + threadIdx.x;
    if (c4 >= C_ / 4) return;
    const int g = blockIdx.y;
    float4 s1 = make_float4(0.f,0.f,0.f,0.f), s2 = make_float4(0.f,0.f,0.f,0.f);
    const ushort4* vp = (const ushort4*)v;
    for (int i = 0; i < BPG_; ++i) {
        const int b = g * BPG_ + i;
        const ushort4 t4 = vp[(size_t)b * (C_ / 4) + c4];
        const float tx = bf2f(t4.x), ty = bf2f(t4.y),
                    tz = bf2f(t4.z), tw = bf2f(t4.w);
        s1.x += tx; s1.y += ty; s1.z += tz; s1.w += tw;
        s2.x = fmaf(tx, tx, s2.x); s2.y = fmaf(ty, ty, s2.y);
        s2.z = fmaf(tz, tz, s2.z); s2.w = fmaf(tw, tw, s2.w);
    }
    ((float4*)(P1 + (size_t)g * C_))[c4] = s1;
    ((float4*)(P2 + (size_t)g * C_))[c4] = s2;
}

// Finalize BN coefficients into SC/SH.
__global__ __launch_bounds__(256) void k_bnfin(const float* __restrict__ P1,
                                               const float* __restrict__ P2,
                                               const float* __restrict__ gam,
                                               const float* __restrict__ bet,
                                               float* __restrict__ SC,
                                               float* __restrict__ SH) {
    const int c4 = blockIdx.x * 256 + threadIdx.x;
    if (c4 >= C_ / 4) return;
    float4 s1 = make_float4(0.f,0.f,0.f,0.f), s2 = make_float4(0.f,0.f,0.f,0.f);
    for (int g = 0; g < NBG_; ++g) {
        const float4 a = ((const float4*)(P1 + (size_t)g * C_))[c4];
        const float4 b = ((const float4*)(P2 + (size_t)g * C_))[c4];
        s1.x += a.x; s1.y += a.y; s1.z += a.z; s1.w += a.w;
        s2.x += b.x; s2.y += b.y; s2.z += b.z; s2.w += b.w;
    }
    const float inv = 1.f / (float)B_;
    const float4 gm = ((const float4*)gam)[c4];
    const float4 bt = ((const float4*)bet)[c4];
    float4 sc, sh;
    float mu, var;
    mu = s1.x*inv; var = fmaf(-mu, mu, s2.x*inv); sc.x = gm.x*rsqrtf(var+EPS_); sh.x = bt.x - mu*sc.x;
    mu = s1.y*inv; var = fmaf(-mu, mu, s2.y*inv); sc.y = gm.y*rsqrtf(var+EPS_); sh.y = bt.y - mu*sc.y;
    mu = s1.z*inv; var = fmaf(-mu, mu, s2.z*inv); sc.z = gm.z*rsqrtf(var+EPS_); sh.z = bt.z - mu*sc.z;
    mu = s1.w*inv; var = fmaf(-mu, mu, s2.w*inv); sc.w = gm.w*rsqrtf(var+EPS_); sh.w = bt.w - mu*sc.w;
    ((float4*)SC)[c4] = sc;
    ((float4*)SH)[c4] = sh;
}

// ---------------------------------------------------------------------------
// Fully fused decoder with fused final h-update:
// A = tanh(Yin*SC+SH) + h5  (bf16 staged); then dual-MFMA + iDCT + splice.
// ---------------------------------------------------------------------------
__global__ __launch_bounds__(256) void k_dec2(const ushort* __restrict__ Yin,
                                              const float* __restrict__ SC,
                                              const float* __restrict__ SH,
                                              const float* __restrict__ hin,
                                              const ushort* __restrict__ dwT,
                                              const ushort* __restrict__ aPd,
                                              const float* __restrict__ db,
                                              const float* __restrict__ xd,
                                              const float* __restrict__ itm,
                                              const float* __restrict__ x,
                                              float* __restrict__ out) {
    __shared__ __align__(16) ushort As[80 * ASTR];   // 42,240 B
    __shared__ __align__(16) ushort oT[32 * MSTR];   //  6,656 B
    __shared__ float odL[N_ * 21];                   //  5,544 B
    __shared__ float itL[T_ * D_];                   // 10,000 B
    const int b    = blockIdx.x;
    const int tid  = threadIdx.x;
    const int lane = tid & 63;
    const int wc   = tid >> 6;
    const int kq   = lane >> 4;
    const int fr   = lane & 15;

    for (int i = tid; i < T_*D_; i += 256) {
        const int t = i / D_, d = i % D_;
        itL[i] = itm[t * T_ + d];
    }
    const int ar1 = tid >> 2;
    const int ak  = (tid & 3) * 8;
    const int ar2 = 64 + (tid >> 2);
    for (int kt = 0; kt < 8; ++kt) {
        const int kk = kt * 32 + ak;
        *(bf16x8*)&As[ar1 * ASTR + kk] =
            stage8(Yin, SC, SH, hin, nullptr, ar1 * H_ + kk,
                   ((size_t)b * N_ + ar1) * H_ + kk);
    }
    if (tid < 64) {
        for (int kt = 0; kt < 8; ++kt) {
            const int kk = kt * 32 + ak;
            bf16x8 v = {};
            if (ar2 < N_)
                v = stage8(Yin, SC, SH, hin, nullptr, ar2 * H_ + kk,
                           ((size_t)b * N_ + ar2) * H_ + kk);
            *(bf16x8*)&As[ar2 * ASTR + kk] = v;
        }
    }
    if (tid >= 128 && tid < 160) {
        bf16x8 z = {};
        *(bf16x8*)&oT[(tid - 128) * MSTR + 80] = z;
        *(bf16x8*)&oT[(tid - 128) * MSTR + 88] = z;
    }
    __syncthreads();

    if (wc < 2) {
        f32x4 acc[5] = {};
        for (int kt = 0; kt < 8; ++kt) {
            const int kb = kt * 32;
            bf16x8 a[5];
            #pragma unroll
            for (int m = 0; m < 5; ++m)
                a[m] = *(const bf16x8*)&As[(m * 16 + fr) * ASTR + kb + kq * 8];
            const bf16x8 bv = *(const bf16x8*)(dwT + (size_t)(wc * 16 + fr) * H_ + kb + kq * 8);
            #pragma unroll
            for (int m = 0; m < 5; ++m)
                acc[m] = __builtin_amdgcn_mfma_f32_16x16x32_bf16(a[m], bv, acc[m], 0, 0, 0);
        }
        #pragma unroll
        for (int m = 0; m < 5; ++m)
            #pragma unroll
            for (int j = 0; j < 4; ++j)
                oT[(wc * 16 + fr) * MSTR + m * 16 + kq * 4 + j] = f2bf(acc[m][j]);
    }
    __syncthreads();

    if (wc < 2) {
        f32x4 acc2[5] = {};
        for (int kt = 0; kt < 3; ++kt) {
            const int kb = kt * 32;
            bf16x8 a2[5];
            #pragma unroll
            for (int m = 0; m < 5; ++m)
                a2[m] = *(const bf16x8*)(aPd + (size_t)(m * 16 + fr) * 96 + kb + kq * 8);
            const bf16x8 b2 = *(const bf16x8*)&oT[(wc * 16 + fr) * MSTR + kb + kq * 8];
            #pragma unroll
            for (int m = 0; m < 5; ++m)
                acc2[m] = __builtin_amdgcn_mfma_f32_16x16x32_bf16(a2[m], b2, acc2[m], 0, 0, 0);
        }
        const int d = wc * 16 + fr;
        if (d < D_) {
            const float dbv = db[d];
            #pragma unroll
            for (int m = 0; m < 5; ++m)
                #pragma unroll
                for (int j = 0; j < 4; ++j) {
                    const int n = m * 16 + kq * 4 + j;
                    if (n < N_)
                        odL[n * 21 + d] = acc2[m][j] + dbv
                                        + xd[(size_t)b * N_ * D_ + n * D_ + d];
                }
        }
    }
    __syncthreads();

    const float* xb = x + (size_t)b * T_ * N_;
    float* ob = out + (size_t)b * T_ * N_;
    for (int q = tid; q < T_*N_; q += 256) {
        const int t = q / N_, n = q % N_;
        float o;
        if (t < THIS_) {
            o = xb[q];
        } else {
            o = 0.f;
            #pragma unroll 4
            for (int d = 0; d < D_; ++d)
                o = fmaf(itL[t * D_ + d], odL[n * 21 + d], o);
        }
        ob[q] = o;
    }
}

// ---------------------------------------------------------------------------
extern "C" void kernel_launch(void* const* d_in, const int* in_sizes, int n_in,
                              void* d_out, int out_size, void* d_ws, size_t ws_size,
                              hipStream_t stream) {
    const float* x    = (const float*)d_in[0];
    const float* tm   = (const float*)d_in[1];
    const float* itm  = (const float*)d_in[2];
    const float* encw = (const float*)d_in[3];
    const float* enca = (const float*)d_in[4];
    const float* encb = (const float*)d_in[5];
    const float* bn0g = (const float*)d_in[6];
    const float* bn0b = (const float*)d_in[7];
    const float* g1w  = (const float*)d_in[8];
    const float* g1a  = (const float*)d_in[9];
    const float* g1b  = (const float*)d_in[10];
    const float* b1g  = (const float*)d_in[11];
    const float* b1b  = (const float*)d_in[12];
    const float* g2w  = (const float*)d_in[13];
    const float* g2a  = (const float*)d_in[14];
    const float* g2b  = (const float*)d_in[15];
    const float* b2g  = (const float*)d_in[16];
    const float* b2b  = (const float*)d_in[17];
    const float* decw = (const float*)d_in[18];
    const float* deca = (const float*)d_in[19];
    const float* decb = (const float*)d_in[20];
    float* out = (float*)d_out;

    // ws layout (round-1 footprint, proven)
    float* ws = (float*)d_ws;
    float* xd = ws;                         //   675840 floats
    float* h  = xd + 675840;                //  8650752
    float* slotA = h + 8650752;             //  8650752 (bf16 buffers)
    float* slotB = slotA + 8650752;         //  8650752 (unused)
    float* P1 = slotB + 8650752;            //   270336
    float* P2 = P1 + 270336;                //   270336
    float* SC = P2 + 270336;                //    16896
    float* SH = SC + 16896;                 //    16896
    ushort* WT1 = (ushort*)slotA;           //   393216 u16
    ushort* WT2 = WT1 + 393216;             //   393216 u16
    ushort* ybf = WT2 + 393216;             //  8650752 u16
    ushort* aP1 = ybf + 8650752;            //    46080 u16
    ushort* aP2 = aP1 + 46080;              //    46080 u16
    ushort* aPd = aP2 + 46080;              //     7680 u16
    ushort* aPe = aPd + 7680;               //     7680 u16
    ushort* dwT = aPe + 7680;               //     8192 u16
    ushort* ewT = dwT + 8192;               //     8192 u16

    const dim3 blk(256);
    const dim3 gS(17, NBG_);

    // preprocessing
    k_wtrans<<<dim3(4,4,ST_), blk, 0, stream>>>(g1w, WT1);
    k_wtrans<<<dim3(4,4,ST_), blk, 0, stream>>>(g2w, WT2);
    k_aprep<<<180, blk, 0, stream>>>(g1a, aP1, ST_);
    k_aprep<<<180, blk, 0, stream>>>(g2a, aP2, ST_);
    k_aprep<<<30, blk, 0, stream>>>(deca, aPd, 1);
    k_aprep<<<30, blk, 0, stream>>>(enca, aPe, 1);
    k_dwprep<<<32, blk, 0, stream>>>(decw, dwT);
    k_ewprep<<<32, blk, 0, stream>>>(encw, ewT);

    k_dct<<<B_, blk, 0, stream>>>(x, tm, xd);

    // encoder (dual-MFMA) -> ybf; bn0 stats+coefs
    k_genc2<<<B_, blk, 0, stream>>>(xd, ewT, aPe, encb, ybf);
    k_stats<<<gS, blk, 0, stream>>>(ybf, P1, P2);
    k_bnfin<<<17, blk, 0, stream>>>(P1, P2, bn0g, bn0b, SC, SH);

    for (int s = 0; s < ST_; ++s) {
        // gc1: A = tanh(bn(y)) (+h for s>0); h updated; ybf = att1*(A@w1)+b1
        k_gc<<<B_, blk, 0, stream>>>(ybf, SC, SH, s ? h : nullptr, h,
                                     WT1 + s*H_*H_, aP1 + s*7680,
                                     g1b + s*H_, ybf);
        k_stats<<<gS, blk, 0, stream>>>(ybf, P1, P2);
        k_bnfin<<<17, blk, 0, stream>>>(P1, P2, b1g + s*C_, b1b + s*C_, SC, SH);
        // gc2: A = tanh(bn1(y)); ybf = att2*(A@w2)+b2
        k_gc<<<B_, blk, 0, stream>>>(ybf, SC, SH, nullptr, nullptr,
                                     WT2 + s*H_*H_, aP2 + s*7680,
                                     g2b + s*H_, ybf);
        k_stats<<<gS, blk, 0, stream>>>(ybf, P1, P2);
        k_bnfin<<<17, blk, 0, stream>>>(P1, P2, b2g + s*C_, b2b + s*C_, SC, SH);
    }

    // decoder with fused final h-update (h6 = tanh(bn2(y2_5)) + h5)
    k_dec2<<<B_, blk, 0, stream>>>(ybf, SC, SH, h, dwT, aPd, decb, xd, itm,
                                   x, out);
}

// Round 14
// 598.385 us; speedup vs baseline: 12.0479x; 1.0992x over previous
//
#include <hip/hip_runtime.h>
#include <math.h>

// Problem dims
#define B_    512
#define T_    125
#define N_    66
#define D_    20
#define H_    256
#define ST_   6
#define THIS_ 25
#define C_    (N_*H_)     // 16896 channels for BN
#define NBGS  64          // batch groups for BN stats
#define BPGS  (B_/NBGS)   // 8
#define EPS_  1e-5f

#define ASTR  264         // As row stride (ushorts)
#define MSTR  104         // XLT/oT row stride (ushorts), 96 used
#define ESTR  40          // genc As row stride (32 used)

typedef __attribute__((ext_vector_type(8))) short bf16x8;
typedef __attribute__((ext_vector_type(4))) float f32x4;

__device__ __forceinline__ ushort f2bf(float f) {
    unsigned u = __float_as_uint(f);
    u += 0x7fffu + ((u >> 16) & 1u);       // round-to-nearest-even
    return (ushort)(u >> 16);
}
__device__ __forceinline__ float bf2f(ushort h) {
    return __uint_as_float((unsigned)h << 16);
}

// tanh(x) = 1 - 2/(e^{2x}+1); v_exp/v_rcp are ~1ulp, exact at +-inf.
__device__ __forceinline__ float fast_tanh(float x) {
    float t, r;
    const float z = x * 2.885390081777927f;   // 2*log2(e)
    asm("v_exp_f32 %0, %1" : "=v"(t) : "v"(z));
    const float tp1 = t + 1.f;
    asm("v_rcp_f32 %0, %1" : "=v"(r) : "v"(tp1));
    return 1.f - 2.f * r;
}

// Fused staging element: t = tanh(y*sc+sh) (+ hin bf16); optional hout (bf16).
__device__ __forceinline__ bf16x8 stage8(const ushort* __restrict__ Yin,
                                         const float* __restrict__ SC,
                                         const float* __restrict__ SH,
                                         const ushort* __restrict__ hin,
                                         ushort* __restrict__ hout,
                                         int ch, size_t g) {
    const bf16x8 raw = *(const bf16x8*)(Yin + g);
    float sv[8], hv[8], t[8];
    *(float4*)&sv[0] = *(const float4*)(SC + ch);
    *(float4*)&sv[4] = *(const float4*)(SC + ch + 4);
    *(float4*)&hv[0] = *(const float4*)(SH + ch);
    *(float4*)&hv[4] = *(const float4*)(SH + ch + 4);
    #pragma unroll
    for (int j = 0; j < 8; ++j)
        t[j] = fast_tanh(fmaf(bf2f((ushort)raw[j]), sv[j], hv[j]));
    if (hin) {
        const bf16x8 rv = *(const bf16x8*)(hin + g);
        #pragma unroll
        for (int j = 0; j < 8; ++j) t[j] += bf2f((ushort)rv[j]);
    }
    bf16x8 v;
    #pragma unroll
    for (int j = 0; j < 8; ++j) v[j] = (short)f2bf(t[j]);
    if (hout) *(bf16x8*)(hout + g) = v;
    return v;
}

// ---------------------------------------------------------------------------
// Weight transpose+convert: WT[s][f][k] = bf16(W[s][k][f]).  grid (4,4,ST).
// ---------------------------------------------------------------------------
__global__ __launch_bounds__(256) void k_wtrans(const float* __restrict__ W,
                                                ushort* __restrict__ WT) {
    __shared__ ushort t[64][65];
    const int s = blockIdx.z;
    const int kb = blockIdx.x * 64, fb = blockIdx.y * 64;
    const int tid = threadIdx.x;
    const int c = tid & 63;
    const int r4 = tid >> 6;
    for (int rr = 0; rr < 64; rr += 4) {
        const int r = rr + r4;
        t[r][c] = f2bf(W[(size_t)s * 65536 + (size_t)(kb + r) * 256 + fb + c]);
    }
    __syncthreads();
    for (int rr = 0; rr < 64; rr += 4) {
        const int f = rr + r4;
        WT[(size_t)s * 65536 + (size_t)(fb + f) * 256 + kb + c] = t[c][f];
    }
}

// ---------------------------------------------------------------------------
// att pad+convert: P[s][r][m] = bf16(A[s][r][m]) for r,m<66 else 0.  [80][96]
// ---------------------------------------------------------------------------
__global__ __launch_bounds__(256) void k_aprep(const float* __restrict__ A,
                                               ushort* __restrict__ P,
                                               int S) {
    const int idx = blockIdx.x * 256 + threadIdx.x;
    if (idx >= S * 80 * 96) return;
    const int s = idx / 7680, rm = idx % 7680;
    const int r = rm / 96, m = rm % 96;
    const float v = (r < N_ && m < N_) ? A[(size_t)s * N_ * N_ + r * N_ + m] : 0.f;
    P[idx] = f2bf(v);
}

// ---------------------------------------------------------------------------
// decw pad+transpose: dwT[f][k] = bf16(decw[k][f]) for f<20 else 0.  [32][256]
// ---------------------------------------------------------------------------
__global__ __launch_bounds__(256) void k_dwprep(const float* __restrict__ dw,
                                                ushort* __restrict__ dwT) {
    const int idx = blockIdx.x * 256 + threadIdx.x;
    if (idx >= 32 * 256) return;
    const int f = idx / 256, k = idx % 256;
    const float v = (f < D_) ? dw[(size_t)k * D_ + f] : 0.f;
    dwT[idx] = f2bf(v);
}

// ---------------------------------------------------------------------------
// encw pad+transpose: ewT[f][k] = bf16(encw[k][f]) for k<20 else 0.  [256][32]
// ---------------------------------------------------------------------------
__global__ __launch_bounds__(256) void k_ewprep(const float* __restrict__ ew,
                                                ushort* __restrict__ ewT) {
    const int idx = blockIdx.x * 256 + threadIdx.x;
    if (idx >= 256 * 32) return;
    const int f = idx / 32, k = idx % 32;
    const float v = (k < D_) ? ew[(size_t)k * H_ + f] : 0.f;
    ewT[idx] = f2bf(v);
}

// ---------------------------------------------------------------------------
// DCT along time: xd[b][n][d] = sum_t trans[d][t] * x[b][t][n]
// ---------------------------------------------------------------------------
__global__ __launch_bounds__(256) void k_dct(const float* __restrict__ x,
                                             const float* __restrict__ tm,
                                             float* __restrict__ xd) {
    __shared__ float xs[T_*N_];
    __shared__ float tl[D_*T_];
    const int b = blockIdx.x, tid = threadIdx.x;
    const float* xb = x + (size_t)b * T_ * N_;
    for (int i = tid; i < T_*N_; i += 256) xs[i] = xb[i];
    for (int i = tid; i < D_*T_; i += 256) tl[i] = tm[i];
    __syncthreads();
    for (int p = tid; p < N_*D_; p += 256) {
        const int n = p / D_, d = p % D_;
        float acc = 0.f;
        for (int t = 0; t < T_; ++t)
            acc = fmaf(tl[d*T_ + t], xs[t*N_ + n], acc);
        xd[(size_t)b * N_ * D_ + p] = acc;
    }
}

// ---------------------------------------------------------------------------
// Encoder GC, dual-MFMA: per-batch block. Phase 1 K=32 (20 real), phase 2 attP.
// ---------------------------------------------------------------------------
__global__ __launch_bounds__(256) void k_genc2(const float* __restrict__ xd,
                                               const ushort* __restrict__ ewT,
                                               const ushort* __restrict__ attP,
                                               const float* __restrict__ bias,
                                               ushort* __restrict__ Ybf) {
    __shared__ __align__(16) ushort As[80 * ESTR];       //  6,400 B
    __shared__ __align__(16) ushort XLT[256 * MSTR];     // 53,248 B
    const int b    = blockIdx.x;
    const int tid  = threadIdx.x;
    const int lane = tid & 63;
    const int wc   = tid >> 6;
    const int kq   = lane >> 4;
    const int fr   = lane & 15;

    const int ar1 = tid >> 2;
    const int ak  = (tid & 3) * 8;
    const int ar2 = 64 + (tid >> 2);
    {
        bf16x8 v;
        #pragma unroll
        for (int j = 0; j < 8; ++j) {
            const int k = ak + j;
            v[j] = (k < D_) ? (short)f2bf(xd[((size_t)b * N_ + ar1) * D_ + k]) : (short)0;
        }
        *(bf16x8*)&As[ar1 * ESTR + ak] = v;
    }
    if (tid < 64) {
        bf16x8 v;
        #pragma unroll
        for (int j = 0; j < 8; ++j) {
            const int k = ak + j;
            v[j] = (ar2 < N_ && k < D_) ?
                   (short)f2bf(xd[((size_t)b * N_ + ar2) * D_ + k]) : (short)0;
        }
        *(bf16x8*)&As[ar2 * ESTR + ak] = v;
    }
    __syncthreads();

    f32x4 acc[5][4] = {};
    {
        bf16x8 a[5], bv[4];
        #pragma unroll
        for (int m = 0; m < 5; ++m)
            a[m] = *(const bf16x8*)&As[(m * 16 + fr) * ESTR + kq * 8];
        #pragma unroll
        for (int n = 0; n < 4; ++n)
            bv[n] = *(const bf16x8*)(ewT + (size_t)(wc * 64 + n * 16 + fr) * 32 + kq * 8);
        #pragma unroll
        for (int m = 0; m < 5; ++m)
            #pragma unroll
            for (int n = 0; n < 4; ++n)
                acc[m][n] = __builtin_amdgcn_mfma_f32_16x16x32_bf16(
                                a[m], bv[n], acc[m][n], 0, 0, 0);
    }

    {
        bf16x8 z = {};
        *(bf16x8*)&XLT[(wc * 64 + lane) * MSTR + 80] = z;
        *(bf16x8*)&XLT[(wc * 64 + lane) * MSTR + 88] = z;
    }
    #pragma unroll
    for (int m = 0; m < 5; ++m)
        #pragma unroll
        for (int n = 0; n < 4; ++n)
            #pragma unroll
            for (int j = 0; j < 4; ++j)
                XLT[(wc * 64 + n * 16 + fr) * MSTR + m * 16 + kq * 4 + j] =
                    f2bf(acc[m][n][j]);

    f32x4 acc2[5][4] = {};
    for (int kt = 0; kt < 3; ++kt) {
        const int kb = kt * 32;
        bf16x8 a2[5], b2[4];
        #pragma unroll
        for (int m = 0; m < 5; ++m)
            a2[m] = *(const bf16x8*)(attP + (size_t)(m * 16 + fr) * 96 + kb + kq * 8);
        #pragma unroll
        for (int n = 0; n < 4; ++n)
            b2[n] = *(const bf16x8*)&XLT[(wc * 64 + n * 16 + fr) * MSTR + kb + kq * 8];
        #pragma unroll
        for (int m = 0; m < 5; ++m)
            #pragma unroll
            for (int n = 0; n < 4; ++n)
                acc2[m][n] = __builtin_amdgcn_mfma_f32_16x16x32_bf16(
                                a2[m], b2[n], acc2[m][n], 0, 0, 0);
    }
    float bsv[4];
    #pragma unroll
    for (int n = 0; n < 4; ++n) bsv[n] = bias[wc * 64 + n * 16 + fr];
    #pragma unroll
    for (int m = 0; m < 5; ++m)
        #pragma unroll
        for (int n = 0; n < 4; ++n)
            #pragma unroll
            for (int j = 0; j < 4; ++j) {
                const int row = m * 16 + kq * 4 + j;
                if (row < N_) {
                    const int f = wc * 64 + n * 16 + fr;
                    Ybf[(size_t)b * C_ + row * H_ + f] = f2bf(acc2[m][n][j] + bsv[n]);
                }
            }
}

// ---------------------------------------------------------------------------
// Stage GC, dual-MFMA with fused BN+tanh(+residual update, bf16 h) staging.
// ---------------------------------------------------------------------------
__global__ __launch_bounds__(256) void k_gc(const ushort* __restrict__ Yin,
                                            const float* __restrict__ SC,
                                            const float* __restrict__ SH,
                                            const ushort* __restrict__ hin,
                                            ushort* __restrict__ hout,
                                            const ushort* __restrict__ WT,
                                            const ushort* __restrict__ attP,
                                            const float* __restrict__ bias,
                                            ushort* __restrict__ Ybf) {
    __shared__ __align__(16) ushort smem[256 * MSTR];   // 53,248 B (union)
    ushort* As  = smem;                                 // [80][ASTR] phase 1
    ushort* XLT = smem;                                 // [256][MSTR] phase 2
    const int b    = blockIdx.x;
    const int tid  = threadIdx.x;
    const int lane = tid & 63;
    const int wc   = tid >> 6;
    const int kq   = lane >> 4;
    const int fr   = lane & 15;

    const int ar1 = tid >> 2;
    const int ak  = (tid & 3) * 8;
    const int ar2 = 64 + (tid >> 2);

    for (int kt = 0; kt < 8; ++kt) {
        const int kk = kt * 32 + ak;
        *(bf16x8*)&As[ar1 * ASTR + kk] =
            stage8(Yin, SC, SH, hin, hout, ar1 * H_ + kk,
                   ((size_t)b * N_ + ar1) * H_ + kk);
    }
    if (tid < 64) {
        for (int kt = 0; kt < 8; ++kt) {
            const int kk = kt * 32 + ak;
            bf16x8 v = {};
            if (ar2 < N_)
                v = stage8(Yin, SC, SH, hin, hout, ar2 * H_ + kk,
                           ((size_t)b * N_ + ar2) * H_ + kk);
            *(bf16x8*)&As[ar2 * ASTR + kk] = v;
        }
    }
    __syncthreads();

    // phase 1 k-loop (B from global WT, L2-resident)
    f32x4 acc[5][4] = {};
    for (int kt = 0; kt < 8; ++kt) {
        const int kb = kt * 32;
        bf16x8 a[5], bv[4];
        #pragma unroll
        for (int m = 0; m < 5; ++m)
            a[m] = *(const bf16x8*)&As[(m * 16 + fr) * ASTR + kb + kq * 8];
        #pragma unroll
        for (int n = 0; n < 4; ++n)
            bv[n] = *(const bf16x8*)(WT + (size_t)(wc * 64 + n * 16 + fr) * H_ + kb + kq * 8);
        #pragma unroll
        for (int m = 0; m < 5; ++m)
            #pragma unroll
            for (int n = 0; n < 4; ++n)
                acc[m][n] = __builtin_amdgcn_mfma_f32_16x16x32_bf16(
                                a[m], bv[n], acc[m][n], 0, 0, 0);
    }
    __syncthreads();   // As dead -> reuse as XLT

    {
        bf16x8 z = {};
        *(bf16x8*)&XLT[(wc * 64 + lane) * MSTR + 80] = z;
        *(bf16x8*)&XLT[(wc * 64 + lane) * MSTR + 88] = z;
    }
    #pragma unroll
    for (int m = 0; m < 5; ++m)
        #pragma unroll
        for (int n = 0; n < 4; ++n)
            #pragma unroll
            for (int j = 0; j < 4; ++j)
                XLT[(wc * 64 + n * 16 + fr) * MSTR + m * 16 + kq * 4 + j] =
                    f2bf(acc[m][n][j]);
    // no barrier: each wave reads only its own strip

    f32x4 acc2[5][4] = {};
    for (int kt = 0; kt < 3; ++kt) {
        const int kb = kt * 32;
        bf16x8 a2[5], b2[4];
        #pragma unroll
        for (int m = 0; m < 5; ++m)
            a2[m] = *(const bf16x8*)(attP + (size_t)(m * 16 + fr) * 96 + kb + kq * 8);
        #pragma unroll
        for (int n = 0; n < 4; ++n)
            b2[n] = *(const bf16x8*)&XLT[(wc * 64 + n * 16 + fr) * MSTR + kb + kq * 8];
        #pragma unroll
        for (int m = 0; m < 5; ++m)
            #pragma unroll
            for (int n = 0; n < 4; ++n)
                acc2[m][n] = __builtin_amdgcn_mfma_f32_16x16x32_bf16(
                                a2[m], b2[n], acc2[m][n], 0, 0, 0);
    }
    float bsv[4];
    #pragma unroll
    for (int n = 0; n < 4; ++n) bsv[n] = bias[wc * 64 + n * 16 + fr];
    #pragma unroll
    for (int m = 0; m < 5; ++m)
        #pragma unroll
        for (int n = 0; n < 4; ++n)
            #pragma unroll
            for (int j = 0; j < 4; ++j) {
                const int row = m * 16 + kq * 4 + j;
                if (row < N_) {
                    const int f = wc * 64 + n * 16 + fr;
                    Ybf[(size_t)b * C_ + row * H_ + f] = f2bf(acc2[m][n][j] + bsv[n]);
                }
            }
}

// ---------------------------------------------------------------------------
// BN partial stats over batch group g (bf16 input).  grid (17, NBGS).
// ---------------------------------------------------------------------------
__global__ __launch_bounds__(256) void k_stats(const ushort* __restrict__ v,
                                               float* __restrict__ P1,
                                               float* __restrict__ P2) {
    const int c4 = blockIdx.x * 256 + threadIdx.x;
    if (c4 >= C_ / 4) return;
    const int g = blockIdx.y;
    float4 s1 = make_float4(0.f,0.f,0.f,0.f), s2 = make_float4(0.f,0.f,0.f,0.f);
    const ushort4* vp = (const ushort4*)v;
    for (int i = 0; i < BPGS; ++i) {
        const int b = g * BPGS + i;
        const ushort4 t4 = vp[(size_t)b * (C_ / 4) + c4];
        const float tx = bf2f(t4.x), ty = bf2f(t4.y),
                    tz = bf2f(t4.z), tw = bf2f(t4.w);
        s1.x += tx; s1.y += ty; s1.z += tz; s1.w += tw;
        s2.x = fmaf(tx, tx, s2.x); s2.y = fmaf(ty, ty, s2.y);
        s2.z = fmaf(tz, tz, s2.z); s2.w = fmaf(tw, tw, s2.w);
    }
    ((float4*)(P1 + (size_t)g * C_))[c4] = s1;
    ((float4*)(P2 + (size_t)g * C_))[c4] = s2;
}

// Finalize BN coefficients into SC/SH (reduce NBGS groups).
__global__ __launch_bounds__(256) void k_bnfin(const float* __restrict__ P1,
                                               const float* __restrict__ P2,
                                               const float* __restrict__ gam,
                                               const float* __restrict__ bet,
                                               float* __restrict__ SC,
                                               float* __restrict__ SH) {
    const int c4 = blockIdx.x * 256 + threadIdx.x;
    if (c4 >= C_ / 4) return;
    float4 s1 = make_float4(0.f,0.f,0.f,0.f), s2 = make_float4(0.f,0.f,0.f,0.f);
    for (int g = 0; g < NBGS; ++g) {
        const float4 a = ((const float4*)(P1 + (size_t)g * C_))[c4];
        const float4 b = ((const float4*)(P2 + (size_t)g * C_))[c4];
        s1.x += a.x; s1.y += a.y; s1.z += a.z; s1.w += a.w;
        s2.x += b.x; s2.y += b.y; s2.z += b.z; s2.w += b.w;
    }
    const float inv = 1.f / (float)B_;
    const float4 gm = ((const float4*)gam)[c4];
    const float4 bt = ((const float4*)bet)[c4];
    float4 sc, sh;
    float mu, var;
    mu = s1.x*inv; var = fmaf(-mu, mu, s2.x*inv); sc.x = gm.x*rsqrtf(var+EPS_); sh.x = bt.x - mu*sc.x;
    mu = s1.y*inv; var = fmaf(-mu, mu, s2.y*inv); sc.y = gm.y*rsqrtf(var+EPS_); sh.y = bt.y - mu*sc.y;
    mu = s1.z*inv; var = fmaf(-mu, mu, s2.z*inv); sc.z = gm.z*rsqrtf(var+EPS_); sh.z = bt.z - mu*sc.z;
    mu = s1.w*inv; var = fmaf(-mu, mu, s2.w*inv); sc.w = gm.w*rsqrtf(var+EPS_); sh.w = bt.w - mu*sc.w;
    ((float4*)SC)[c4] = sc;
    ((float4*)SH)[c4] = sh;
}

// ---------------------------------------------------------------------------
// Fully fused decoder with fused final h-update (bf16 h):
// ---------------------------------------------------------------------------
__global__ __launch_bounds__(256) void k_dec2(const ushort* __restrict__ Yin,
                                              const float* __restrict__ SC,
                                              const float* __restrict__ SH,
                                              const ushort* __restrict__ hin,
                                              const ushort* __restrict__ dwT,
                                              const ushort* __restrict__ aPd,
                                              const float* __restrict__ db,
                                              const float* __restrict__ xd,
                                              const float* __restrict__ itm,
                                              const float* __restrict__ x,
                                              float* __restrict__ out) {
    __shared__ __align__(16) ushort As[80 * ASTR];   // 42,240 B
    __shared__ __align__(16) ushort oT[32 * MSTR];   //  6,656 B
    __shared__ float odL[N_ * 21];                   //  5,544 B
    __shared__ float itL[T_ * D_];                   // 10,000 B
    const int b    = blockIdx.x;
    const int tid  = threadIdx.x;
    const int lane = tid & 63;
    const int wc   = tid >> 6;
    const int kq   = lane >> 4;
    const int fr   = lane & 15;

    for (int i = tid; i < T_*D_; i += 256) {
        const int t = i / D_, d = i % D_;
        itL[i] = itm[t * T_ + d];
    }
    const int ar1 = tid >> 2;
    const int ak  = (tid & 3) * 8;
    const int ar2 = 64 + (tid >> 2);
    for (int kt = 0; kt < 8; ++kt) {
        const int kk = kt * 32 + ak;
        *(bf16x8*)&As[ar1 * ASTR + kk] =
            stage8(Yin, SC, SH, hin, nullptr, ar1 * H_ + kk,
                   ((size_t)b * N_ + ar1) * H_ + kk);
    }
    if (tid < 64) {
        for (int kt = 0; kt < 8; ++kt) {
            const int kk = kt * 32 + ak;
            bf16x8 v = {};
            if (ar2 < N_)
                v = stage8(Yin, SC, SH, hin, nullptr, ar2 * H_ + kk,
                           ((size_t)b * N_ + ar2) * H_ + kk);
            *(bf16x8*)&As[ar2 * ASTR + kk] = v;
        }
    }
    if (tid >= 128 && tid < 160) {
        bf16x8 z = {};
        *(bf16x8*)&oT[(tid - 128) * MSTR + 80] = z;
        *(bf16x8*)&oT[(tid - 128) * MSTR + 88] = z;
    }
    __syncthreads();

    if (wc < 2) {
        f32x4 acc[5] = {};
        for (int kt = 0; kt < 8; ++kt) {
            const int kb = kt * 32;
            bf16x8 a[5];
            #pragma unroll
            for (int m = 0; m < 5; ++m)
                a[m] = *(const bf16x8*)&As[(m * 16 + fr) * ASTR + kb + kq * 8];
            const bf16x8 bv = *(const bf16x8*)(dwT + (size_t)(wc * 16 + fr) * H_ + kb + kq * 8);
            #pragma unroll
            for (int m = 0; m < 5; ++m)
                acc[m] = __builtin_amdgcn_mfma_f32_16x16x32_bf16(a[m], bv, acc[m], 0, 0, 0);
        }
        #pragma unroll
        for (int m = 0; m < 5; ++m)
            #pragma unroll
            for (int j = 0; j < 4; ++j)
                oT[(wc * 16 + fr) * MSTR + m * 16 + kq * 4 + j] = f2bf(acc[m][j]);
    }
    __syncthreads();

    if (wc < 2) {
        f32x4 acc2[5] = {};
        for (int kt = 0; kt < 3; ++kt) {
            const int kb = kt * 32;
            bf16x8 a2[5];
            #pragma unroll
            for (int m = 0; m < 5; ++m)
                a2[m] = *(const bf16x8*)(aPd + (size_t)(m * 16 + fr) * 96 + kb + kq * 8);
            const bf16x8 b2 = *(const bf16x8*)&oT[(wc * 16 + fr) * MSTR + kb + kq * 8];
            #pragma unroll
            for (int m = 0; m < 5; ++m)
                acc2[m] = __builtin_amdgcn_mfma_f32_16x16x32_bf16(a2[m], b2, acc2[m], 0, 0, 0);
        }
        const int d = wc * 16 + fr;
        if (d < D_) {
            const float dbv = db[d];
            #pragma unroll
            for (int m = 0; m < 5; ++m)
                #pragma unroll
                for (int j = 0; j < 4; ++j) {
                    const int n = m * 16 + kq * 4 + j;
                    if (n < N_)
                        odL[n * 21 + d] = acc2[m][j] + dbv
                                        + xd[(size_t)b * N_ * D_ + n * D_ + d];
                }
        }
    }
    __syncthreads();

    const float* xb = x + (size_t)b * T_ * N_;
    float* ob = out + (size_t)b * T_ * N_;
    for (int q = tid; q < T_*N_; q += 256) {
        const int t = q / N_, n = q % N_;
        float o;
        if (t < THIS_) {
            o = xb[q];
        } else {
            o = 0.f;
            #pragma unroll 4
            for (int d = 0; d < D_; ++d)
                o = fmaf(itL[t * D_ + d], odL[n * 21 + d], o);
        }
        ob[q] = o;
    }
}

// ---------------------------------------------------------------------------
extern "C" void kernel_launch(void* const* d_in, const int* in_sizes, int n_in,
                              void* d_out, int out_size, void* d_ws, size_t ws_size,
                              hipStream_t stream) {
    const float* x    = (const float*)d_in[0];
    const float* tm   = (const float*)d_in[1];
    const float* itm  = (const float*)d_in[2];
    const float* encw = (const float*)d_in[3];
    const float* enca = (const float*)d_in[4];
    const float* encb = (const float*)d_in[5];
    const float* bn0g = (const float*)d_in[6];
    const float* bn0b = (const float*)d_in[7];
    const float* g1w  = (const float*)d_in[8];
    const float* g1a  = (const float*)d_in[9];
    const float* g1b  = (const float*)d_in[10];
    const float* b1g  = (const float*)d_in[11];
    const float* b1b  = (const float*)d_in[12];
    const float* g2w  = (const float*)d_in[13];
    const float* g2a  = (const float*)d_in[14];
    const float* g2b  = (const float*)d_in[15];
    const float* b2g  = (const float*)d_in[16];
    const float* b2b  = (const float*)d_in[17];
    const float* decw = (const float*)d_in[18];
    const float* deca = (const float*)d_in[19];
    const float* decb = (const float*)d_in[20];
    float* out = (float*)d_out;

    // ws layout (round-1 footprint, proven)
    float* ws = (float*)d_ws;
    float* xd = ws;                         //   675840 floats
    float* hslot = xd + 675840;             //  8650752 floats
    float* slotA = hslot + 8650752;         //  8650752
    float* slotB = slotA + 8650752;         //  8650752
    float* oldP1 = slotB + 8650752;         //   270336 (unused)
    float* oldP2 = oldP1 + 270336;          //   270336 (unused)
    float* SC = oldP2 + 270336;             //    16896
    float* SH = SC + 16896;                 //    16896
    ushort* hbf = (ushort*)hslot;           //  4325376 u16
    ushort* WT1 = (ushort*)slotA;           //   393216 u16
    ushort* WT2 = WT1 + 393216;             //   393216 u16
    ushort* ybf = WT2 + 393216;             //  8650752 u16
    ushort* aP1 = ybf + 8650752;            //    46080 u16
    ushort* aP2 = aP1 + 46080;              //    46080 u16
    ushort* aPd = aP2 + 46080;              //     7680 u16
    ushort* aPe = aPd + 7680;               //     7680 u16
    ushort* dwT = aPe + 7680;               //     8192 u16
    ushort* ewT = dwT + 8192;               //     8192 u16
    float* P1 = slotB;                      //  1081344 f (64 groups)
    float* P2 = P1 + (size_t)NBGS * C_;     //  1081344 f

    const dim3 blk(256);
    const dim3 gS(17, NBGS);

    // preprocessing
    k_wtrans<<<dim3(4,4,ST_), blk, 0, stream>>>(g1w, WT1);
    k_wtrans<<<dim3(4,4,ST_), blk, 0, stream>>>(g2w, WT2);
    k_aprep<<<180, blk, 0, stream>>>(g1a, aP1, ST_);
    k_aprep<<<180, blk, 0, stream>>>(g2a, aP2, ST_);
    k_aprep<<<30, blk, 0, stream>>>(deca, aPd, 1);
    k_aprep<<<30, blk, 0, stream>>>(enca, aPe, 1);
    k_dwprep<<<32, blk, 0, stream>>>(decw, dwT);
    k_ewprep<<<32, blk, 0, stream>>>(encw, ewT);

    k_dct<<<B_, blk, 0, stream>>>(x, tm, xd);

    // encoder (dual-MFMA) -> ybf; bn0 stats+coefs
    k_genc2<<<B_, blk, 0, stream>>>(xd, ewT, aPe, encb, ybf);
    k_stats<<<gS, blk, 0, stream>>>(ybf, P1, P2);
    k_bnfin<<<17, blk, 0, stream>>>(P1, P2, bn0g, bn0b, SC, SH);

    for (int s = 0; s < ST_; ++s) {
        // gc1: A = tanh(bn(y)) (+h for s>0); h updated; ybf = att1*(A@w1)+b1
        k_gc<<<B_, blk, 0, stream>>>(ybf, SC, SH, s ? hbf : nullptr, hbf,
                                     WT1 + s*H_*H_, aP1 + s*7680,
                                     g1b + s*H_, ybf);
        k_stats<<<gS, blk, 0, stream>>>(ybf, P1, P2);
        k_bnfin<<<17, blk, 0, stream>>>(P1, P2, b1g + s*C_, b1b + s*C_, SC, SH);
        // gc2: A = tanh(bn1(y)); ybf = att2*(A@w2)+b2
        k_gc<<<B_, blk, 0, stream>>>(ybf, SC, SH, nullptr, nullptr,
                                     WT2 + s*H_*H_, aP2 + s*7680,
                                     g2b + s*H_, ybf);
        k_stats<<<gS, blk, 0, stream>>>(ybf, P1, P2);
        k_bnfin<<<17, blk, 0, stream>>>(P1, P2, b2g + s*C_, b2b + s*C_, SC, SH);
    }

    // decoder with fused final h-update (h6 = tanh(bn2(y2_5)) + h5)
    k_dec2<<<B_, blk, 0, stream>>>(ybf, SC, SH, hbf, dwT, aPd, decb, xd, itm,
                                   x, out);
}